// Round 11
// baseline (544.481 us; speedup 1.0000x reference)
//
#include <hip/hip_runtime.h>
#include <hip/hip_bf16.h>

#define THREADS 256

typedef __attribute__((ext_vector_type(2))) float f32x2;
typedef __attribute__((ext_vector_type(4))) float f32x4;
typedef __attribute__((ext_vector_type(8))) float f32x8;
typedef __attribute__((ext_vector_type(8))) short short8;
typedef __attribute__((ext_vector_type(4))) unsigned short u16x4;
typedef __attribute__((ext_vector_type(8))) unsigned short u16x8;

__device__ inline unsigned short f2bf(float f) {
    unsigned int u = __builtin_bit_cast(unsigned int, f);
    unsigned int r = (u + 0x7FFFu + ((u >> 16) & 1u)) >> 16;
    return (unsigned short)r;
}
__device__ inline float bf2f(unsigned short h) {
    unsigned int u = ((unsigned int)h) << 16;
    return __builtin_bit_cast(float, u);
}
__device__ __forceinline__ f32x8 bfv8(u16x8 v) {
    f32x8 r;
#pragma unroll
    for (int j = 0; j < 8; ++j) r[j] = bf2f(v[j]);
    return r;
}

// ---------------- graph preprocessing ----------------

__global__ __launch_bounds__(256) void init_cnt_kernel(int* cnt, int n) {
    int i = blockIdx.x * blockDim.x + threadIdx.x;
    if (i < n) cnt[i] = 1;   // self loop
}

__global__ __launch_bounds__(256) void count_edges_kernel(const int* ei, int* cnt, int E) {
    int e = blockIdx.x * blockDim.x + threadIdx.x;
    if (e < E) atomicAdd(&cnt[ei[E + e]], 1);   // dst row
}

// single-block exclusive scan: 1024 threads, chunked
__global__ __launch_bounds__(1024) void scan_kernel(const int* cnt, int* row_ptr, int n) {
    __shared__ int sh[1024];
    int chunk = (n + 1023) >> 10;
    int beg = (int)threadIdx.x * chunk;
    int end = min(beg + chunk, n);
    int s = 0;
    for (int i = beg; i < end; ++i) s += cnt[i];
    sh[threadIdx.x] = s;
    __syncthreads();
    for (int off = 1; off < 1024; off <<= 1) {
        int t = (threadIdx.x >= (unsigned)off) ? sh[threadIdx.x - off] : 0;
        __syncthreads();
        sh[threadIdx.x] += t;
        __syncthreads();
    }
    int run = sh[threadIdx.x] - s;   // exclusive prefix
    for (int i = beg; i < end; ++i) { row_ptr[i] = run; run += cnt[i]; }
    if (threadIdx.x == 1023) row_ptr[n] = run;
}

// dinv + self-fill + cursor init in one pass
__global__ __launch_bounds__(256) void prep_fused_kernel(const int* cnt, const int* row_ptr,
                                                         int* cursor, float* dinv,
                                                         int* src_sorted, int n) {
    int i = blockIdx.x * blockDim.x + threadIdx.x;
    if (i < n) {
        dinv[i] = rsqrtf((float)cnt[i]);
        int p = row_ptr[i];
        src_sorted[p] = i;     // self loop first (deterministic slot)
        cursor[i] = p + 1;
    }
}

__global__ __launch_bounds__(256) void fill_edges_kernel(const int* ei, int* cursor, int* src_sorted, int E) {
    int e = blockIdx.x * blockDim.x + threadIdx.x;
    if (e < E) {
        int s = ei[e];
        int d = ei[E + e];
        int pos = atomicAdd(&cursor[d], 1);
        src_sorted[pos] = s;
    }
}

// ---------------- split-bf16 conversion ----------------
// x -> [hi | lo]  (row length 2F)
__global__ __launch_bounds__(256) void convert_x_kernel(const float* __restrict__ x,
                                                        unsigned short* __restrict__ xs,
                                                        int n, int F) {
    long idx = (long)blockIdx.x * 256 + threadIdx.x;
    long total = (long)n * (F / 4);
    if (idx >= total) return;
    int row = (int)(idx / (F / 4));
    int c4 = (int)(idx % (F / 4)) * 4;
    f32x4 v = *(const f32x4*)&x[(long)row * F + c4];
    u16x4 hi, lo;
#pragma unroll
    for (int j = 0; j < 4; ++j) {
        hi[j] = f2bf(v[j]);
        lo[j] = f2bf(v[j] - bf2f(hi[j]));
    }
    unsigned short* base = xs + (long)row * 2 * F;
    *(u16x4*)&base[c4] = hi;
    *(u16x4*)&base[F + c4] = lo;
}

// W [K,N] f32 -> Wt [N, 3K] bf16 transposed: rows of B' = [hi; hi; lo]
__global__ __launch_bounds__(256) void convert_w_kernel(const float* __restrict__ W,
                                                        unsigned short* __restrict__ Wt,
                                                        int K, int N) {
    int idx = blockIdx.x * 256 + threadIdx.x;
    if (idx >= K * N) return;
    int k = idx / N, n = idx % N;
    float v = W[(long)k * N + n];
    unsigned short hi = f2bf(v);
    unsigned short lo = f2bf(v - bf2f(hi));
    unsigned short* base = Wt + (long)n * 3 * K;
    base[k] = hi;
    base[K + k] = hi;
    base[2 * K + k] = lo;
}

// ---------------- MFMA bf16 GEMM, register-direct (no LDS, no barriers) ----------------
// C[M,N] = A'[M,Kp] * Bt[N,Kp]^T, epilogue *dinv[row], C in bf16.
// BM=64 per block, 4 waves as 2m x 2n. Each lane loads its MFMA fragments
// straight from global (B is L2-resident, A is L3-resident); the fully unrolled
// k-loop is a pure load->MFMA dep graph the compiler pipelines freely — no
// vmcnt(0) barrier drains (the round-9/10 wall).
// A stored [hi|lo] (row len KA=KP*2/3); logical segment [KA,KP) remaps to hi.
template <int BN, int KP>
__global__ __launch_bounds__(256) void gemm_reg_kernel(const unsigned short* __restrict__ A,
                                                       const unsigned short* __restrict__ Bt,
                                                       const float* __restrict__ dinv,
                                                       unsigned short* __restrict__ C,
                                                       int M, int N) {
    constexpr int KA = (KP / 3) * 2;
    constexpr int NI = BN / 32;          // n-tiles per wave (2 waves split BN)
    constexpr int NT = KP / 64;
    const int tid = threadIdx.x;
    const int m0 = blockIdx.x * 64;
    const int wave = tid >> 6, l = tid & 63;
    const int wm = wave & 1, wn = wave >> 1;
    const int lr = l & 15, lg = l >> 4;
    const unsigned short* abase = A + (long)(m0 + wm * 32 + lr) * KA + (lg << 3);
    const unsigned short* bbase = Bt + (long)(wn * (BN / 2) + lr) * KP + (lg << 3);
    f32x4 acc[2][NI] = {};
#pragma unroll
    for (int t = 0; t < NT; ++t) {
#pragma unroll
        for (int ks = 0; ks < 2; ++ks) {
            constexpr int dummy = 0; (void)dummy;
            int koff = t * 64 + ks * 32;
            if (koff >= KA) koff -= KA;           // compile-time folded (t,ks unrolled)
            int kfull = t * 64 + ks * 32;
            short8 a[2], b[NI];
#pragma unroll
            for (int i = 0; i < 2; ++i)
                a[i] = *(const short8*)&abase[(long)i * 16 * KA + koff];
#pragma unroll
            for (int ni = 0; ni < NI; ++ni)
                b[ni] = *(const short8*)&bbase[(long)ni * 16 * KP + kfull];
#pragma unroll
            for (int i = 0; i < 2; ++i)
#pragma unroll
                for (int ni = 0; ni < NI; ++ni)
                    acc[i][ni] = __builtin_amdgcn_mfma_f32_16x16x32_bf16(a[i], b[ni], acc[i][ni], 0, 0, 0);
        }
    }
#pragma unroll
    for (int i = 0; i < 2; ++i) {
        int rbase = m0 + wm * 32 + i * 16 + lg * 4;
#pragma unroll
        for (int ni = 0; ni < NI; ++ni) {
            int col = wn * (BN / 2) + ni * 16 + lr;
#pragma unroll
            for (int r = 0; r < 4; ++r) {
                int row = rbase + r;
                if (row < M) C[(long)row * N + col] = f2bf(acc[i][ni][r] * dinv[row]);
            }
        }
    }
}

// ---------------- bf16 gather core: 8-deep unroll, u16x8 (16B) per lane ----------------
template <int R8>   // row stride in u16x8 units
__device__ __forceinline__ f32x8 gather_sum_bf(const u16x8* __restrict__ base,
                                               const int* __restrict__ src,
                                               int beg, int end) {
    f32x8 acc = {0.f, 0.f, 0.f, 0.f, 0.f, 0.f, 0.f, 0.f};
    int e = beg;
    for (; e + 8 <= end; e += 8) {
        u16x8 v0 = base[(long)src[e] * R8],     v1 = base[(long)src[e + 1] * R8];
        u16x8 v2 = base[(long)src[e + 2] * R8], v3 = base[(long)src[e + 3] * R8];
        u16x8 v4 = base[(long)src[e + 4] * R8], v5 = base[(long)src[e + 5] * R8];
        u16x8 v6 = base[(long)src[e + 6] * R8], v7 = base[(long)src[e + 7] * R8];
        acc += ((bfv8(v0) + bfv8(v1)) + (bfv8(v2) + bfv8(v3)))
             + ((bfv8(v4) + bfv8(v5)) + (bfv8(v6) + bfv8(v7)));
    }
    for (; e < end; ++e) acc += bfv8(base[(long)src[e] * R8]);
    return acc;
}

// ---------------- f32 gather core (layers 3/4) ----------------
template <int G>
__device__ __forceinline__ f32x4 gather_sum(const f32x4* __restrict__ tsv,
                                            const int* __restrict__ src,
                                            int beg, int end, int lane) {
    f32x4 acc = {0.f, 0.f, 0.f, 0.f};
    int e = beg;
    for (; e + 8 <= end; e += 8) {
        int s0 = src[e], s1 = src[e + 1], s2 = src[e + 2], s3 = src[e + 3];
        int s4 = src[e + 4], s5 = src[e + 5], s6 = src[e + 6], s7 = src[e + 7];
        f32x4 v0 = tsv[(long)s0 * G + lane], v1 = tsv[(long)s1 * G + lane];
        f32x4 v2 = tsv[(long)s2 * G + lane], v3 = tsv[(long)s3 * G + lane];
        f32x4 v4 = tsv[(long)s4 * G + lane], v5 = tsv[(long)s5 * G + lane];
        f32x4 v6 = tsv[(long)s6 * G + lane], v7 = tsv[(long)s7 * G + lane];
        acc += ((v0 + v1) + (v2 + v3)) + ((v4 + v5) + (v6 + v7));
    }
    for (; e + 2 <= end; e += 2) {
        int s0 = src[e], s1 = src[e + 1];
        acc += tsv[(long)s0 * G + lane] + tsv[(long)s1 * G + lane];
    }
    if (e < end) acc += tsv[(long)src[e] * G + lane];
    return acc;
}

// D=256 bf16 gather: h1 = relu(dinv*sum + b1) -> split bf16 [hi|lo] write (row len 512)
__global__ __launch_bounds__(256) void agg_split256_kernel(const unsigned short* __restrict__ ts,
                                                           const int* __restrict__ row_ptr,
                                                           const int* __restrict__ src_sorted,
                                                           const float* __restrict__ dinv,
                                                           const float* __restrict__ bias,
                                                           unsigned short* __restrict__ out_s,
                                                           int n) {
    int g = threadIdx.x >> 5, lane = threadIdx.x & 31;   // 8 nodes/block, 32 lanes/node
    int node = blockIdx.x * 8 + g;
    if (node >= n) return;
    const u16x8* base = (const u16x8*)ts + lane;         // row stride 32 chunks
    f32x8 acc = gather_sum_bf<32>(base, src_sorted, row_ptr[node], row_ptr[node + 1]);
    float di = dinv[node];
    f32x8 b8 = *(const f32x8*)&bias[lane * 8];
    f32x8 v = acc * di + b8;
    u16x8 hi, lo;
#pragma unroll
    for (int j = 0; j < 8; ++j) {
        float r = fmaxf(v[j], 0.f);
        hi[j] = f2bf(r);
        lo[j] = f2bf(r - bf2f(hi[j]));
    }
    unsigned short* ob = out_s + (long)node * 512 + lane * 8;
    *(u16x8*)ob = hi;
    *(u16x8*)(ob + 256) = lo;
}

// D=128 bf16 gather + fused W3 matvec: ts3[node] = dinv * (relu(dinv*sum+b2) @ W3)  (128 -> 32)
__global__ __launch_bounds__(256) void agg_fused_w3_kernel(const unsigned short* __restrict__ ts,
                                                           const int* __restrict__ row_ptr,
                                                           const int* __restrict__ src_sorted,
                                                           const float* __restrict__ dinv,
                                                           const float* __restrict__ bias,
                                                           const float* __restrict__ W3,
                                                           float* __restrict__ ts3, int n) {
    __shared__ float W3s[128 * 32];
    __shared__ float hbuf[16][132];   // +4 pad: spreads per-node broadcast reads across banks
    for (int i = threadIdx.x; i < 128 * 32; i += 256) W3s[i] = W3[i];
    __syncthreads();
    int g = threadIdx.x >> 4, lane = threadIdx.x & 15;   // 16 nodes/block, 16 lanes/node
    int node = blockIdx.x * 16 + g;
    if (node >= n) return;
    const u16x8* base = (const u16x8*)ts + lane;         // row stride 16 chunks
    f32x8 acc = gather_sum_bf<16>(base, src_sorted, row_ptr[node], row_ptr[node + 1]);
    float di = dinv[node];
    f32x8 b8 = *(const f32x8*)&bias[lane * 8];
    f32x8 v = acc * di + b8;
#pragma unroll
    for (int j = 0; j < 8; ++j) v[j] = fmaxf(v[j], 0.f);
    f32x4 vlo = {v[0], v[1], v[2], v[3]};
    f32x4 vhi = {v[4], v[5], v[6], v[7]};
    *(f32x4*)&hbuf[g][lane * 8] = vlo;        // same-wave DS: in-order, no barrier needed
    *(f32x4*)&hbuf[g][lane * 8 + 4] = vhi;
    int c0 = lane * 2;
    float aj0 = 0.f, aj1 = 0.f;
#pragma unroll
    for (int k = 0; k < 128; k += 4) {
        f32x4 hv = *(const f32x4*)&hbuf[g][k];
        aj0 += hv[0] * W3s[k * 32 + c0] + hv[1] * W3s[(k + 1) * 32 + c0]
             + hv[2] * W3s[(k + 2) * 32 + c0] + hv[3] * W3s[(k + 3) * 32 + c0];
        aj1 += hv[0] * W3s[k * 32 + c0 + 1] + hv[1] * W3s[(k + 1) * 32 + c0 + 1]
             + hv[2] * W3s[(k + 2) * 32 + c0 + 1] + hv[3] * W3s[(k + 3) * 32 + c0 + 1];
    }
    f32x2 o = {aj0 * di, aj1 * di};
    *(f32x2*)&ts3[(long)node * 32 + c0] = o;
}

// D=32 agg + fused Wk matvec: tsk[node] = dinv * (relu(dinv*sum+b3) @ Wk)    (32 -> 8)
__global__ __launch_bounds__(256) void agg_fused_wk_kernel(const float* __restrict__ ts,
                                                           const int* __restrict__ row_ptr,
                                                           const int* __restrict__ src_sorted,
                                                           const float* __restrict__ dinv,
                                                           const float* __restrict__ bias,
                                                           const float* __restrict__ Wk,
                                                           float* __restrict__ tsk, int n) {
    __shared__ float Wks[32 * 8];
    __shared__ float hbuf[32][36];   // +4 pad
    for (int i = threadIdx.x; i < 32 * 8; i += 256) Wks[i] = Wk[i];
    __syncthreads();
    int g = threadIdx.x >> 3, lane = threadIdx.x & 7;
    int node = blockIdx.x * 32 + g;
    if (node >= n) return;
    f32x4 acc = gather_sum<8>((const f32x4*)ts, src_sorted, row_ptr[node], row_ptr[node + 1], lane);
    float di = dinv[node];
    f32x4 b4 = *(const f32x4*)&bias[lane * 4];
    f32x4 v = acc * di + b4;
#pragma unroll
    for (int j = 0; j < 4; ++j) v[j] = fmaxf(v[j], 0.f);
    *(f32x4*)&hbuf[g][lane * 4] = v;
    float aj = 0.f;
#pragma unroll
    for (int k = 0; k < 32; k += 4) {
        f32x4 hv = *(const f32x4*)&hbuf[g][k];
        aj += hv[0] * Wks[k * 8 + lane] + hv[1] * Wks[(k + 1) * 8 + lane]
            + hv[2] * Wks[(k + 2) * 8 + lane] + hv[3] * Wks[(k + 3) * 8 + lane];
    }
    tsk[(long)node * 8 + lane] = aj * di;
}

// D=8: z = relu(dinv*sum + bk)
__global__ __launch_bounds__(256) void agg_plain8_kernel(const float* __restrict__ ts,
                                                         const int* __restrict__ row_ptr,
                                                         const int* __restrict__ src_sorted,
                                                         const float* __restrict__ dinv,
                                                         const float* __restrict__ bias,
                                                         float* __restrict__ z, int n) {
    int g = threadIdx.x >> 1, lane = threadIdx.x & 1;
    int node = blockIdx.x * 128 + g;
    if (node >= n) return;
    f32x4 acc = gather_sum<2>((const f32x4*)ts, src_sorted, row_ptr[node], row_ptr[node + 1], lane);
    float di = dinv[node];
    f32x4 b4 = *(const f32x4*)&bias[lane * 4];
    f32x4 v = acc * di + b4;
#pragma unroll
    for (int j = 0; j < 4; ++j) v[j] = fmaxf(v[j], 0.f);
    *(f32x4*)&z[(long)node * 8 + lane * 4] = v;
}

// ---------------- decoder: out[k,e] = dot(z[s_e], z[d_e]) (identical across k) ----------------
__global__ __launch_bounds__(256) void decoder_kernel(const float* __restrict__ z,
                                                      const int* __restrict__ ei,
                                                      float* __restrict__ out,
                                                      int E, int K) {
    int e = blockIdx.x * blockDim.x + threadIdx.x;
    if (e >= E) return;
    int s = ei[e];
    int d = ei[E + e];
    const f32x4* zv = (const f32x4*)z;
    f32x4 a0 = zv[(long)s * 2], a1 = zv[(long)s * 2 + 1];
    f32x4 b0 = zv[(long)d * 2], b1 = zv[(long)d * 2 + 1];
    f32x4 p = a0 * b0 + a1 * b1;
    float acc = p[0] + p[1] + p[2] + p[3];
    for (int k = 0; k < K; k++) out[(long)k * E + e] = acc;
}

// ---------------- launch ----------------

extern "C" void kernel_launch(void* const* d_in, const int* in_sizes, int n_in,
                              void* d_out, int out_size, void* d_ws, size_t ws_size,
                              hipStream_t stream) {
    const float* x  = (const float*)d_in[0];
    const int*   ei = (const int*)d_in[1];
    const float* W1 = (const float*)d_in[3];
    const float* b1 = (const float*)d_in[4];
    const float* W2 = (const float*)d_in[5];
    const float* b2 = (const float*)d_in[6];
    const float* W3 = (const float*)d_in[7];
    const float* b3 = (const float*)d_in[8];
    const float* Wk = (const float*)d_in[9];
    const float* bk = (const float*)d_in[10];
    float* out = (float*)d_out;

    const int D1 = in_sizes[4];            // 256
    const int D2 = in_sizes[6];            // 128
    const int F  = in_sizes[3] / D1;       // 256
    const int N  = in_sizes[0] / F;        // 50000
    const int E  = in_sizes[1] / 2;        // 800000
    const int K  = out_size / E;           // 8
    const int M  = E + N;                  // edges incl self loops
    const int Mpad = (N + 127) & ~127;     // 50048

    size_t off = 0;
    auto alloc = [&](size_t bytes) -> void* {
        off = (off + 255) & ~(size_t)255;
        void* p = (char*)d_ws + off;
        off += bytes;
        return p;
    };
    int*   cnt        = (int*)alloc((size_t)N * sizeof(int));
    int*   row_ptr    = (int*)alloc((size_t)(N + 1) * sizeof(int));
    int*   cursor     = (int*)alloc((size_t)N * sizeof(int));
    float* dinv       = (float*)alloc((size_t)N * sizeof(float));
    int*   src_sorted = (int*)alloc((size_t)M * sizeof(int));
    unsigned short* region_x = (unsigned short*)alloc((size_t)Mpad * 2 * F * sizeof(short));  // xs -> h1s (51.2MB)
    float* region_t   = (float*)alloc((size_t)Mpad * 256 * sizeof(float));                    // ts1/ts2 (as bf16)
    unsigned short* Wt1 = (unsigned short*)alloc((size_t)D1 * 3 * F * sizeof(short));
    unsigned short* Wt2 = (unsigned short*)alloc((size_t)D2 * 3 * D1 * sizeof(short));
    float* ts3        = (float*)alloc((size_t)Mpad * 32 * sizeof(float));
    float* tsk        = (float*)alloc((size_t)Mpad * 8 * sizeof(float));
    float* z          = (float*)alloc((size_t)Mpad * 8 * sizeof(float));
    (void)ws_size; (void)n_in;

    unsigned short* xs  = region_x;
    unsigned short* h1s = region_x;                 // reused after GEMM1 consumed xs
    unsigned short* ts1 = (unsigned short*)region_t;  // [Mpad,256] bf16 (25.6MB)
    unsigned short* ts2 = (unsigned short*)region_t;  // [Mpad,128] bf16 (ts1 consumed)

    int nbN = (N + THREADS - 1) / THREADS;
    int nbE = (E + THREADS - 1) / THREADS;

    // ---- graph prep ----
    init_cnt_kernel<<<nbN, THREADS, 0, stream>>>(cnt, N);
    count_edges_kernel<<<nbE, THREADS, 0, stream>>>(ei, cnt, E);
    scan_kernel<<<1, 1024, 0, stream>>>(cnt, row_ptr, N);
    prep_fused_kernel<<<nbN, THREADS, 0, stream>>>(cnt, row_ptr, cursor, dinv, src_sorted, N);
    fill_edges_kernel<<<nbE, THREADS, 0, stream>>>(ei, cursor, src_sorted, E);

    // ---- conversions ----
    convert_x_kernel<<<(int)(((long)N * (F / 4) + 255) / 256), THREADS, 0, stream>>>(x, xs, N, F);
    convert_w_kernel<<<(F * D1 + 255) / 256, THREADS, 0, stream>>>(W1, Wt1, F, D1);
    convert_w_kernel<<<(D1 * D2 + 255) / 256, THREADS, 0, stream>>>(W2, Wt2, D1, D2);

    // ---- layer 1: ts1 = bf16(dinv .* (x @ W1)); agg (bf16 gather) -> h1s [hi|lo] ----
    gemm_reg_kernel<256, 768><<<Mpad / 64, THREADS, 0, stream>>>(xs, Wt1, dinv, ts1, N, D1);
    agg_split256_kernel<<<(N + 7) / 8, THREADS, 0, stream>>>(ts1, row_ptr, src_sorted, dinv, b1, h1s, N);

    // ---- layer 2: ts2 = bf16(dinv .* (h1 @ W2)); agg (bf16 gather) + fused W3 -> ts3 ----
    gemm_reg_kernel<128, 768><<<Mpad / 64, THREADS, 0, stream>>>(h1s, Wt2, dinv, ts2, N, D2);
    agg_fused_w3_kernel<<<(N + 15) / 16, THREADS, 0, stream>>>(ts2, row_ptr, src_sorted, dinv, b2, W3, ts3, N);

    // ---- layer 3 agg + fused Wk (32 -> 8), then final agg ----
    agg_fused_wk_kernel<<<(N + 31) / 32, THREADS, 0, stream>>>(ts3, row_ptr, src_sorted, dinv, b3, Wk, tsk, N);
    agg_plain8_kernel<<<(N + 127) / 128, THREADS, 0, stream>>>(tsk, row_ptr, src_sorted, dinv, bk, z, N);

    // ---- decoder ----
    decoder_kernel<<<nbE, THREADS, 0, stream>>>(z, ei, out, E, K);
}

// Round 12
// 434.404 us; speedup vs baseline: 1.2534x; 1.2534x over previous
//
#include <hip/hip_runtime.h>
#include <hip/hip_bf16.h>

#define THREADS 256

typedef __attribute__((ext_vector_type(2))) float f32x2;
typedef __attribute__((ext_vector_type(4))) float f32x4;
typedef __attribute__((ext_vector_type(8))) float f32x8;
typedef __attribute__((ext_vector_type(8))) short short8;
typedef __attribute__((ext_vector_type(4))) unsigned short u16x4;
typedef __attribute__((ext_vector_type(8))) unsigned short u16x8;

__device__ inline unsigned short f2bf(float f) {
    unsigned int u = __builtin_bit_cast(unsigned int, f);
    unsigned int r = (u + 0x7FFFu + ((u >> 16) & 1u)) >> 16;
    return (unsigned short)r;
}
__device__ inline float bf2f(unsigned short h) {
    unsigned int u = ((unsigned int)h) << 16;
    return __builtin_bit_cast(float, u);
}
__device__ __forceinline__ f32x8 bfv8(u16x8 v) {
    f32x8 r;
#pragma unroll
    for (int j = 0; j < 8; ++j) r[j] = bf2f(v[j]);
    return r;
}

// ---------------- graph preprocessing ----------------

__global__ __launch_bounds__(256) void init_cnt_kernel(int* cnt, int n) {
    int i = blockIdx.x * blockDim.x + threadIdx.x;
    if (i < n) cnt[i] = 1;   // self loop
}

__global__ __launch_bounds__(256) void count_edges_kernel(const int* ei, int* cnt, int E) {
    int e = blockIdx.x * blockDim.x + threadIdx.x;
    if (e < E) atomicAdd(&cnt[ei[E + e]], 1);   // dst row
}

// single-block exclusive scan: 1024 threads, chunked
__global__ __launch_bounds__(1024) void scan_kernel(const int* cnt, int* row_ptr, int n) {
    __shared__ int sh[1024];
    int chunk = (n + 1023) >> 10;
    int beg = (int)threadIdx.x * chunk;
    int end = min(beg + chunk, n);
    int s = 0;
    for (int i = beg; i < end; ++i) s += cnt[i];
    sh[threadIdx.x] = s;
    __syncthreads();
    for (int off = 1; off < 1024; off <<= 1) {
        int t = (threadIdx.x >= (unsigned)off) ? sh[threadIdx.x - off] : 0;
        __syncthreads();
        sh[threadIdx.x] += t;
        __syncthreads();
    }
    int run = sh[threadIdx.x] - s;   // exclusive prefix
    for (int i = beg; i < end; ++i) { row_ptr[i] = run; run += cnt[i]; }
    if (threadIdx.x == 1023) row_ptr[n] = run;
}

// dinv + self-fill + cursor init in one pass
__global__ __launch_bounds__(256) void prep_fused_kernel(const int* cnt, const int* row_ptr,
                                                         int* cursor, float* dinv,
                                                         int* src_sorted, int n) {
    int i = blockIdx.x * blockDim.x + threadIdx.x;
    if (i < n) {
        dinv[i] = rsqrtf((float)cnt[i]);
        int p = row_ptr[i];
        src_sorted[p] = i;     // self loop first (deterministic slot)
        cursor[i] = p + 1;
    }
}

__global__ __launch_bounds__(256) void fill_edges_kernel(const int* ei, int* cursor, int* src_sorted, int E) {
    int e = blockIdx.x * blockDim.x + threadIdx.x;
    if (e < E) {
        int s = ei[e];
        int d = ei[E + e];
        int pos = atomicAdd(&cursor[d], 1);
        src_sorted[pos] = s;
    }
}

// ---------------- fragment-linear packed conversions ----------------
// Packed A layout (KA=512 phys = [hi(256)|lo(256)]): chunk(row,kp8) at
// ((row/16)*16 + kp/32)*64 + ((kp%32)/8)*16 + row%16, 8 bf16 per chunk.
// MFMA lane l of tile (rt,kg) then reads chunk (rt*16+kg)*64 + l  -> coalesced.
__global__ __launch_bounds__(256) void convert_x_pack_kernel(const float* __restrict__ x,
                                                             unsigned short* __restrict__ Ap,
                                                             int n, int F) {
    long idx = (long)blockIdx.x * 256 + threadIdx.x;
    if (idx >= (long)n * 64) return;
    int row = (int)(idx >> 6), ck = (int)(idx & 63);
    int kp = ck * 8;
    bool ishi = kp < 256;
    const float* src = &x[(long)row * F + (kp & 255)];
    f32x4 v0 = *(const f32x4*)src;
    f32x4 v1 = *(const f32x4*)(src + 4);
    u16x8 o;
#pragma unroll
    for (int j = 0; j < 4; ++j) {
        unsigned short h0 = f2bf(v0[j]);
        unsigned short h1 = f2bf(v1[j]);
        o[j]     = ishi ? h0 : f2bf(v0[j] - bf2f(h0));
        o[j + 4] = ishi ? h1 : f2bf(v1[j] - bf2f(h1));
    }
    size_t chunk = ((size_t)(row >> 4) * 16 + (ck >> 2)) * 64 + (ck & 3) * 16 + (row & 15);
    *(u16x8*)&Ap[chunk * 8] = o;
}

// W [K,N] f32 -> packed B, logical KP=3K rows [hi; hi; lo], fragment-linear:
// chunk(col,kp8) at ((col/16)*(3K/32) + kp/32)*64 + ((kp%32)/8)*16 + col%16.
__global__ __launch_bounds__(256) void convert_w_pack_kernel(const float* __restrict__ W,
                                                             unsigned short* __restrict__ Bp,
                                                             int K, int N) {
    int cpc = 3 * K / 8;                   // chunks per column
    int idx = blockIdx.x * 256 + threadIdx.x;
    if (idx >= N * cpc) return;
    int n = idx / cpc, ck = idx % cpc;
    int kp = ck * 8;
    int seg = kp / K;
    int c = kp - seg * K;
    u16x8 o;
#pragma unroll
    for (int j = 0; j < 8; ++j) {
        float f = W[(long)(c + j) * N + n];
        unsigned short h = f2bf(f);
        o[j] = (seg < 2) ? h : f2bf(f - bf2f(h));
    }
    size_t chunk = ((size_t)(n >> 4) * (3 * K / 32) + (ck >> 2)) * 64 + (ck & 3) * 16 + (n & 15);
    *(u16x8*)&Bp[chunk * 8] = o;
}

// ---------------- MFMA bf16 GEMM, packed-operand register-direct ----------------
// No LDS, no barriers, fully coalesced fragment loads (chunk l at base+l*16B).
// A: 16 phys kg groups ([hi|lo]); logical kg 0..23 with kg>=16 remapped to hi.
// B: 24 kg groups stored explicitly. BM=64 (4 row-tiles), 4 waves = 2m x 2n.
template <int BN>
__global__ __launch_bounds__(256) void gemm_pack_kernel(const unsigned short* __restrict__ Ap,
                                                        const unsigned short* __restrict__ Bp,
                                                        const float* __restrict__ dinv,
                                                        unsigned short* __restrict__ C,
                                                        int M, int N) {
    constexpr int NI = BN / 32;            // col-tiles per wave
    const int tid = threadIdx.x;
    const int wave = tid >> 6, l = tid & 63;
    const int wm = wave & 1, wn = wave >> 1;
    const int lr = l & 15, lg = l >> 4;
    const int rt0 = blockIdx.x * 4 + wm * 2;
    const int ct0 = wn * NI;
    const short8* ab = (const short8*)Ap + (size_t)rt0 * 1024 + l;   // 16 kg * 64 chunks per rtile
    const short8* bb = (const short8*)Bp + (size_t)ct0 * 1536 + l;   // 24 kg * 64 chunks per ctile
    f32x4 acc[2][NI] = {};
#pragma unroll
    for (int kg = 0; kg < 24; ++kg) {
        const int kga = (kg < 16) ? kg : kg - 16;
        short8 a[2], b[NI];
#pragma unroll
        for (int i = 0; i < 2; ++i)
            a[i] = ab[((size_t)i * 16 + kga) * 64];
#pragma unroll
        for (int ni = 0; ni < NI; ++ni)
            b[ni] = bb[((size_t)ni * 24 + kg) * 64];
#pragma unroll
        for (int i = 0; i < 2; ++i)
#pragma unroll
            for (int ni = 0; ni < NI; ++ni)
                acc[i][ni] = __builtin_amdgcn_mfma_f32_16x16x32_bf16(a[i], b[ni], acc[i][ni], 0, 0, 0);
    }
#pragma unroll
    for (int i = 0; i < 2; ++i) {
        int rbase = blockIdx.x * 64 + (wm * 2 + i) * 16 + lg * 4;
#pragma unroll
        for (int ni = 0; ni < NI; ++ni) {
            int col = wn * (BN / 2) + ni * 16 + lr;
#pragma unroll
            for (int r = 0; r < 4; ++r) {
                int row = rbase + r;
                if (row < M) C[(long)row * N + col] = f2bf(acc[i][ni][r] * dinv[row]);
            }
        }
    }
}

// ---------------- bf16 gather core: 8-deep unroll, u16x8 (16B) per lane ----------------
template <int R8>   // row stride in u16x8 units
__device__ __forceinline__ f32x8 gather_sum_bf(const u16x8* __restrict__ base,
                                               const int* __restrict__ src,
                                               int beg, int end) {
    f32x8 acc = {0.f, 0.f, 0.f, 0.f, 0.f, 0.f, 0.f, 0.f};
    int e = beg;
    for (; e + 8 <= end; e += 8) {
        u16x8 v0 = base[(long)src[e] * R8],     v1 = base[(long)src[e + 1] * R8];
        u16x8 v2 = base[(long)src[e + 2] * R8], v3 = base[(long)src[e + 3] * R8];
        u16x8 v4 = base[(long)src[e + 4] * R8], v5 = base[(long)src[e + 5] * R8];
        u16x8 v6 = base[(long)src[e + 6] * R8], v7 = base[(long)src[e + 7] * R8];
        acc += ((bfv8(v0) + bfv8(v1)) + (bfv8(v2) + bfv8(v3)))
             + ((bfv8(v4) + bfv8(v5)) + (bfv8(v6) + bfv8(v7)));
    }
    for (; e < end; ++e) acc += bfv8(base[(long)src[e] * R8]);
    return acc;
}

// ---------------- f32 gather core (layers 3/4) ----------------
template <int G>
__device__ __forceinline__ f32x4 gather_sum(const f32x4* __restrict__ tsv,
                                            const int* __restrict__ src,
                                            int beg, int end, int lane) {
    f32x4 acc = {0.f, 0.f, 0.f, 0.f};
    int e = beg;
    for (; e + 8 <= end; e += 8) {
        int s0 = src[e], s1 = src[e + 1], s2 = src[e + 2], s3 = src[e + 3];
        int s4 = src[e + 4], s5 = src[e + 5], s6 = src[e + 6], s7 = src[e + 7];
        f32x4 v0 = tsv[(long)s0 * G + lane], v1 = tsv[(long)s1 * G + lane];
        f32x4 v2 = tsv[(long)s2 * G + lane], v3 = tsv[(long)s3 * G + lane];
        f32x4 v4 = tsv[(long)s4 * G + lane], v5 = tsv[(long)s5 * G + lane];
        f32x4 v6 = tsv[(long)s6 * G + lane], v7 = tsv[(long)s7 * G + lane];
        acc += ((v0 + v1) + (v2 + v3)) + ((v4 + v5) + (v6 + v7));
    }
    for (; e + 2 <= end; e += 2) {
        int s0 = src[e], s1 = src[e + 1];
        acc += tsv[(long)s0 * G + lane] + tsv[(long)s1 * G + lane];
    }
    if (e < end) acc += tsv[(long)src[e] * G + lane];
    return acc;
}

// D=256 bf16 gather: h1 = relu(dinv*sum + b1) -> PACKED bf16 [hi|lo] write (KA=512 layout)
__global__ __launch_bounds__(256) void agg_split256_kernel(const unsigned short* __restrict__ ts,
                                                           const int* __restrict__ row_ptr,
                                                           const int* __restrict__ src_sorted,
                                                           const float* __restrict__ dinv,
                                                           const float* __restrict__ bias,
                                                           unsigned short* __restrict__ out_p,
                                                           int n) {
    int g = threadIdx.x >> 5, lane = threadIdx.x & 31;   // 8 nodes/block, 32 lanes/node
    int node = blockIdx.x * 8 + g;
    if (node >= n) return;
    const u16x8* base = (const u16x8*)ts + lane;         // row stride 32 chunks
    f32x8 acc = gather_sum_bf<32>(base, src_sorted, row_ptr[node], row_ptr[node + 1]);
    float di = dinv[node];
    f32x8 b8 = *(const f32x8*)&bias[lane * 8];
    f32x8 v = acc * di + b8;
    u16x8 hi, lo;
#pragma unroll
    for (int j = 0; j < 8; ++j) {
        float r = fmaxf(v[j], 0.f);
        hi[j] = f2bf(r);
        lo[j] = f2bf(r - bf2f(hi[j]));
    }
    // packed: hi chunk kg=lane/4 in [0,8), lo chunk kg=8+lane/4
    size_t tilebase = (size_t)(node >> 4) * 1024 + (lane & 3) * 16 + (node & 15);
    *(u16x8*)&out_p[(tilebase + (size_t)(lane >> 2) * 64) * 8] = hi;
    *(u16x8*)&out_p[(tilebase + (size_t)(8 + (lane >> 2)) * 64) * 8] = lo;
}

// D=128 bf16 gather + fused W3 matvec: ts3[node] = dinv * (relu(dinv*sum+b2) @ W3)  (128 -> 32)
__global__ __launch_bounds__(256) void agg_fused_w3_kernel(const unsigned short* __restrict__ ts,
                                                           const int* __restrict__ row_ptr,
                                                           const int* __restrict__ src_sorted,
                                                           const float* __restrict__ dinv,
                                                           const float* __restrict__ bias,
                                                           const float* __restrict__ W3,
                                                           float* __restrict__ ts3, int n) {
    __shared__ float W3s[128 * 32];
    __shared__ float hbuf[16][132];   // +4 pad: spreads per-node broadcast reads across banks
    for (int i = threadIdx.x; i < 128 * 32; i += 256) W3s[i] = W3[i];
    __syncthreads();
    int g = threadIdx.x >> 4, lane = threadIdx.x & 15;   // 16 nodes/block, 16 lanes/node
    int node = blockIdx.x * 16 + g;
    if (node >= n) return;
    const u16x8* base = (const u16x8*)ts + lane;         // row stride 16 chunks
    f32x8 acc = gather_sum_bf<16>(base, src_sorted, row_ptr[node], row_ptr[node + 1]);
    float di = dinv[node];
    f32x8 b8 = *(const f32x8*)&bias[lane * 8];
    f32x8 v = acc * di + b8;
#pragma unroll
    for (int j = 0; j < 8; ++j) v[j] = fmaxf(v[j], 0.f);
    f32x4 vlo = {v[0], v[1], v[2], v[3]};
    f32x4 vhi = {v[4], v[5], v[6], v[7]};
    *(f32x4*)&hbuf[g][lane * 8] = vlo;        // same-wave DS: in-order, no barrier needed
    *(f32x4*)&hbuf[g][lane * 8 + 4] = vhi;
    int c0 = lane * 2;
    float aj0 = 0.f, aj1 = 0.f;
#pragma unroll
    for (int k = 0; k < 128; k += 4) {
        f32x4 hv = *(const f32x4*)&hbuf[g][k];
        aj0 += hv[0] * W3s[k * 32 + c0] + hv[1] * W3s[(k + 1) * 32 + c0]
             + hv[2] * W3s[(k + 2) * 32 + c0] + hv[3] * W3s[(k + 3) * 32 + c0];
        aj1 += hv[0] * W3s[k * 32 + c0 + 1] + hv[1] * W3s[(k + 1) * 32 + c0 + 1]
             + hv[2] * W3s[(k + 2) * 32 + c0 + 1] + hv[3] * W3s[(k + 3) * 32 + c0 + 1];
    }
    f32x2 o = {aj0 * di, aj1 * di};
    *(f32x2*)&ts3[(long)node * 32 + c0] = o;
}

// D=32 agg + fused Wk matvec: tsk[node] = dinv * (relu(dinv*sum+b3) @ Wk)    (32 -> 8)
__global__ __launch_bounds__(256) void agg_fused_wk_kernel(const float* __restrict__ ts,
                                                           const int* __restrict__ row_ptr,
                                                           const int* __restrict__ src_sorted,
                                                           const float* __restrict__ dinv,
                                                           const float* __restrict__ bias,
                                                           const float* __restrict__ Wk,
                                                           float* __restrict__ tsk, int n) {
    __shared__ float Wks[32 * 8];
    __shared__ float hbuf[32][36];   // +4 pad
    for (int i = threadIdx.x; i < 32 * 8; i += 256) Wks[i] = Wk[i];
    __syncthreads();
    int g = threadIdx.x >> 3, lane = threadIdx.x & 7;
    int node = blockIdx.x * 32 + g;
    if (node >= n) return;
    f32x4 acc = gather_sum<8>((const f32x4*)ts, src_sorted, row_ptr[node], row_ptr[node + 1], lane);
    float di = dinv[node];
    f32x4 b4 = *(const f32x4*)&bias[lane * 4];
    f32x4 v = acc * di + b4;
#pragma unroll
    for (int j = 0; j < 4; ++j) v[j] = fmaxf(v[j], 0.f);
    *(f32x4*)&hbuf[g][lane * 4] = v;
    float aj = 0.f;
#pragma unroll
    for (int k = 0; k < 32; k += 4) {
        f32x4 hv = *(const f32x4*)&hbuf[g][k];
        aj += hv[0] * Wks[k * 8 + lane] + hv[1] * Wks[(k + 1) * 8 + lane]
            + hv[2] * Wks[(k + 2) * 8 + lane] + hv[3] * Wks[(k + 3) * 8 + lane];
    }
    tsk[(long)node * 8 + lane] = aj * di;
}

// D=8: z = relu(dinv*sum + bk)
__global__ __launch_bounds__(256) void agg_plain8_kernel(const float* __restrict__ ts,
                                                         const int* __restrict__ row_ptr,
                                                         const int* __restrict__ src_sorted,
                                                         const float* __restrict__ dinv,
                                                         const float* __restrict__ bias,
                                                         float* __restrict__ z, int n) {
    int g = threadIdx.x >> 1, lane = threadIdx.x & 1;
    int node = blockIdx.x * 128 + g;
    if (node >= n) return;
    f32x4 acc = gather_sum<2>((const f32x4*)ts, src_sorted, row_ptr[node], row_ptr[node + 1], lane);
    float di = dinv[node];
    f32x4 b4 = *(const f32x4*)&bias[lane * 4];
    f32x4 v = acc * di + b4;
#pragma unroll
    for (int j = 0; j < 4; ++j) v[j] = fmaxf(v[j], 0.f);
    *(f32x4*)&z[(long)node * 8 + lane * 4] = v;
}

// ---------------- decoder: out[k,e] = dot(z[s_e], z[d_e]) (identical across k) ----------------
__global__ __launch_bounds__(256) void decoder_kernel(const float* __restrict__ z,
                                                      const int* __restrict__ ei,
                                                      float* __restrict__ out,
                                                      int E, int K) {
    int e = blockIdx.x * blockDim.x + threadIdx.x;
    if (e >= E) return;
    int s = ei[e];
    int d = ei[E + e];
    const f32x4* zv = (const f32x4*)z;
    f32x4 a0 = zv[(long)s * 2], a1 = zv[(long)s * 2 + 1];
    f32x4 b0 = zv[(long)d * 2], b1 = zv[(long)d * 2 + 1];
    f32x4 p = a0 * b0 + a1 * b1;
    float acc = p[0] + p[1] + p[2] + p[3];
    for (int k = 0; k < K; k++) out[(long)k * E + e] = acc;
}

// ---------------- launch ----------------

extern "C" void kernel_launch(void* const* d_in, const int* in_sizes, int n_in,
                              void* d_out, int out_size, void* d_ws, size_t ws_size,
                              hipStream_t stream) {
    const float* x  = (const float*)d_in[0];
    const int*   ei = (const int*)d_in[1];
    const float* W1 = (const float*)d_in[3];
    const float* b1 = (const float*)d_in[4];
    const float* W2 = (const float*)d_in[5];
    const float* b2 = (const float*)d_in[6];
    const float* W3 = (const float*)d_in[7];
    const float* b3 = (const float*)d_in[8];
    const float* Wk = (const float*)d_in[9];
    const float* bk = (const float*)d_in[10];
    float* out = (float*)d_out;

    const int D1 = in_sizes[4];            // 256
    const int D2 = in_sizes[6];            // 128
    const int F  = in_sizes[3] / D1;       // 256
    const int N  = in_sizes[0] / F;        // 50000
    const int E  = in_sizes[1] / 2;        // 800000
    const int K  = out_size / E;           // 8
    const int M  = E + N;                  // edges incl self loops
    const int Mpad = (N + 127) & ~127;     // 50048

    size_t off = 0;
    auto alloc = [&](size_t bytes) -> void* {
        off = (off + 255) & ~(size_t)255;
        void* p = (char*)d_ws + off;
        off += bytes;
        return p;
    };
    int*   cnt        = (int*)alloc((size_t)N * sizeof(int));
    int*   row_ptr    = (int*)alloc((size_t)(N + 1) * sizeof(int));
    int*   cursor     = (int*)alloc((size_t)N * sizeof(int));
    float* dinv       = (float*)alloc((size_t)N * sizeof(float));
    int*   src_sorted = (int*)alloc((size_t)M * sizeof(int));
    unsigned short* region_x = (unsigned short*)alloc((size_t)Mpad * 2 * F * sizeof(short));  // xs_pack -> h1s_pack (51.2MB)
    float* region_t   = (float*)alloc((size_t)Mpad * 256 * sizeof(float));                    // ts1/ts2 (as bf16)
    unsigned short* Wt1 = (unsigned short*)alloc((size_t)D1 * 3 * F * sizeof(short));
    unsigned short* Wt2 = (unsigned short*)alloc((size_t)D2 * 3 * D1 * sizeof(short));
    float* ts3        = (float*)alloc((size_t)Mpad * 32 * sizeof(float));
    float* tsk        = (float*)alloc((size_t)Mpad * 8 * sizeof(float));
    float* z          = (float*)alloc((size_t)Mpad * 8 * sizeof(float));
    (void)ws_size; (void)n_in;

    unsigned short* xs  = region_x;                   // packed A for GEMM1
    unsigned short* h1s = region_x;                   // packed A for GEMM2 (reuse after GEMM1)
    unsigned short* ts1 = (unsigned short*)region_t;  // [Mpad,256] bf16 row-major gather table
    unsigned short* ts2 = (unsigned short*)region_t;  // [Mpad,128] bf16 (ts1 consumed)

    int nbN = (N + THREADS - 1) / THREADS;
    int nbE = (E + THREADS - 1) / THREADS;

    // ---- graph prep ----
    init_cnt_kernel<<<nbN, THREADS, 0, stream>>>(cnt, N);
    count_edges_kernel<<<nbE, THREADS, 0, stream>>>(ei, cnt, E);
    scan_kernel<<<1, 1024, 0, stream>>>(cnt, row_ptr, N);
    prep_fused_kernel<<<nbN, THREADS, 0, stream>>>(cnt, row_ptr, cursor, dinv, src_sorted, N);
    fill_edges_kernel<<<nbE, THREADS, 0, stream>>>(ei, cursor, src_sorted, E);

    // ---- conversions (fragment-linear packed) ----
    convert_x_pack_kernel<<<(int)(((long)N * 64 + 255) / 256), THREADS, 0, stream>>>(x, xs, N, F);
    convert_w_pack_kernel<<<(D1 * (3 * F / 8) + 255) / 256, THREADS, 0, stream>>>(W1, Wt1, F, D1);
    convert_w_pack_kernel<<<(D2 * (3 * D1 / 8) + 255) / 256, THREADS, 0, stream>>>(W2, Wt2, D1, D2);

    // ---- layer 1: ts1 = bf16(dinv .* (x @ W1)); agg (bf16 gather) -> h1s packed ----
    gemm_pack_kernel<256><<<Mpad / 64, THREADS, 0, stream>>>(xs, Wt1, dinv, ts1, N, D1);
    agg_split256_kernel<<<(N + 7) / 8, THREADS, 0, stream>>>(ts1, row_ptr, src_sorted, dinv, b1, h1s, N);

    // ---- layer 2: ts2 = bf16(dinv .* (h1 @ W2)); agg (bf16 gather) + fused W3 -> ts3 ----
    gemm_pack_kernel<128><<<Mpad / 64, THREADS, 0, stream>>>(h1s, Wt2, dinv, ts2, N, D2);
    agg_fused_w3_kernel<<<(N + 15) / 16, THREADS, 0, stream>>>(ts2, row_ptr, src_sorted, dinv, b2, W3, ts3, N);

    // ---- layer 3 agg + fused Wk (32 -> 8), then final agg ----
    agg_fused_wk_kernel<<<(N + 31) / 32, THREADS, 0, stream>>>(ts3, row_ptr, src_sorted, dinv, b3, Wk, tsk, N);
    agg_plain8_kernel<<<(N + 127) / 128, THREADS, 0, stream>>>(tsk, row_ptr, src_sorted, dinv, bk, z, N);

    // ---- decoder ----
    decoder_kernel<<<nbE, THREADS, 0, stream>>>(z, ei, out, E, K);
}

// Round 13
// 364.176 us; speedup vs baseline: 1.4951x; 1.1928x over previous
//
#include <hip/hip_runtime.h>
#include <hip/hip_bf16.h>

#define THREADS 256

typedef __attribute__((ext_vector_type(2))) float f32x2;
typedef __attribute__((ext_vector_type(4))) float f32x4;
typedef __attribute__((ext_vector_type(8))) float f32x8;
typedef __attribute__((ext_vector_type(8))) short short8;
typedef __attribute__((ext_vector_type(4))) unsigned short u16x4;
typedef __attribute__((ext_vector_type(8))) unsigned short u16x8;

__device__ inline unsigned short f2bf(float f) {
    unsigned int u = __builtin_bit_cast(unsigned int, f);
    unsigned int r = (u + 0x7FFFu + ((u >> 16) & 1u)) >> 16;
    return (unsigned short)r;
}
__device__ inline float bf2f(unsigned short h) {
    unsigned int u = ((unsigned int)h) << 16;
    return __builtin_bit_cast(float, u);
}
__device__ __forceinline__ f32x8 bfv8(u16x8 v) {
    f32x8 r;
#pragma unroll
    for (int j = 0; j < 8; ++j) r[j] = bf2f(v[j]);
    return r;
}

// ---------------- graph preprocessing ----------------

__global__ __launch_bounds__(256) void init_cnt_kernel(int* cnt, int n) {
    int i = blockIdx.x * blockDim.x + threadIdx.x;
    if (i < n) cnt[i] = 1;   // self loop
}

__global__ __launch_bounds__(256) void count_edges_kernel(const int* ei, int* cnt, int E) {
    int e = blockIdx.x * blockDim.x + threadIdx.x;
    if (e < E) atomicAdd(&cnt[ei[E + e]], 1);   // dst row
}

// ---------------- 3-phase multi-block exclusive scan (coalesced) ----------------
// p1: per-block sums of cnt -> bsum
__global__ __launch_bounds__(256) void scan_p1_kernel(const int* __restrict__ cnt,
                                                      int* __restrict__ bsum, int n) {
    __shared__ int sh[256];
    int i = blockIdx.x * 256 + threadIdx.x;
    int v = (i < n) ? cnt[i] : 0;
    sh[threadIdx.x] = v;
    __syncthreads();
#pragma unroll
    for (int off = 128; off > 0; off >>= 1) {
        if ((int)threadIdx.x < off) sh[threadIdx.x] += sh[threadIdx.x + off];
        __syncthreads();
    }
    if (threadIdx.x == 0) bsum[blockIdx.x] = sh[0];
}

// p2: single-block exclusive scan of bsum (nb <= 1024)
__global__ __launch_bounds__(1024) void scan_p2_kernel(int* __restrict__ bsum, int nb) {
    __shared__ int sh[1024];
    int v = ((int)threadIdx.x < nb) ? bsum[threadIdx.x] : 0;
    sh[threadIdx.x] = v;
    __syncthreads();
    for (int off = 1; off < 1024; off <<= 1) {
        int t = (threadIdx.x >= (unsigned)off) ? sh[threadIdx.x - off] : 0;
        __syncthreads();
        sh[threadIdx.x] += t;
        __syncthreads();
    }
    if ((int)threadIdx.x < nb) bsum[threadIdx.x] = sh[threadIdx.x] - v;   // exclusive
}

// p3: per-block exclusive scan + block offset -> row_ptr (+ row_ptr[n] tail)
__global__ __launch_bounds__(256) void scan_p3_kernel(const int* __restrict__ cnt,
                                                      const int* __restrict__ bsum,
                                                      int* __restrict__ row_ptr, int n) {
    __shared__ int sh[256];
    int i = blockIdx.x * 256 + threadIdx.x;
    int v = (i < n) ? cnt[i] : 0;
    sh[threadIdx.x] = v;
    __syncthreads();
    for (int off = 1; off < 256; off <<= 1) {
        int t = (threadIdx.x >= (unsigned)off) ? sh[threadIdx.x - off] : 0;
        __syncthreads();
        sh[threadIdx.x] += t;
        __syncthreads();
    }
    int excl = sh[threadIdx.x] - v + bsum[blockIdx.x];
    if (i < n) row_ptr[i] = excl;
    if (i == n - 1) row_ptr[n] = excl + v;
}

// dinv + self-fill + cursor init in one pass
__global__ __launch_bounds__(256) void prep_fused_kernel(const int* cnt, const int* row_ptr,
                                                         int* cursor, float* dinv,
                                                         int* src_sorted, int n) {
    int i = blockIdx.x * blockDim.x + threadIdx.x;
    if (i < n) {
        dinv[i] = rsqrtf((float)cnt[i]);
        int p = row_ptr[i];
        src_sorted[p] = i;     // self loop first (deterministic slot)
        cursor[i] = p + 1;
    }
}

__global__ __launch_bounds__(256) void fill_edges_kernel(const int* ei, int* cursor, int* src_sorted, int E) {
    int e = blockIdx.x * blockDim.x + threadIdx.x;
    if (e < E) {
        int s = ei[e];
        int d = ei[E + e];
        int pos = atomicAdd(&cursor[d], 1);
        src_sorted[pos] = s;
    }
}

// ---------------- fragment-linear packed conversions ----------------
// Packed A layout (KA=512 phys = [hi(256)|lo(256)]): chunk(row,kp8) at
// ((row/16)*16 + kp/32)*64 + ((kp%32)/8)*16 + row%16, 8 bf16 per chunk.
__global__ __launch_bounds__(256) void convert_x_pack_kernel(const float* __restrict__ x,
                                                             unsigned short* __restrict__ Ap,
                                                             int n, int F) {
    long idx = (long)blockIdx.x * 256 + threadIdx.x;
    if (idx >= (long)n * 64) return;
    int row = (int)(idx >> 6), ck = (int)(idx & 63);
    int kp = ck * 8;
    bool ishi = kp < 256;
    const float* src = &x[(long)row * F + (kp & 255)];
    f32x4 v0 = *(const f32x4*)src;
    f32x4 v1 = *(const f32x4*)(src + 4);
    u16x8 o;
#pragma unroll
    for (int j = 0; j < 4; ++j) {
        unsigned short h0 = f2bf(v0[j]);
        unsigned short h1 = f2bf(v1[j]);
        o[j]     = ishi ? h0 : f2bf(v0[j] - bf2f(h0));
        o[j + 4] = ishi ? h1 : f2bf(v1[j] - bf2f(h1));
    }
    size_t chunk = ((size_t)(row >> 4) * 16 + (ck >> 2)) * 64 + (ck & 3) * 16 + (row & 15);
    *(u16x8*)&Ap[chunk * 8] = o;
}

// W [K,N] f32 -> packed B, logical KP=3K rows [hi; hi; lo], fragment-linear.
__global__ __launch_bounds__(256) void convert_w_pack_kernel(const float* __restrict__ W,
                                                             unsigned short* __restrict__ Bp,
                                                             int K, int N) {
    int cpc = 3 * K / 8;                   // chunks per column
    int idx = blockIdx.x * 256 + threadIdx.x;
    if (idx >= N * cpc) return;
    int n = idx / cpc, ck = idx % cpc;
    int kp = ck * 8;
    int seg = kp / K;
    int c = kp - seg * K;
    u16x8 o;
#pragma unroll
    for (int j = 0; j < 8; ++j) {
        float f = W[(long)(c + j) * N + n];
        unsigned short h = f2bf(f);
        o[j] = (seg < 2) ? h : f2bf(f - bf2f(h));
    }
    size_t chunk = ((size_t)(n >> 4) * (3 * K / 32) + (ck >> 2)) * 64 + (ck & 3) * 16 + (n & 15);
    *(u16x8*)&Bp[chunk * 8] = o;
}

// ---------------- MFMA bf16 GEMM, packed-operand register-direct ----------------
// No LDS, no barriers, fully coalesced fragment loads (chunk l at base+l*16B).
template <int BN>
__global__ __launch_bounds__(256) void gemm_pack_kernel(const unsigned short* __restrict__ Ap,
                                                        const unsigned short* __restrict__ Bp,
                                                        const float* __restrict__ dinv,
                                                        unsigned short* __restrict__ C,
                                                        int M, int N) {
    constexpr int NI = BN / 32;            // col-tiles per wave
    const int tid = threadIdx.x;
    const int wave = tid >> 6, l = tid & 63;
    const int wm = wave & 1, wn = wave >> 1;
    const int lr = l & 15, lg = l >> 4;
    const int rt0 = blockIdx.x * 4 + wm * 2;
    const int ct0 = wn * NI;
    const short8* ab = (const short8*)Ap + (size_t)rt0 * 1024 + l;   // 16 kg * 64 chunks per rtile
    const short8* bb = (const short8*)Bp + (size_t)ct0 * 1536 + l;   // 24 kg * 64 chunks per ctile
    f32x4 acc[2][NI] = {};
#pragma unroll
    for (int kg = 0; kg < 24; ++kg) {
        const int kga = (kg < 16) ? kg : kg - 16;
        short8 a[2], b[NI];
#pragma unroll
        for (int i = 0; i < 2; ++i)
            a[i] = ab[((size_t)i * 16 + kga) * 64];
#pragma unroll
        for (int ni = 0; ni < NI; ++ni)
            b[ni] = bb[((size_t)ni * 24 + kg) * 64];
#pragma unroll
        for (int i = 0; i < 2; ++i)
#pragma unroll
            for (int ni = 0; ni < NI; ++ni)
                acc[i][ni] = __builtin_amdgcn_mfma_f32_16x16x32_bf16(a[i], b[ni], acc[i][ni], 0, 0, 0);
    }
#pragma unroll
    for (int i = 0; i < 2; ++i) {
        int rbase = blockIdx.x * 64 + (wm * 2 + i) * 16 + lg * 4;
#pragma unroll
        for (int ni = 0; ni < NI; ++ni) {
            int col = wn * (BN / 2) + ni * 16 + lr;
#pragma unroll
            for (int r = 0; r < 4; ++r) {
                int row = rbase + r;
                if (row < M) C[(long)row * N + col] = f2bf(acc[i][ni][r] * dinv[row]);
            }
        }
    }
}

// ---------------- bf16 gather core: 8-deep unroll, u16x8 (16B) per lane ----------------
template <int R8>   // row stride in u16x8 units
__device__ __forceinline__ f32x8 gather_sum_bf(const u16x8* __restrict__ base,
                                               const int* __restrict__ src,
                                               int beg, int end) {
    f32x8 acc = {0.f, 0.f, 0.f, 0.f, 0.f, 0.f, 0.f, 0.f};
    int e = beg;
    for (; e + 8 <= end; e += 8) {
        u16x8 v0 = base[(long)src[e] * R8],     v1 = base[(long)src[e + 1] * R8];
        u16x8 v2 = base[(long)src[e + 2] * R8], v3 = base[(long)src[e + 3] * R8];
        u16x8 v4 = base[(long)src[e + 4] * R8], v5 = base[(long)src[e + 5] * R8];
        u16x8 v6 = base[(long)src[e + 6] * R8], v7 = base[(long)src[e + 7] * R8];
        acc += ((bfv8(v0) + bfv8(v1)) + (bfv8(v2) + bfv8(v3)))
             + ((bfv8(v4) + bfv8(v5)) + (bfv8(v6) + bfv8(v7)));
    }
    for (; e < end; ++e) acc += bfv8(base[(long)src[e] * R8]);
    return acc;
}

// ---------------- f32 gather core (layers 3/4) ----------------
template <int G>
__device__ __forceinline__ f32x4 gather_sum(const f32x4* __restrict__ tsv,
                                            const int* __restrict__ src,
                                            int beg, int end, int lane) {
    f32x4 acc = {0.f, 0.f, 0.f, 0.f};
    int e = beg;
    for (; e + 8 <= end; e += 8) {
        int s0 = src[e], s1 = src[e + 1], s2 = src[e + 2], s3 = src[e + 3];
        int s4 = src[e + 4], s5 = src[e + 5], s6 = src[e + 6], s7 = src[e + 7];
        f32x4 v0 = tsv[(long)s0 * G + lane], v1 = tsv[(long)s1 * G + lane];
        f32x4 v2 = tsv[(long)s2 * G + lane], v3 = tsv[(long)s3 * G + lane];
        f32x4 v4 = tsv[(long)s4 * G + lane], v5 = tsv[(long)s5 * G + lane];
        f32x4 v6 = tsv[(long)s6 * G + lane], v7 = tsv[(long)s7 * G + lane];
        acc += ((v0 + v1) + (v2 + v3)) + ((v4 + v5) + (v6 + v7));
    }
    for (; e + 2 <= end; e += 2) {
        int s0 = src[e], s1 = src[e + 1];
        acc += tsv[(long)s0 * G + lane] + tsv[(long)s1 * G + lane];
    }
    if (e < end) acc += tsv[(long)src[e] * G + lane];
    return acc;
}

// D=256 bf16 gather: h1 = relu(dinv*sum + b1) -> PACKED bf16 [hi|lo] write (KA=512 layout)
__global__ __launch_bounds__(256) void agg_split256_kernel(const unsigned short* __restrict__ ts,
                                                           const int* __restrict__ row_ptr,
                                                           const int* __restrict__ src_sorted,
                                                           const float* __restrict__ dinv,
                                                           const float* __restrict__ bias,
                                                           unsigned short* __restrict__ out_p,
                                                           int n) {
    int g = threadIdx.x >> 5, lane = threadIdx.x & 31;   // 8 nodes/block, 32 lanes/node
    int node = blockIdx.x * 8 + g;
    if (node >= n) return;
    const u16x8* base = (const u16x8*)ts + lane;         // row stride 32 chunks
    f32x8 acc = gather_sum_bf<32>(base, src_sorted, row_ptr[node], row_ptr[node + 1]);
    float di = dinv[node];
    f32x8 b8 = *(const f32x8*)&bias[lane * 8];
    f32x8 v = acc * di + b8;
    u16x8 hi, lo;
#pragma unroll
    for (int j = 0; j < 8; ++j) {
        float r = fmaxf(v[j], 0.f);
        hi[j] = f2bf(r);
        lo[j] = f2bf(r - bf2f(hi[j]));
    }
    // packed: hi chunk kg=lane/4 in [0,8), lo chunk kg=8+lane/4
    size_t tilebase = (size_t)(node >> 4) * 1024 + (lane & 3) * 16 + (node & 15);
    *(u16x8*)&out_p[(tilebase + (size_t)(lane >> 2) * 64) * 8] = hi;
    *(u16x8*)&out_p[(tilebase + (size_t)(8 + (lane >> 2)) * 64) * 8] = lo;
}

// D=128 bf16 gather + fused W3 matvec: ts3[node] = dinv * (relu(dinv*sum+b2) @ W3)  (128 -> 32)
__global__ __launch_bounds__(256) void agg_fused_w3_kernel(const unsigned short* __restrict__ ts,
                                                           const int* __restrict__ row_ptr,
                                                           const int* __restrict__ src_sorted,
                                                           const float* __restrict__ dinv,
                                                           const float* __restrict__ bias,
                                                           const float* __restrict__ W3,
                                                           float* __restrict__ ts3, int n) {
    __shared__ float W3s[128 * 32];
    __shared__ float hbuf[16][132];   // +4 pad: spreads per-node broadcast reads across banks
    for (int i = threadIdx.x; i < 128 * 32; i += 256) W3s[i] = W3[i];
    __syncthreads();
    int g = threadIdx.x >> 4, lane = threadIdx.x & 15;   // 16 nodes/block, 16 lanes/node
    int node = blockIdx.x * 16 + g;
    if (node >= n) return;
    const u16x8* base = (const u16x8*)ts + lane;         // row stride 16 chunks
    f32x8 acc = gather_sum_bf<16>(base, src_sorted, row_ptr[node], row_ptr[node + 1]);
    float di = dinv[node];
    f32x8 b8 = *(const f32x8*)&bias[lane * 8];
    f32x8 v = acc * di + b8;
#pragma unroll
    for (int j = 0; j < 8; ++j) v[j] = fmaxf(v[j], 0.f);
    f32x4 vlo = {v[0], v[1], v[2], v[3]};
    f32x4 vhi = {v[4], v[5], v[6], v[7]};
    *(f32x4*)&hbuf[g][lane * 8] = vlo;        // same-wave DS: in-order, no barrier needed
    *(f32x4*)&hbuf[g][lane * 8 + 4] = vhi;
    int c0 = lane * 2;
    float aj0 = 0.f, aj1 = 0.f;
#pragma unroll
    for (int k = 0; k < 128; k += 4) {
        f32x4 hv = *(const f32x4*)&hbuf[g][k];
        aj0 += hv[0] * W3s[k * 32 + c0] + hv[1] * W3s[(k + 1) * 32 + c0]
             + hv[2] * W3s[(k + 2) * 32 + c0] + hv[3] * W3s[(k + 3) * 32 + c0];
        aj1 += hv[0] * W3s[k * 32 + c0 + 1] + hv[1] * W3s[(k + 1) * 32 + c0 + 1]
             + hv[2] * W3s[(k + 2) * 32 + c0 + 1] + hv[3] * W3s[(k + 3) * 32 + c0 + 1];
    }
    f32x2 o = {aj0 * di, aj1 * di};
    *(f32x2*)&ts3[(long)node * 32 + c0] = o;
}

// D=32 agg + fused Wk matvec: tsk[node] = dinv * (relu(dinv*sum+b3) @ Wk)    (32 -> 8)
__global__ __launch_bounds__(256) void agg_fused_wk_kernel(const float* __restrict__ ts,
                                                           const int* __restrict__ row_ptr,
                                                           const int* __restrict__ src_sorted,
                                                           const float* __restrict__ dinv,
                                                           const float* __restrict__ bias,
                                                           const float* __restrict__ Wk,
                                                           float* __restrict__ tsk, int n) {
    __shared__ float Wks[32 * 8];
    __shared__ float hbuf[32][36];   // +4 pad
    for (int i = threadIdx.x; i < 32 * 8; i += 256) Wks[i] = Wk[i];
    __syncthreads();
    int g = threadIdx.x >> 3, lane = threadIdx.x & 7;
    int node = blockIdx.x * 32 + g;
    if (node >= n) return;
    f32x4 acc = gather_sum<8>((const f32x4*)ts, src_sorted, row_ptr[node], row_ptr[node + 1], lane);
    float di = dinv[node];
    f32x4 b4 = *(const f32x4*)&bias[lane * 4];
    f32x4 v = acc * di + b4;
#pragma unroll
    for (int j = 0; j < 4; ++j) v[j] = fmaxf(v[j], 0.f);
    *(f32x4*)&hbuf[g][lane * 4] = v;
    float aj = 0.f;
#pragma unroll
    for (int k = 0; k < 32; k += 4) {
        f32x4 hv = *(const f32x4*)&hbuf[g][k];
        aj += hv[0] * Wks[k * 8 + lane] + hv[1] * Wks[(k + 1) * 8 + lane]
            + hv[2] * Wks[(k + 2) * 8 + lane] + hv[3] * Wks[(k + 3) * 8 + lane];
    }
    tsk[(long)node * 8 + lane] = aj * di;
}

// D=8: z = relu(dinv*sum + bk)
__global__ __launch_bounds__(256) void agg_plain8_kernel(const float* __restrict__ ts,
                                                         const int* __restrict__ row_ptr,
                                                         const int* __restrict__ src_sorted,
                                                         const float* __restrict__ dinv,
                                                         const float* __restrict__ bias,
                                                         float* __restrict__ z, int n) {
    int g = threadIdx.x >> 1, lane = threadIdx.x & 1;
    int node = blockIdx.x * 128 + g;
    if (node >= n) return;
    f32x4 acc = gather_sum<2>((const f32x4*)ts, src_sorted, row_ptr[node], row_ptr[node + 1], lane);
    float di = dinv[node];
    f32x4 b4 = *(const f32x4*)&bias[lane * 4];
    f32x4 v = acc * di + b4;
#pragma unroll
    for (int j = 0; j < 4; ++j) v[j] = fmaxf(v[j], 0.f);
    *(f32x4*)&z[(long)node * 8 + lane * 4] = v;
}

// ---------------- decoder: out[k,e] = dot(z[s_e], z[d_e]) (identical across k) ----------------
__global__ __launch_bounds__(256) void decoder_kernel(const float* __restrict__ z,
                                                      const int* __restrict__ ei,
                                                      float* __restrict__ out,
                                                      int E, int K) {
    int e = blockIdx.x * blockDim.x + threadIdx.x;
    if (e >= E) return;
    int s = ei[e];
    int d = ei[E + e];
    const f32x4* zv = (const f32x4*)z;
    f32x4 a0 = zv[(long)s * 2], a1 = zv[(long)s * 2 + 1];
    f32x4 b0 = zv[(long)d * 2], b1 = zv[(long)d * 2 + 1];
    f32x4 p = a0 * b0 + a1 * b1;
    float acc = p[0] + p[1] + p[2] + p[3];
    for (int k = 0; k < K; k++) out[(long)k * E + e] = acc;
}

// ---------------- launch ----------------

extern "C" void kernel_launch(void* const* d_in, const int* in_sizes, int n_in,
                              void* d_out, int out_size, void* d_ws, size_t ws_size,
                              hipStream_t stream) {
    const float* x  = (const float*)d_in[0];
    const int*   ei = (const int*)d_in[1];
    const float* W1 = (const float*)d_in[3];
    const float* b1 = (const float*)d_in[4];
    const float* W2 = (const float*)d_in[5];
    const float* b2 = (const float*)d_in[6];
    const float* W3 = (const float*)d_in[7];
    const float* b3 = (const float*)d_in[8];
    const float* Wk = (const float*)d_in[9];
    const float* bk = (const float*)d_in[10];
    float* out = (float*)d_out;

    const int D1 = in_sizes[4];            // 256
    const int D2 = in_sizes[6];            // 128
    const int F  = in_sizes[3] / D1;       // 256
    const int N  = in_sizes[0] / F;        // 50000
    const int E  = in_sizes[1] / 2;        // 800000
    const int K  = out_size / E;           // 8
    const int M  = E + N;                  // edges incl self loops
    const int Mpad = (N + 127) & ~127;     // 50048

    size_t off = 0;
    auto alloc = [&](size_t bytes) -> void* {
        off = (off + 255) & ~(size_t)255;
        void* p = (char*)d_ws + off;
        off += bytes;
        return p;
    };
    int*   cnt        = (int*)alloc((size_t)N * sizeof(int));
    int*   row_ptr    = (int*)alloc((size_t)(N + 1) * sizeof(int));
    int*   cursor     = (int*)alloc((size_t)N * sizeof(int));
    int*   bsum       = (int*)alloc(1024 * sizeof(int));
    float* dinv       = (float*)alloc((size_t)N * sizeof(float));
    int*   src_sorted = (int*)alloc((size_t)M * sizeof(int));
    unsigned short* region_x = (unsigned short*)alloc((size_t)Mpad * 2 * F * sizeof(short));  // xs_pack -> h1s_pack (51.2MB)
    float* region_t   = (float*)alloc((size_t)Mpad * 256 * sizeof(float));                    // ts1/ts2 (as bf16)
    unsigned short* Wt1 = (unsigned short*)alloc((size_t)D1 * 3 * F * sizeof(short));
    unsigned short* Wt2 = (unsigned short*)alloc((size_t)D2 * 3 * D1 * sizeof(short));
    float* ts3        = (float*)alloc((size_t)Mpad * 32 * sizeof(float));
    float* tsk        = (float*)alloc((size_t)Mpad * 8 * sizeof(float));
    float* z          = (float*)alloc((size_t)Mpad * 8 * sizeof(float));
    (void)ws_size; (void)n_in;

    unsigned short* xs  = region_x;                   // packed A for GEMM1
    unsigned short* h1s = region_x;                   // packed A for GEMM2 (reuse after GEMM1)
    unsigned short* ts1 = (unsigned short*)region_t;  // [Mpad,256] bf16 row-major gather table
    unsigned short* ts2 = (unsigned short*)region_t;  // [Mpad,128] bf16 (ts1 consumed)

    int nbN = (N + THREADS - 1) / THREADS;
    int nbE = (E + THREADS - 1) / THREADS;

    // ---- graph prep ----
    init_cnt_kernel<<<nbN, THREADS, 0, stream>>>(cnt, N);
    count_edges_kernel<<<nbE, THREADS, 0, stream>>>(ei, cnt, E);
    scan_p1_kernel<<<nbN, THREADS, 0, stream>>>(cnt, bsum, N);
    scan_p2_kernel<<<1, 1024, 0, stream>>>(bsum, nbN);
    scan_p3_kernel<<<nbN, THREADS, 0, stream>>>(cnt, bsum, row_ptr, N);
    prep_fused_kernel<<<nbN, THREADS, 0, stream>>>(cnt, row_ptr, cursor, dinv, src_sorted, N);
    fill_edges_kernel<<<nbE, THREADS, 0, stream>>>(ei, cursor, src_sorted, E);

    // ---- conversions (fragment-linear packed) ----
    convert_x_pack_kernel<<<(int)(((long)N * 64 + 255) / 256), THREADS, 0, stream>>>(x, xs, N, F);
    convert_w_pack_kernel<<<(D1 * (3 * F / 8) + 255) / 256, THREADS, 0, stream>>>(W1, Wt1, F, D1);
    convert_w_pack_kernel<<<(D2 * (3 * D1 / 8) + 255) / 256, THREADS, 0, stream>>>(W2, Wt2, D1, D2);

    // ---- layer 1: ts1 = bf16(dinv .* (x @ W1)); agg (bf16 gather) -> h1s packed ----
    gemm_pack_kernel<256><<<Mpad / 64, THREADS, 0, stream>>>(xs, Wt1, dinv, ts1, N, D1);
    agg_split256_kernel<<<(N + 7) / 8, THREADS, 0, stream>>>(ts1, row_ptr, src_sorted, dinv, b1, h1s, N);

    // ---- layer 2: ts2 = bf16(dinv .* (h1 @ W2)); agg (bf16 gather) + fused W3 -> ts3 ----
    gemm_pack_kernel<128><<<Mpad / 64, THREADS, 0, stream>>>(h1s, Wt2, dinv, ts2, N, D2);
    agg_fused_w3_kernel<<<(N + 15) / 16, THREADS, 0, stream>>>(ts2, row_ptr, src_sorted, dinv, b2, W3, ts3, N);

    // ---- layer 3 agg + fused Wk (32 -> 8), then final agg ----
    agg_fused_wk_kernel<<<(N + 31) / 32, THREADS, 0, stream>>>(ts3, row_ptr, src_sorted, dinv, b3, Wk, tsk, N);
    agg_plain8_kernel<<<(N + 127) / 128, THREADS, 0, stream>>>(tsk, row_ptr, src_sorted, dinv, bk, z, N);

    // ---- decoder ----
    decoder_kernel<<<nbE, THREADS, 0, stream>>>(z, ei, out, E, K);
}

// Round 14
// 333.977 us; speedup vs baseline: 1.6303x; 1.0904x over previous
//
#include <hip/hip_runtime.h>
#include <hip/hip_bf16.h>

#define THREADS 256

typedef __attribute__((ext_vector_type(2))) float f32x2;
typedef __attribute__((ext_vector_type(4))) float f32x4;
typedef __attribute__((ext_vector_type(8))) float f32x8;
typedef __attribute__((ext_vector_type(8))) short short8;
typedef __attribute__((ext_vector_type(4))) unsigned short u16x4;
typedef __attribute__((ext_vector_type(8))) unsigned short u16x8;

__device__ inline unsigned short f2bf(float f) {
    unsigned int u = __builtin_bit_cast(unsigned int, f);
    unsigned int r = (u + 0x7FFFu + ((u >> 16) & 1u)) >> 16;
    return (unsigned short)r;
}
__device__ inline float bf2f(unsigned short h) {
    unsigned int u = ((unsigned int)h) << 16;
    return __builtin_bit_cast(float, u);
}
__device__ __forceinline__ f32x8 bfv8(u16x8 v) {
    f32x8 r;
#pragma unroll
    for (int j = 0; j < 8; ++j) r[j] = bf2f(v[j]);
    return r;
}

// ---------------- graph preprocessing ----------------

__global__ __launch_bounds__(256) void init_cnt_kernel(int* cnt, int n) {
    int i = blockIdx.x * blockDim.x + threadIdx.x;
    if (i < n) cnt[i] = 1;   // self loop
}

__global__ __launch_bounds__(256) void count_edges_kernel(const int* ei, int* cnt, int E) {
    int e = blockIdx.x * blockDim.x + threadIdx.x;
    if (e < E) atomicAdd(&cnt[ei[E + e]], 1);   // dst row
}

// ---------------- 3-phase multi-block exclusive scan (coalesced) ----------------
__global__ __launch_bounds__(256) void scan_p1_kernel(const int* __restrict__ cnt,
                                                      int* __restrict__ bsum, int n) {
    __shared__ int sh[256];
    int i = blockIdx.x * 256 + threadIdx.x;
    int v = (i < n) ? cnt[i] : 0;
    sh[threadIdx.x] = v;
    __syncthreads();
#pragma unroll
    for (int off = 128; off > 0; off >>= 1) {
        if ((int)threadIdx.x < off) sh[threadIdx.x] += sh[threadIdx.x + off];
        __syncthreads();
    }
    if (threadIdx.x == 0) bsum[blockIdx.x] = sh[0];
}

__global__ __launch_bounds__(1024) void scan_p2_kernel(int* __restrict__ bsum, int nb) {
    __shared__ int sh[1024];
    int v = ((int)threadIdx.x < nb) ? bsum[threadIdx.x] : 0;
    sh[threadIdx.x] = v;
    __syncthreads();
    for (int off = 1; off < 1024; off <<= 1) {
        int t = (threadIdx.x >= (unsigned)off) ? sh[threadIdx.x - off] : 0;
        __syncthreads();
        sh[threadIdx.x] += t;
        __syncthreads();
    }
    if ((int)threadIdx.x < nb) bsum[threadIdx.x] = sh[threadIdx.x] - v;   // exclusive
}

__global__ __launch_bounds__(256) void scan_p3_kernel(const int* __restrict__ cnt,
                                                      const int* __restrict__ bsum,
                                                      int* __restrict__ row_ptr, int n) {
    __shared__ int sh[256];
    int i = blockIdx.x * 256 + threadIdx.x;
    int v = (i < n) ? cnt[i] : 0;
    sh[threadIdx.x] = v;
    __syncthreads();
    for (int off = 1; off < 256; off <<= 1) {
        int t = (threadIdx.x >= (unsigned)off) ? sh[threadIdx.x - off] : 0;
        __syncthreads();
        sh[threadIdx.x] += t;
        __syncthreads();
    }
    int excl = sh[threadIdx.x] - v + bsum[blockIdx.x];
    if (i < n) row_ptr[i] = excl;
    if (i == n - 1) row_ptr[n] = excl + v;
}

// dinv + self-fill + cursor init in one pass
__global__ __launch_bounds__(256) void prep_fused_kernel(const int* cnt, const int* row_ptr,
                                                         int* cursor, float* dinv,
                                                         int* src_sorted, int n) {
    int i = blockIdx.x * blockDim.x + threadIdx.x;
    if (i < n) {
        dinv[i] = rsqrtf((float)cnt[i]);
        int p = row_ptr[i];
        src_sorted[p] = i;     // self loop first (deterministic slot)
        cursor[i] = p + 1;
    }
}

__global__ __launch_bounds__(256) void fill_edges_kernel(const int* ei, int* cursor, int* src_sorted, int E) {
    int e = blockIdx.x * blockDim.x + threadIdx.x;
    if (e < E) {
        int s = ei[e];
        int d = ei[E + e];
        int pos = atomicAdd(&cursor[d], 1);
        src_sorted[pos] = s;
    }
}

// ---------------- fragment-linear packed conversions ----------------
// Packed A layout (KA=512 phys = [hi(256)|lo(256)]): chunk(row,kp8) at
// ((row/16)*16 + kp/32)*64 + ((kp%32)/8)*16 + row%16, 8 bf16 per chunk.
__global__ __launch_bounds__(256) void convert_x_pack_kernel(const float* __restrict__ x,
                                                             unsigned short* __restrict__ Ap,
                                                             int n, int F) {
    long idx = (long)blockIdx.x * 256 + threadIdx.x;
    if (idx >= (long)n * 64) return;
    int row = (int)(idx >> 6), ck = (int)(idx & 63);
    int kp = ck * 8;
    bool ishi = kp < 256;
    const float* src = &x[(long)row * F + (kp & 255)];
    f32x4 v0 = *(const f32x4*)src;
    f32x4 v1 = *(const f32x4*)(src + 4);
    u16x8 o;
#pragma unroll
    for (int j = 0; j < 4; ++j) {
        unsigned short h0 = f2bf(v0[j]);
        unsigned short h1 = f2bf(v1[j]);
        o[j]     = ishi ? h0 : f2bf(v0[j] - bf2f(h0));
        o[j + 4] = ishi ? h1 : f2bf(v1[j] - bf2f(h1));
    }
    size_t chunk = ((size_t)(row >> 4) * 16 + (ck >> 2)) * 64 + (ck & 3) * 16 + (row & 15);
    *(u16x8*)&Ap[chunk * 8] = o;
}

// W [K,N] f32 -> packed B = hi(W) only, K rows, fragment-linear:
// chunk(col,kp8) at ((col/16)*(K/32) + kp/32)*64 + ((kp%32)/8)*16 + col%16.
__global__ __launch_bounds__(256) void convert_w_hi_kernel(const float* __restrict__ W,
                                                           unsigned short* __restrict__ Bp,
                                                           int K, int N) {
    int cpc = K / 8;                       // chunks per column
    int idx = blockIdx.x * 256 + threadIdx.x;
    if (idx >= N * cpc) return;
    int n = idx / cpc, ck = idx % cpc;
    int c = ck * 8;
    u16x8 o;
#pragma unroll
    for (int j = 0; j < 8; ++j) o[j] = f2bf(W[(long)(c + j) * N + n]);
    size_t chunk = ((size_t)(n >> 4) * (K / 32) + (ck >> 2)) * 64 + (ck & 3) * 16 + (n & 15);
    *(u16x8*)&Bp[chunk * 8] = o;
}

// ---------------- MFMA bf16 GEMM, packed-operand register-direct ----------------
// C = (A_hi + A_lo) @ B_hi: A phys 512 k ([hi|lo], 16 kg), B = W_hi (256 k, 8 kg).
// Each B fragment loaded ONCE and used by both A_hi and A_lo MFMAs.
// No LDS, no barriers, coalesced fragment loads (chunk l at base+l*16B).
template <int BN>
__global__ __launch_bounds__(256) void gemm_pack_kernel(const unsigned short* __restrict__ Ap,
                                                        const unsigned short* __restrict__ Bp,
                                                        const float* __restrict__ dinv,
                                                        unsigned short* __restrict__ C,
                                                        int M, int N) {
    constexpr int NI = BN / 32;            // col-tiles per wave
    const int tid = threadIdx.x;
    const int wave = tid >> 6, l = tid & 63;
    const int wm = wave & 1, wn = wave >> 1;
    const int lr = l & 15, lg = l >> 4;
    const int rt0 = blockIdx.x * 4 + wm * 2;
    const int ct0 = wn * NI;
    const short8* ab = (const short8*)Ap + (size_t)rt0 * 1024 + l;   // 16 kg * 64 chunks per rtile
    const short8* bb = (const short8*)Bp + (size_t)ct0 * 512 + l;    // 8 kg * 64 chunks per ctile
    f32x4 acc[2][NI] = {};
#pragma unroll
    for (int kgb = 0; kgb < 8; ++kgb) {
        short8 b[NI], ah[2], al[2];
#pragma unroll
        for (int ni = 0; ni < NI; ++ni)
            b[ni] = bb[((size_t)ni * 8 + kgb) * 64];
#pragma unroll
        for (int i = 0; i < 2; ++i) {
            ah[i] = ab[((size_t)i * 16 + kgb) * 64];
            al[i] = ab[((size_t)i * 16 + 8 + kgb) * 64];
        }
#pragma unroll
        for (int i = 0; i < 2; ++i)
#pragma unroll
            for (int ni = 0; ni < NI; ++ni)
                acc[i][ni] = __builtin_amdgcn_mfma_f32_16x16x32_bf16(ah[i], b[ni], acc[i][ni], 0, 0, 0);
#pragma unroll
        for (int i = 0; i < 2; ++i)
#pragma unroll
            for (int ni = 0; ni < NI; ++ni)
                acc[i][ni] = __builtin_amdgcn_mfma_f32_16x16x32_bf16(al[i], b[ni], acc[i][ni], 0, 0, 0);
    }
#pragma unroll
    for (int i = 0; i < 2; ++i) {
        int rbase = blockIdx.x * 64 + (wm * 2 + i) * 16 + lg * 4;
#pragma unroll
        for (int ni = 0; ni < NI; ++ni) {
            int col = wn * (BN / 2) + ni * 16 + lr;
#pragma unroll
            for (int r = 0; r < 4; ++r) {
                int row = rbase + r;
                if (row < M) C[(long)row * N + col] = f2bf(acc[i][ni][r] * dinv[row]);
            }
        }
    }
}

// ---------------- bf16 gather core: 8-deep unroll, u16x8 (16B) per lane ----------------
template <int R8>   // row stride in u16x8 units
__device__ __forceinline__ f32x8 gather_sum_bf(const u16x8* __restrict__ base,
                                               const int* __restrict__ src,
                                               int beg, int end) {
    f32x8 acc = {0.f, 0.f, 0.f, 0.f, 0.f, 0.f, 0.f, 0.f};
    int e = beg;
    for (; e + 8 <= end; e += 8) {
        u16x8 v0 = base[(long)src[e] * R8],     v1 = base[(long)src[e + 1] * R8];
        u16x8 v2 = base[(long)src[e + 2] * R8], v3 = base[(long)src[e + 3] * R8];
        u16x8 v4 = base[(long)src[e + 4] * R8], v5 = base[(long)src[e + 5] * R8];
        u16x8 v6 = base[(long)src[e + 6] * R8], v7 = base[(long)src[e + 7] * R8];
        acc += ((bfv8(v0) + bfv8(v1)) + (bfv8(v2) + bfv8(v3)))
             + ((bfv8(v4) + bfv8(v5)) + (bfv8(v6) + bfv8(v7)));
    }
    for (; e < end; ++e) acc += bfv8(base[(long)src[e] * R8]);
    return acc;
}

// ---------------- f32 gather core (layers 3/4) ----------------
template <int G>
__device__ __forceinline__ f32x4 gather_sum(const f32x4* __restrict__ tsv,
                                            const int* __restrict__ src,
                                            int beg, int end, int lane) {
    f32x4 acc = {0.f, 0.f, 0.f, 0.f};
    int e = beg;
    for (; e + 8 <= end; e += 8) {
        int s0 = src[e], s1 = src[e + 1], s2 = src[e + 2], s3 = src[e + 3];
        int s4 = src[e + 4], s5 = src[e + 5], s6 = src[e + 6], s7 = src[e + 7];
        f32x4 v0 = tsv[(long)s0 * G + lane], v1 = tsv[(long)s1 * G + lane];
        f32x4 v2 = tsv[(long)s2 * G + lane], v3 = tsv[(long)s3 * G + lane];
        f32x4 v4 = tsv[(long)s4 * G + lane], v5 = tsv[(long)s5 * G + lane];
        f32x4 v6 = tsv[(long)s6 * G + lane], v7 = tsv[(long)s7 * G + lane];
        acc += ((v0 + v1) + (v2 + v3)) + ((v4 + v5) + (v6 + v7));
    }
    for (; e + 2 <= end; e += 2) {
        int s0 = src[e], s1 = src[e + 1];
        acc += tsv[(long)s0 * G + lane] + tsv[(long)s1 * G + lane];
    }
    if (e < end) acc += tsv[(long)src[e] * G + lane];
    return acc;
}

// D=256 bf16 gather: h1 = relu(dinv*sum + b1) -> PACKED bf16 [hi|lo] write (KA=512 layout)
__global__ __launch_bounds__(256) void agg_split256_kernel(const unsigned short* __restrict__ ts,
                                                           const int* __restrict__ row_ptr,
                                                           const int* __restrict__ src_sorted,
                                                           const float* __restrict__ dinv,
                                                           const float* __restrict__ bias,
                                                           unsigned short* __restrict__ out_p,
                                                           int n) {
    int g = threadIdx.x >> 5, lane = threadIdx.x & 31;   // 8 nodes/block, 32 lanes/node
    int node = blockIdx.x * 8 + g;
    if (node >= n) return;
    const u16x8* base = (const u16x8*)ts + lane;         // row stride 32 chunks
    f32x8 acc = gather_sum_bf<32>(base, src_sorted, row_ptr[node], row_ptr[node + 1]);
    float di = dinv[node];
    f32x8 b8 = *(const f32x8*)&bias[lane * 8];
    f32x8 v = acc * di + b8;
    u16x8 hi, lo;
#pragma unroll
    for (int j = 0; j < 8; ++j) {
        float r = fmaxf(v[j], 0.f);
        hi[j] = f2bf(r);
        lo[j] = f2bf(r - bf2f(hi[j]));
    }
    // packed: hi chunk kg=lane/4 in [0,8), lo chunk kg=8+lane/4
    size_t tilebase = (size_t)(node >> 4) * 1024 + (lane & 3) * 16 + (node & 15);
    *(u16x8*)&out_p[(tilebase + (size_t)(lane >> 2) * 64) * 8] = hi;
    *(u16x8*)&out_p[(tilebase + (size_t)(8 + (lane >> 2)) * 64) * 8] = lo;
}

// D=128 bf16 gather + fused W3 matvec: ts3[node] = dinv * (relu(dinv*sum+b2) @ W3)  (128 -> 32)
__global__ __launch_bounds__(256) void agg_fused_w3_kernel(const unsigned short* __restrict__ ts,
                                                           const int* __restrict__ row_ptr,
                                                           const int* __restrict__ src_sorted,
                                                           const float* __restrict__ dinv,
                                                           const float* __restrict__ bias,
                                                           const float* __restrict__ W3,
                                                           float* __restrict__ ts3, int n) {
    __shared__ float W3s[128 * 32];
    __shared__ float hbuf[16][132];   // +4 pad: spreads per-node broadcast reads across banks
    for (int i = threadIdx.x; i < 128 * 32; i += 256) W3s[i] = W3[i];
    __syncthreads();
    int g = threadIdx.x >> 4, lane = threadIdx.x & 15;   // 16 nodes/block, 16 lanes/node
    int node = blockIdx.x * 16 + g;
    if (node >= n) return;
    const u16x8* base = (const u16x8*)ts + lane;         // row stride 16 chunks
    f32x8 acc = gather_sum_bf<16>(base, src_sorted, row_ptr[node], row_ptr[node + 1]);
    float di = dinv[node];
    f32x8 b8 = *(const f32x8*)&bias[lane * 8];
    f32x8 v = acc * di + b8;
#pragma unroll
    for (int j = 0; j < 8; ++j) v[j] = fmaxf(v[j], 0.f);
    f32x4 vlo = {v[0], v[1], v[2], v[3]};
    f32x4 vhi = {v[4], v[5], v[6], v[7]};
    *(f32x4*)&hbuf[g][lane * 8] = vlo;        // same-wave DS: in-order, no barrier needed
    *(f32x4*)&hbuf[g][lane * 8 + 4] = vhi;
    int c0 = lane * 2;
    float aj0 = 0.f, aj1 = 0.f;
#pragma unroll
    for (int k = 0; k < 128; k += 4) {
        f32x4 hv = *(const f32x4*)&hbuf[g][k];
        aj0 += hv[0] * W3s[k * 32 + c0] + hv[1] * W3s[(k + 1) * 32 + c0]
             + hv[2] * W3s[(k + 2) * 32 + c0] + hv[3] * W3s[(k + 3) * 32 + c0];
        aj1 += hv[0] * W3s[k * 32 + c0 + 1] + hv[1] * W3s[(k + 1) * 32 + c0 + 1]
             + hv[2] * W3s[(k + 2) * 32 + c0 + 1] + hv[3] * W3s[(k + 3) * 32 + c0 + 1];
    }
    f32x2 o = {aj0 * di, aj1 * di};
    *(f32x2*)&ts3[(long)node * 32 + c0] = o;
}

// D=32 agg + fused Wk matvec: tsk[node] = dinv * (relu(dinv*sum+b3) @ Wk)    (32 -> 8)
__global__ __launch_bounds__(256) void agg_fused_wk_kernel(const float* __restrict__ ts,
                                                           const int* __restrict__ row_ptr,
                                                           const int* __restrict__ src_sorted,
                                                           const float* __restrict__ dinv,
                                                           const float* __restrict__ bias,
                                                           const float* __restrict__ Wk,
                                                           float* __restrict__ tsk, int n) {
    __shared__ float Wks[32 * 8];
    __shared__ float hbuf[32][36];   // +4 pad
    for (int i = threadIdx.x; i < 32 * 8; i += 256) Wks[i] = Wk[i];
    __syncthreads();
    int g = threadIdx.x >> 3, lane = threadIdx.x & 7;
    int node = blockIdx.x * 32 + g;
    if (node >= n) return;
    f32x4 acc = gather_sum<8>((const f32x4*)ts, src_sorted, row_ptr[node], row_ptr[node + 1], lane);
    float di = dinv[node];
    f32x4 b4 = *(const f32x4*)&bias[lane * 4];
    f32x4 v = acc * di + b4;
#pragma unroll
    for (int j = 0; j < 4; ++j) v[j] = fmaxf(v[j], 0.f);
    *(f32x4*)&hbuf[g][lane * 4] = v;
    float aj = 0.f;
#pragma unroll
    for (int k = 0; k < 32; k += 4) {
        f32x4 hv = *(const f32x4*)&hbuf[g][k];
        aj += hv[0] * Wks[k * 8 + lane] + hv[1] * Wks[(k + 1) * 8 + lane]
            + hv[2] * Wks[(k + 2) * 8 + lane] + hv[3] * Wks[(k + 3) * 8 + lane];
    }
    tsk[(long)node * 8 + lane] = aj * di;
}

// D=8: z = relu(dinv*sum + bk)
__global__ __launch_bounds__(256) void agg_plain8_kernel(const float* __restrict__ ts,
                                                         const int* __restrict__ row_ptr,
                                                         const int* __restrict__ src_sorted,
                                                         const float* __restrict__ dinv,
                                                         const float* __restrict__ bias,
                                                         float* __restrict__ z, int n) {
    int g = threadIdx.x >> 1, lane = threadIdx.x & 1;
    int node = blockIdx.x * 128 + g;
    if (node >= n) return;
    f32x4 acc = gather_sum<2>((const f32x4*)ts, src_sorted, row_ptr[node], row_ptr[node + 1], lane);
    float di = dinv[node];
    f32x4 b4 = *(const f32x4*)&bias[lane * 4];
    f32x4 v = acc * di + b4;
#pragma unroll
    for (int j = 0; j < 4; ++j) v[j] = fmaxf(v[j], 0.f);
    *(f32x4*)&z[(long)node * 8 + lane * 4] = v;
}

// ---------------- decoder: out[k,e] = dot(z[s_e], z[d_e]) (identical across k) ----------------
__global__ __launch_bounds__(256) void decoder_kernel(const float* __restrict__ z,
                                                      const int* __restrict__ ei,
                                                      float* __restrict__ out,
                                                      int E, int K) {
    int e = blockIdx.x * blockDim.x + threadIdx.x;
    if (e >= E) return;
    int s = ei[e];
    int d = ei[E + e];
    const f32x4* zv = (const f32x4*)z;
    f32x4 a0 = zv[(long)s * 2], a1 = zv[(long)s * 2 + 1];
    f32x4 b0 = zv[(long)d * 2], b1 = zv[(long)d * 2 + 1];
    f32x4 p = a0 * b0 + a1 * b1;
    float acc = p[0] + p[1] + p[2] + p[3];
    for (int k = 0; k < K; k++) out[(long)k * E + e] = acc;
}

// ---------------- launch ----------------

extern "C" void kernel_launch(void* const* d_in, const int* in_sizes, int n_in,
                              void* d_out, int out_size, void* d_ws, size_t ws_size,
                              hipStream_t stream) {
    const float* x  = (const float*)d_in[0];
    const int*   ei = (const int*)d_in[1];
    const float* W1 = (const float*)d_in[3];
    const float* b1 = (const float*)d_in[4];
    const float* W2 = (const float*)d_in[5];
    const float* b2 = (const float*)d_in[6];
    const float* W3 = (const float*)d_in[7];
    const float* b3 = (const float*)d_in[8];
    const float* Wk = (const float*)d_in[9];
    const float* bk = (const float*)d_in[10];
    float* out = (float*)d_out;

    const int D1 = in_sizes[4];            // 256
    const int D2 = in_sizes[6];            // 128
    const int F  = in_sizes[3] / D1;       // 256
    const int N  = in_sizes[0] / F;        // 50000
    const int E  = in_sizes[1] / 2;        // 800000
    const int K  = out_size / E;           // 8
    const int M  = E + N;                  // edges incl self loops
    const int Mpad = (N + 127) & ~127;     // 50048

    size_t off = 0;
    auto alloc = [&](size_t bytes) -> void* {
        off = (off + 255) & ~(size_t)255;
        void* p = (char*)d_ws + off;
        off += bytes;
        return p;
    };
    int*   cnt        = (int*)alloc((size_t)N * sizeof(int));
    int*   row_ptr    = (int*)alloc((size_t)(N + 1) * sizeof(int));
    int*   cursor     = (int*)alloc((size_t)N * sizeof(int));
    int*   bsum       = (int*)alloc(1024 * sizeof(int));
    float* dinv       = (float*)alloc((size_t)N * sizeof(float));
    int*   src_sorted = (int*)alloc((size_t)M * sizeof(int));
    unsigned short* region_x = (unsigned short*)alloc((size_t)Mpad * 2 * F * sizeof(short));  // xs_pack -> h1s_pack (51.2MB)
    float* region_t   = (float*)alloc((size_t)Mpad * 256 * sizeof(float));                    // ts1/ts2 (as bf16)
    unsigned short* Wt1 = (unsigned short*)alloc((size_t)D1 * F * sizeof(short));             // W1_hi packed (131KB)
    unsigned short* Wt2 = (unsigned short*)alloc((size_t)D2 * D1 * sizeof(short));            // W2_hi packed (65KB)
    float* ts3        = (float*)alloc((size_t)Mpad * 32 * sizeof(float));
    float* tsk        = (float*)alloc((size_t)Mpad * 8 * sizeof(float));
    float* z          = (float*)alloc((size_t)Mpad * 8 * sizeof(float));
    (void)ws_size; (void)n_in;

    unsigned short* xs  = region_x;                   // packed A for GEMM1
    unsigned short* h1s = region_x;                   // packed A for GEMM2 (reuse after GEMM1)
    unsigned short* ts1 = (unsigned short*)region_t;  // [Mpad,256] bf16 row-major gather table
    unsigned short* ts2 = (unsigned short*)region_t;  // [Mpad,128] bf16 (ts1 consumed)

    int nbN = (N + THREADS - 1) / THREADS;
    int nbE = (E + THREADS - 1) / THREADS;

    // ---- graph prep ----
    init_cnt_kernel<<<nbN, THREADS, 0, stream>>>(cnt, N);
    count_edges_kernel<<<nbE, THREADS, 0, stream>>>(ei, cnt, E);
    scan_p1_kernel<<<nbN, THREADS, 0, stream>>>(cnt, bsum, N);
    scan_p2_kernel<<<1, 1024, 0, stream>>>(bsum, nbN);
    scan_p3_kernel<<<nbN, THREADS, 0, stream>>>(cnt, bsum, row_ptr, N);
    prep_fused_kernel<<<nbN, THREADS, 0, stream>>>(cnt, row_ptr, cursor, dinv, src_sorted, N);
    fill_edges_kernel<<<nbE, THREADS, 0, stream>>>(ei, cursor, src_sorted, E);

    // ---- conversions (fragment-linear packed; B = hi(W) only) ----
    convert_x_pack_kernel<<<(int)(((long)N * 64 + 255) / 256), THREADS, 0, stream>>>(x, xs, N, F);
    convert_w_hi_kernel<<<(D1 * (F / 8) + 255) / 256, THREADS, 0, stream>>>(W1, Wt1, F, D1);
    convert_w_hi_kernel<<<(D2 * (D1 / 8) + 255) / 256, THREADS, 0, stream>>>(W2, Wt2, D1, D2);

    // ---- layer 1: ts1 = bf16(dinv .* (x @ W1)); agg (bf16 gather) -> h1s packed ----
    gemm_pack_kernel<256><<<Mpad / 64, THREADS, 0, stream>>>(xs, Wt1, dinv, ts1, N, D1);
    agg_split256_kernel<<<(N + 7) / 8, THREADS, 0, stream>>>(ts1, row_ptr, src_sorted, dinv, b1, h1s, N);

    // ---- layer 2: ts2 = bf16(dinv .* (h1 @ W2)); agg (bf16 gather) + fused W3 -> ts3 ----
    gemm_pack_kernel<128><<<Mpad / 64, THREADS, 0, stream>>>(h1s, Wt2, dinv, ts2, N, D2);
    agg_fused_w3_kernel<<<(N + 15) / 16, THREADS, 0, stream>>>(ts2, row_ptr, src_sorted, dinv, b2, W3, ts3, N);

    // ---- layer 3 agg + fused Wk (32 -> 8), then final agg ----
    agg_fused_wk_kernel<<<(N + 31) / 32, THREADS, 0, stream>>>(ts3, row_ptr, src_sorted, dinv, b3, Wk, tsk, N);
    agg_plain8_kernel<<<(N + 127) / 128, THREADS, 0, stream>>>(tsk, row_ptr, src_sorted, dinv, bk, z, N);

    // ---- decoder ----
    decoder_kernel<<<nbE, THREADS, 0, stream>>>(z, ei, out, E, K);
}

// Round 15
// 324.513 us; speedup vs baseline: 1.6778x; 1.0292x over previous
//
#include <hip/hip_runtime.h>
#include <hip/hip_bf16.h>

#define THREADS 256

typedef __attribute__((ext_vector_type(2))) float f32x2;
typedef __attribute__((ext_vector_type(4))) float f32x4;
typedef __attribute__((ext_vector_type(8))) float f32x8;
typedef __attribute__((ext_vector_type(8))) short short8;
typedef __attribute__((ext_vector_type(4))) unsigned short u16x4;
typedef __attribute__((ext_vector_type(8))) unsigned short u16x8;

__device__ inline unsigned short f2bf(float f) {
    unsigned int u = __builtin_bit_cast(unsigned int, f);
    unsigned int r = (u + 0x7FFFu + ((u >> 16) & 1u)) >> 16;
    return (unsigned short)r;
}
__device__ inline float bf2f(unsigned short h) {
    unsigned int u = ((unsigned int)h) << 16;
    return __builtin_bit_cast(float, u);
}
__device__ __forceinline__ f32x8 bfv8(u16x8 v) {
    f32x8 r;
#pragma unroll
    for (int j = 0; j < 8; ++j) r[j] = bf2f(v[j]);
    return r;
}
__device__ __forceinline__ f32x4 bfv4(u16x4 v) {
    f32x4 r;
#pragma unroll
    for (int j = 0; j < 4; ++j) r[j] = bf2f(v[j]);
    return r;
}

// ---------------- graph preprocessing ----------------

__global__ __launch_bounds__(256) void init_cnt_kernel(int* cnt, int n) {
    int i = blockIdx.x * blockDim.x + threadIdx.x;
    if (i < n) cnt[i] = 1;   // self loop
}

__global__ __launch_bounds__(256) void count_edges_kernel(const int* ei, int* cnt, int E) {
    int e = blockIdx.x * blockDim.x + threadIdx.x;
    if (e < E) atomicAdd(&cnt[ei[E + e]], 1);   // dst row
}

// ---------------- 3-phase multi-block exclusive scan (coalesced) ----------------
__global__ __launch_bounds__(256) void scan_p1_kernel(const int* __restrict__ cnt,
                                                      int* __restrict__ bsum, int n) {
    __shared__ int sh[256];
    int i = blockIdx.x * 256 + threadIdx.x;
    int v = (i < n) ? cnt[i] : 0;
    sh[threadIdx.x] = v;
    __syncthreads();
#pragma unroll
    for (int off = 128; off > 0; off >>= 1) {
        if ((int)threadIdx.x < off) sh[threadIdx.x] += sh[threadIdx.x + off];
        __syncthreads();
    }
    if (threadIdx.x == 0) bsum[blockIdx.x] = sh[0];
}

__global__ __launch_bounds__(1024) void scan_p2_kernel(int* __restrict__ bsum, int nb) {
    __shared__ int sh[1024];
    int v = ((int)threadIdx.x < nb) ? bsum[threadIdx.x] : 0;
    sh[threadIdx.x] = v;
    __syncthreads();
    for (int off = 1; off < 1024; off <<= 1) {
        int t = (threadIdx.x >= (unsigned)off) ? sh[threadIdx.x - off] : 0;
        __syncthreads();
        sh[threadIdx.x] += t;
        __syncthreads();
    }
    if ((int)threadIdx.x < nb) bsum[threadIdx.x] = sh[threadIdx.x] - v;   // exclusive
}

__global__ __launch_bounds__(256) void scan_p3_kernel(const int* __restrict__ cnt,
                                                      const int* __restrict__ bsum,
                                                      int* __restrict__ row_ptr, int n) {
    __shared__ int sh[256];
    int i = blockIdx.x * 256 + threadIdx.x;
    int v = (i < n) ? cnt[i] : 0;
    sh[threadIdx.x] = v;
    __syncthreads();
    for (int off = 1; off < 256; off <<= 1) {
        int t = (threadIdx.x >= (unsigned)off) ? sh[threadIdx.x - off] : 0;
        __syncthreads();
        sh[threadIdx.x] += t;
        __syncthreads();
    }
    int excl = sh[threadIdx.x] - v + bsum[blockIdx.x];
    if (i < n) row_ptr[i] = excl;
    if (i == n - 1) row_ptr[n] = excl + v;
}

// dinv + self-fill + cursor init in one pass
__global__ __launch_bounds__(256) void prep_fused_kernel(const int* cnt, const int* row_ptr,
                                                         int* cursor, float* dinv,
                                                         int* src_sorted, int n) {
    int i = blockIdx.x * blockDim.x + threadIdx.x;
    if (i < n) {
        dinv[i] = rsqrtf((float)cnt[i]);
        int p = row_ptr[i];
        src_sorted[p] = i;     // self loop first (deterministic slot)
        cursor[i] = p + 1;
    }
}

__global__ __launch_bounds__(256) void fill_edges_kernel(const int* ei, int* cursor, int* src_sorted, int E) {
    int e = blockIdx.x * blockDim.x + threadIdx.x;
    if (e < E) {
        int s = ei[e];
        int d = ei[E + e];
        int pos = atomicAdd(&cursor[d], 1);
        src_sorted[pos] = s;
    }
}

// ---------------- fragment-linear packed conversions (layout v2) ----------------
// Packed A (KA=512 phys = 16 kg of 32 k): chunk(row,kg,ks) at
// rtile*1024 + kg*64 + row*4 + ks (8 bf16 = k ascending). Node's row is
// line-contiguous per kg (coalesced agg writes); GEMM lane l reads chunk
// rt*1024 + kg*64 + (l&15)*4 + (l>>4) — a permutation within the same 1KB
// block, fully coalesced.
__global__ __launch_bounds__(256) void convert_x_pack_kernel(const float* __restrict__ x,
                                                             unsigned short* __restrict__ Ap,
                                                             int n, int F) {
    long idx = (long)blockIdx.x * 256 + threadIdx.x;
    if (idx >= (long)n * 64) return;
    int row = (int)(idx >> 6), c = (int)(idx & 63);
    int kg = c >> 2, ks = c & 3;
    bool ishi = kg < 8;
    int klocal = (kg & 7) * 32 + ks * 8;
    const float* src = &x[(long)row * F + klocal];
    f32x4 v0 = *(const f32x4*)src;
    f32x4 v1 = *(const f32x4*)(src + 4);
    u16x8 o;
#pragma unroll
    for (int j = 0; j < 4; ++j) {
        unsigned short h0 = f2bf(v0[j]);
        unsigned short h1 = f2bf(v1[j]);
        o[j]     = ishi ? h0 : f2bf(v0[j] - bf2f(h0));
        o[j + 4] = ishi ? h1 : f2bf(v1[j] - bf2f(h1));
    }
    size_t chunk = (size_t)(row >> 4) * 1024 + (size_t)kg * 64 + (row & 15) * 4 + ks;
    *(u16x8*)&Ap[chunk * 8] = o;
}

// W [K,N] f32 -> packed B = hi(W) only, fragment-linear (lane-linear layout kept).
__global__ __launch_bounds__(256) void convert_w_hi_kernel(const float* __restrict__ W,
                                                           unsigned short* __restrict__ Bp,
                                                           int K, int N) {
    int cpc = K / 8;                       // chunks per column
    int idx = blockIdx.x * 256 + threadIdx.x;
    if (idx >= N * cpc) return;
    int n = idx / cpc, ck = idx % cpc;
    int c = ck * 8;
    u16x8 o;
#pragma unroll
    for (int j = 0; j < 8; ++j) o[j] = f2bf(W[(long)(c + j) * N + n]);
    size_t chunk = ((size_t)(n >> 4) * (K / 32) + (ck >> 2)) * 64 + (ck & 3) * 16 + (n & 15);
    *(u16x8*)&Bp[chunk * 8] = o;
}

// ---------------- MFMA bf16 GEMM, packed-operand register-direct ----------------
// C = (A_hi + A_lo) @ B_hi. A layout v2; B lane-linear. No LDS, no barriers.
template <int BN>
__global__ __launch_bounds__(256) void gemm_pack_kernel(const unsigned short* __restrict__ Ap,
                                                        const unsigned short* __restrict__ Bp,
                                                        const float* __restrict__ dinv,
                                                        unsigned short* __restrict__ C,
                                                        int M, int N) {
    constexpr int NI = BN / 32;            // col-tiles per wave
    const int tid = threadIdx.x;
    const int wave = tid >> 6, l = tid & 63;
    const int wm = wave & 1, wn = wave >> 1;
    const int lr = l & 15, lg = l >> 4;
    const int rt0 = blockIdx.x * 4 + wm * 2;
    const int ct0 = wn * NI;
    const short8* ab = (const short8*)Ap + (size_t)rt0 * 1024 + lr * 4 + lg;  // layout v2
    const short8* bb = (const short8*)Bp + (size_t)ct0 * 512 + l;             // 8 kg * 64 chunks per ctile
    f32x4 acc[2][NI] = {};
#pragma unroll
    for (int kgb = 0; kgb < 8; ++kgb) {
        short8 b[NI], ah[2], al[2];
#pragma unroll
        for (int ni = 0; ni < NI; ++ni)
            b[ni] = bb[((size_t)ni * 8 + kgb) * 64];
#pragma unroll
        for (int i = 0; i < 2; ++i) {
            ah[i] = ab[((size_t)i * 16 + kgb) * 64];
            al[i] = ab[((size_t)i * 16 + 8 + kgb) * 64];
        }
#pragma unroll
        for (int i = 0; i < 2; ++i)
#pragma unroll
            for (int ni = 0; ni < NI; ++ni)
                acc[i][ni] = __builtin_amdgcn_mfma_f32_16x16x32_bf16(ah[i], b[ni], acc[i][ni], 0, 0, 0);
#pragma unroll
        for (int i = 0; i < 2; ++i)
#pragma unroll
            for (int ni = 0; ni < NI; ++ni)
                acc[i][ni] = __builtin_amdgcn_mfma_f32_16x16x32_bf16(al[i], b[ni], acc[i][ni], 0, 0, 0);
    }
#pragma unroll
    for (int i = 0; i < 2; ++i) {
        int rbase = blockIdx.x * 64 + (wm * 2 + i) * 16 + lg * 4;
#pragma unroll
        for (int ni = 0; ni < NI; ++ni) {
            int col = wn * (BN / 2) + ni * 16 + lr;
#pragma unroll
            for (int r = 0; r < 4; ++r) {
                int row = rbase + r;
                if (row < M) C[(long)row * N + col] = f2bf(acc[i][ni][r] * dinv[row]);
            }
        }
    }
}

// ---------------- bf16 gather cores ----------------
// u16x4 per lane (full-wave-per-node), 16-deep unroll.
template <int R4>   // row stride in u16x4 units
__device__ __forceinline__ f32x4 gather_sum_bf4(const u16x4* __restrict__ base,
                                                const int* __restrict__ src,
                                                int beg, int end) {
    f32x4 acc = {0.f, 0.f, 0.f, 0.f};
    int e = beg;
    for (; e + 16 <= end; e += 16) {
        u16x4 v[16];
#pragma unroll
        for (int j = 0; j < 16; ++j) v[j] = base[(long)src[e + j] * R4];
        f32x4 s0 = (bfv4(v[0]) + bfv4(v[1])) + (bfv4(v[2]) + bfv4(v[3]));
        f32x4 s1 = (bfv4(v[4]) + bfv4(v[5])) + (bfv4(v[6]) + bfv4(v[7]));
        f32x4 s2 = (bfv4(v[8]) + bfv4(v[9])) + (bfv4(v[10]) + bfv4(v[11]));
        f32x4 s3 = (bfv4(v[12]) + bfv4(v[13])) + (bfv4(v[14]) + bfv4(v[15]));
        acc += (s0 + s1) + (s2 + s3);
    }
    for (; e + 4 <= end; e += 4) {
        u16x4 v0 = base[(long)src[e] * R4],     v1 = base[(long)src[e + 1] * R4];
        u16x4 v2 = base[(long)src[e + 2] * R4], v3 = base[(long)src[e + 3] * R4];
        acc += (bfv4(v0) + bfv4(v1)) + (bfv4(v2) + bfv4(v3));
    }
    for (; e < end; ++e) acc += bfv4(base[(long)src[e] * R4]);
    return acc;
}

// u16x8 per lane, 8-deep (layer-2 agg)
template <int R8>   // row stride in u16x8 units
__device__ __forceinline__ f32x8 gather_sum_bf(const u16x8* __restrict__ base,
                                               const int* __restrict__ src,
                                               int beg, int end) {
    f32x8 acc = {0.f, 0.f, 0.f, 0.f, 0.f, 0.f, 0.f, 0.f};
    int e = beg;
    for (; e + 8 <= end; e += 8) {
        u16x8 v0 = base[(long)src[e] * R8],     v1 = base[(long)src[e + 1] * R8];
        u16x8 v2 = base[(long)src[e + 2] * R8], v3 = base[(long)src[e + 3] * R8];
        u16x8 v4 = base[(long)src[e + 4] * R8], v5 = base[(long)src[e + 5] * R8];
        u16x8 v6 = base[(long)src[e + 6] * R8], v7 = base[(long)src[e + 7] * R8];
        acc += ((bfv8(v0) + bfv8(v1)) + (bfv8(v2) + bfv8(v3)))
             + ((bfv8(v4) + bfv8(v5)) + (bfv8(v6) + bfv8(v7)));
    }
    for (; e < end; ++e) acc += bfv8(base[(long)src[e] * R8]);
    return acc;
}

// ---------------- f32 gather core (layers 3/4) ----------------
template <int G>
__device__ __forceinline__ f32x4 gather_sum(const f32x4* __restrict__ tsv,
                                            const int* __restrict__ src,
                                            int beg, int end, int lane) {
    f32x4 acc = {0.f, 0.f, 0.f, 0.f};
    int e = beg;
    for (; e + 8 <= end; e += 8) {
        int s0 = src[e], s1 = src[e + 1], s2 = src[e + 2], s3 = src[e + 3];
        int s4 = src[e + 4], s5 = src[e + 5], s6 = src[e + 6], s7 = src[e + 7];
        f32x4 v0 = tsv[(long)s0 * G + lane], v1 = tsv[(long)s1 * G + lane];
        f32x4 v2 = tsv[(long)s2 * G + lane], v3 = tsv[(long)s3 * G + lane];
        f32x4 v4 = tsv[(long)s4 * G + lane], v5 = tsv[(long)s5 * G + lane];
        f32x4 v6 = tsv[(long)s6 * G + lane], v7 = tsv[(long)s7 * G + lane];
        acc += ((v0 + v1) + (v2 + v3)) + ((v4 + v5) + (v6 + v7));
    }
    for (; e + 2 <= end; e += 2) {
        int s0 = src[e], s1 = src[e + 1];
        acc += tsv[(long)s0 * G + lane] + tsv[(long)s1 * G + lane];
    }
    if (e < end) acc += tsv[(long)src[e] * G + lane];
    return acc;
}

// D=256 bf16 gather, ONE NODE PER WAVE (no half-wave divergence):
// h1 = relu(dinv*sum + b1) -> packed [hi|lo] layout-v2 write (full 64B lines).
__global__ __launch_bounds__(256) void agg_split256_kernel(const unsigned short* __restrict__ ts,
                                                           const int* __restrict__ row_ptr,
                                                           const int* __restrict__ src_sorted,
                                                           const float* __restrict__ dinv,
                                                           const float* __restrict__ bias,
                                                           unsigned short* __restrict__ out_p,
                                                           int n) {
    int w = threadIdx.x >> 6, l = threadIdx.x & 63;      // 4 nodes/block, 64 lanes/node
    int node = blockIdx.x * 4 + w;
    if (node >= n) return;
    const u16x4* base = (const u16x4*)ts + l;            // row stride 64 u16x4
    f32x4 acc = gather_sum_bf4<64>(base, src_sorted, row_ptr[node], row_ptr[node + 1]);
    float di = dinv[node];
    f32x4 b4 = *(const f32x4*)&bias[l * 4];
    f32x4 v = acc * di + b4;
    u16x4 hi, lo;
#pragma unroll
    for (int j = 0; j < 4; ++j) {
        float r = fmaxf(v[j], 0.f);
        hi[j] = f2bf(r);
        lo[j] = f2bf(r - bf2f(hi[j]));
    }
    // layout v2: chunk = rt*1024 + kg*64 + row*4 + ks; lane covers k=l*4..l*4+4
    int row = node & 15;
    int kg = l >> 3, ks = (l >> 1) & 3, half = l & 1;
    size_t choff = (size_t)(node >> 4) * 1024 + (size_t)kg * 64 + row * 4 + ks;
    *(u16x4*)&out_p[choff * 8 + half * 4] = hi;
    *(u16x4*)&out_p[(choff + 8 * 64) * 8 + half * 4] = lo;   // lo kg block = kg+8
}

// D=128 bf16 gather + fused W3 matvec: ts3[node] = dinv * (relu(dinv*sum+b2) @ W3)  (128 -> 32)
__global__ __launch_bounds__(256) void agg_fused_w3_kernel(const unsigned short* __restrict__ ts,
                                                           const int* __restrict__ row_ptr,
                                                           const int* __restrict__ src_sorted,
                                                           const float* __restrict__ dinv,
                                                           const float* __restrict__ bias,
                                                           const float* __restrict__ W3,
                                                           float* __restrict__ ts3, int n) {
    __shared__ float W3s[128 * 32];
    __shared__ float hbuf[16][132];   // +4 pad: spreads per-node broadcast reads across banks
    for (int i = threadIdx.x; i < 128 * 32; i += 256) W3s[i] = W3[i];
    __syncthreads();
    int g = threadIdx.x >> 4, lane = threadIdx.x & 15;   // 16 nodes/block, 16 lanes/node
    int node = blockIdx.x * 16 + g;
    if (node >= n) return;
    const u16x8* base = (const u16x8*)ts + lane;         // row stride 16 chunks
    f32x8 acc = gather_sum_bf<16>(base, src_sorted, row_ptr[node], row_ptr[node + 1]);
    float di = dinv[node];
    f32x8 b8 = *(const f32x8*)&bias[lane * 8];
    f32x8 v = acc * di + b8;
#pragma unroll
    for (int j = 0; j < 8; ++j) v[j] = fmaxf(v[j], 0.f);
    f32x4 vlo = {v[0], v[1], v[2], v[3]};
    f32x4 vhi = {v[4], v[5], v[6], v[7]};
    *(f32x4*)&hbuf[g][lane * 8] = vlo;        // same-wave DS: in-order, no barrier needed
    *(f32x4*)&hbuf[g][lane * 8 + 4] = vhi;
    int c0 = lane * 2;
    float aj0 = 0.f, aj1 = 0.f;
#pragma unroll
    for (int k = 0; k < 128; k += 4) {
        f32x4 hv = *(const f32x4*)&hbuf[g][k];
        aj0 += hv[0] * W3s[k * 32 + c0] + hv[1] * W3s[(k + 1) * 32 + c0]
             + hv[2] * W3s[(k + 2) * 32 + c0] + hv[3] * W3s[(k + 3) * 32 + c0];
        aj1 += hv[0] * W3s[k * 32 + c0 + 1] + hv[1] * W3s[(k + 1) * 32 + c0 + 1]
             + hv[2] * W3s[(k + 2) * 32 + c0 + 1] + hv[3] * W3s[(k + 3) * 32 + c0 + 1];
    }
    f32x2 o = {aj0 * di, aj1 * di};
    *(f32x2*)&ts3[(long)node * 32 + c0] = o;
}

// D=32 agg + fused Wk matvec: tsk[node] = dinv * (relu(dinv*sum+b3) @ Wk)    (32 -> 8)
__global__ __launch_bounds__(256) void agg_fused_wk_kernel(const float* __restrict__ ts,
                                                           const int* __restrict__ row_ptr,
                                                           const int* __restrict__ src_sorted,
                                                           const float* __restrict__ dinv,
                                                           const float* __restrict__ bias,
                                                           const float* __restrict__ Wk,
                                                           float* __restrict__ tsk, int n) {
    __shared__ float Wks[32 * 8];
    __shared__ float hbuf[32][36];   // +4 pad
    for (int i = threadIdx.x; i < 32 * 8; i += 256) Wks[i] = Wk[i];
    __syncthreads();
    int g = threadIdx.x >> 3, lane = threadIdx.x & 7;
    int node = blockIdx.x * 32 + g;
    if (node >= n) return;
    f32x4 acc = gather_sum<8>((const f32x4*)ts, src_sorted, row_ptr[node], row_ptr[node + 1], lane);
    float di = dinv[node];
    f32x4 b4 = *(const f32x4*)&bias[lane * 4];
    f32x4 v = acc * di + b4;
#pragma unroll
    for (int j = 0; j < 4; ++j) v[j] = fmaxf(v[j], 0.f);
    *(f32x4*)&hbuf[g][lane * 4] = v;
    float aj = 0.f;
#pragma unroll
    for (int k = 0; k < 32; k += 4) {
        f32x4 hv = *(const f32x4*)&hbuf[g][k];
        aj += hv[0] * Wks[k * 8 + lane] + hv[1] * Wks[(k + 1) * 8 + lane]
            + hv[2] * Wks[(k + 2) * 8 + lane] + hv[3] * Wks[(k + 3) * 8 + lane];
    }
    tsk[(long)node * 8 + lane] = aj * di;
}

// D=8: z = relu(dinv*sum + bk)
__global__ __launch_bounds__(256) void agg_plain8_kernel(const float* __restrict__ ts,
                                                         const int* __restrict__ row_ptr,
                                                         const int* __restrict__ src_sorted,
                                                         const float* __restrict__ dinv,
                                                         const float* __restrict__ bias,
                                                         float* __restrict__ z, int n) {
    int g = threadIdx.x >> 1, lane = threadIdx.x & 1;
    int node = blockIdx.x * 128 + g;
    if (node >= n) return;
    f32x4 acc = gather_sum<2>((const f32x4*)ts, src_sorted, row_ptr[node], row_ptr[node + 1], lane);
    float di = dinv[node];
    f32x4 b4 = *(const f32x4*)&bias[lane * 4];
    f32x4 v = acc * di + b4;
#pragma unroll
    for (int j = 0; j < 4; ++j) v[j] = fmaxf(v[j], 0.f);
    *(f32x4*)&z[(long)node * 8 + lane * 4] = v;
}

// ---------------- decoder: out[k,e] = dot(z[s_e], z[d_e]) (identical across k) ----------------
__global__ __launch_bounds__(256) void decoder_kernel(const float* __restrict__ z,
                                                      const int* __restrict__ ei,
                                                      float* __restrict__ out,
                                                      int E, int K) {
    int e = blockIdx.x * blockDim.x + threadIdx.x;
    if (e >= E) return;
    int s = ei[e];
    int d = ei[E + e];
    const f32x4* zv = (const f32x4*)z;
    f32x4 a0 = zv[(long)s * 2], a1 = zv[(long)s * 2 + 1];
    f32x4 b0 = zv[(long)d * 2], b1 = zv[(long)d * 2 + 1];
    f32x4 p = a0 * b0 + a1 * b1;
    float acc = p[0] + p[1] + p[2] + p[3];
    for (int k = 0; k < K; k++) out[(long)k * E + e] = acc;
}

// ---------------- launch ----------------

extern "C" void kernel_launch(void* const* d_in, const int* in_sizes, int n_in,
                              void* d_out, int out_size, void* d_ws, size_t ws_size,
                              hipStream_t stream) {
    const float* x  = (const float*)d_in[0];
    const int*   ei = (const int*)d_in[1];
    const float* W1 = (const float*)d_in[3];
    const float* b1 = (const float*)d_in[4];
    const float* W2 = (const float*)d_in[5];
    const float* b2 = (const float*)d_in[6];
    const float* W3 = (const float*)d_in[7];
    const float* b3 = (const float*)d_in[8];
    const float* Wk = (const float*)d_in[9];
    const float* bk = (const float*)d_in[10];
    float* out = (float*)d_out;

    const int D1 = in_sizes[4];            // 256
    const int D2 = in_sizes[6];            // 128
    const int F  = in_sizes[3] / D1;       // 256
    const int N  = in_sizes[0] / F;        // 50000
    const int E  = in_sizes[1] / 2;        // 800000
    const int K  = out_size / E;           // 8
    const int M  = E + N;                  // edges incl self loops
    const int Mpad = (N + 127) & ~127;     // 50048

    size_t off = 0;
    auto alloc = [&](size_t bytes) -> void* {
        off = (off + 255) & ~(size_t)255;
        void* p = (char*)d_ws + off;
        off += bytes;
        return p;
    };
    int*   cnt        = (int*)alloc((size_t)N * sizeof(int));
    int*   row_ptr    = (int*)alloc((size_t)(N + 1) * sizeof(int));
    int*   cursor     = (int*)alloc((size_t)N * sizeof(int));
    int*   bsum       = (int*)alloc(1024 * sizeof(int));
    float* dinv       = (float*)alloc((size_t)N * sizeof(float));
    int*   src_sorted = (int*)alloc((size_t)M * sizeof(int));
    unsigned short* region_x = (unsigned short*)alloc((size_t)Mpad * 2 * F * sizeof(short));  // xs_pack -> h1s_pack (51.2MB)
    float* region_t   = (float*)alloc((size_t)Mpad * 256 * sizeof(float));                    // ts1/ts2 (as bf16)
    unsigned short* Wt1 = (unsigned short*)alloc((size_t)D1 * F * sizeof(short));             // W1_hi packed (131KB)
    unsigned short* Wt2 = (unsigned short*)alloc((size_t)D2 * D1 * sizeof(short));            // W2_hi packed (65KB)
    float* ts3        = (float*)alloc((size_t)Mpad * 32 * sizeof(float));
    float* tsk        = (float*)alloc((size_t)Mpad * 8 * sizeof(float));
    float* z          = (float*)alloc((size_t)Mpad * 8 * sizeof(float));
    (void)ws_size; (void)n_in;

    unsigned short* xs  = region_x;                   // packed A for GEMM1
    unsigned short* h1s = region_x;                   // packed A for GEMM2 (reuse after GEMM1)
    unsigned short* ts1 = (unsigned short*)region_t;  // [Mpad,256] bf16 row-major gather table
    unsigned short* ts2 = (unsigned short*)region_t;  // [Mpad,128] bf16 (ts1 consumed)

    int nbN = (N + THREADS - 1) / THREADS;
    int nbE = (E + THREADS - 1) / THREADS;

    // ---- graph prep ----
    init_cnt_kernel<<<nbN, THREADS, 0, stream>>>(cnt, N);
    count_edges_kernel<<<nbE, THREADS, 0, stream>>>(ei, cnt, E);
    scan_p1_kernel<<<nbN, THREADS, 0, stream>>>(cnt, bsum, N);
    scan_p2_kernel<<<1, 1024, 0, stream>>>(bsum, nbN);
    scan_p3_kernel<<<nbN, THREADS, 0, stream>>>(cnt, bsum, row_ptr, N);
    prep_fused_kernel<<<nbN, THREADS, 0, stream>>>(cnt, row_ptr, cursor, dinv, src_sorted, N);
    fill_edges_kernel<<<nbE, THREADS, 0, stream>>>(ei, cursor, src_sorted, E);

    // ---- conversions (fragment-linear packed v2; B = hi(W) only) ----
    convert_x_pack_kernel<<<(int)(((long)N * 64 + 255) / 256), THREADS, 0, stream>>>(x, xs, N, F);
    convert_w_hi_kernel<<<(D1 * (F / 8) + 255) / 256, THREADS, 0, stream>>>(W1, Wt1, F, D1);
    convert_w_hi_kernel<<<(D2 * (D1 / 8) + 255) / 256, THREADS, 0, stream>>>(W2, Wt2, D1, D2);

    // ---- layer 1: ts1 = bf16(dinv .* (x @ W1)); agg (bf16 gather) -> h1s packed v2 ----
    gemm_pack_kernel<256><<<Mpad / 64, THREADS, 0, stream>>>(xs, Wt1, dinv, ts1, N, D1);
    agg_split256_kernel<<<(N + 3) / 4, THREADS, 0, stream>>>(ts1, row_ptr, src_sorted, dinv, b1, h1s, N);

    // ---- layer 2: ts2 = bf16(dinv .* (h1 @ W2)); agg (bf16 gather) + fused W3 -> ts3 ----
    gemm_pack_kernel<128><<<Mpad / 64, THREADS, 0, stream>>>(h1s, Wt2, dinv, ts2, N, D2);
    agg_fused_w3_kernel<<<(N + 15) / 16, THREADS, 0, stream>>>(ts2, row_ptr, src_sorted, dinv, b2, W3, ts3, N);

    // ---- layer 3 agg + fused Wk (32 -> 8), then final agg ----
    agg_fused_wk_kernel<<<(N + 31) / 32, THREADS, 0, stream>>>(ts3, row_ptr, src_sorted, dinv, b3, Wk, tsk, N);
    agg_plain8_kernel<<<(N + 127) / 128, THREADS, 0, stream>>>(tsk, row_ptr, src_sorted, dinv, bk, z, N);

    // ---- decoder ----
    decoder_kernel<<<nbE, THREADS, 0, stream>>>(z, ei, out, E, K);
}

// Round 17
// 318.736 us; speedup vs baseline: 1.7082x; 1.0181x over previous
//
#include <hip/hip_runtime.h>
#include <hip/hip_bf16.h>

#define THREADS 256

typedef __attribute__((ext_vector_type(2))) float f32x2;
typedef __attribute__((ext_vector_type(4))) float f32x4;
typedef __attribute__((ext_vector_type(8))) float f32x8;
typedef __attribute__((ext_vector_type(8))) short short8;
typedef __attribute__((ext_vector_type(4))) unsigned short u16x4;
typedef __attribute__((ext_vector_type(8))) unsigned short u16x8;

__device__ inline unsigned short f2bf(float f) {
    unsigned int u = __builtin_bit_cast(unsigned int, f);
    unsigned int r = (u + 0x7FFFu + ((u >> 16) & 1u)) >> 16;
    return (unsigned short)r;
}
__device__ inline float bf2f(unsigned short h) {
    unsigned int u = ((unsigned int)h) << 16;
    return __builtin_bit_cast(float, u);
}
__device__ __forceinline__ f32x8 bfv8(u16x8 v) {
    f32x8 r;
#pragma unroll
    for (int j = 0; j < 8; ++j) r[j] = bf2f(v[j]);
    return r;
}
__device__ __forceinline__ f32x4 bfv4(u16x4 v) {
    f32x4 r;
#pragma unroll
    for (int j = 0; j < 4; ++j) r[j] = bf2f(v[j]);
    return r;
}

// ---------------- device bodies for fused kernels ----------------

// W [K,N] f32 -> packed B = hi(W) only, fragment-linear (lane-linear layout).
__device__ __forceinline__ void convert_w_body(const float* __restrict__ W,
                                               unsigned short* __restrict__ Bp,
                                               int K, int N, int idx) {
    int cpc = K / 8;
    if (idx >= N * cpc) return;
    int n = idx / cpc, ck = idx % cpc;
    int c = ck * 8;
    u16x8 o;
#pragma unroll
    for (int j = 0; j < 8; ++j) o[j] = f2bf(W[(long)(c + j) * N + n]);
    size_t chunk = ((size_t)(n >> 4) * (K / 32) + (ck >> 2)) * 64 + (ck & 3) * 16 + (n & 15);
    *(u16x8*)&Bp[chunk * 8] = o;
}

// x row -> packed A layout v2 (KA=512 phys = 16 kg of 32 k):
// chunk(row,kg,ks) at rtile*1024 + kg*64 + (row&15)*4 + ks.
__device__ __forceinline__ void convert_x_body(const float* __restrict__ x,
                                               unsigned short* __restrict__ Ap,
                                               int n, int F, long idx) {
    if (idx >= (long)n * 64) return;
    int row = (int)(idx >> 6), c = (int)(idx & 63);
    int kg = c >> 2, ks = c & 3;
    bool ishi = kg < 8;
    int klocal = (kg & 7) * 32 + ks * 8;
    const float* src = &x[(long)row * F + klocal];
    f32x4 v0 = *(const f32x4*)src;
    f32x4 v1 = *(const f32x4*)(src + 4);
    u16x8 o;
#pragma unroll
    for (int j = 0; j < 4; ++j) {
        unsigned short h0 = f2bf(v0[j]);
        unsigned short h1 = f2bf(v1[j]);
        o[j]     = ishi ? h0 : f2bf(v0[j] - bf2f(h0));
        o[j + 4] = ishi ? h1 : f2bf(v1[j] - bf2f(h1));
    }
    size_t chunk = (size_t)(row >> 4) * 1024 + (size_t)kg * 64 + (row & 15) * 4 + ks;
    *(u16x8*)&Ap[chunk * 8] = o;
}

// MFMA GEMM body: C = (A_hi + A_lo) @ B_hi. A layout v2; B lane-linear.
template <int BN>
__device__ __forceinline__ void gemm_pack_body(const unsigned short* __restrict__ Ap,
                                               const unsigned short* __restrict__ Bp,
                                               const float* __restrict__ dinv,
                                               unsigned short* __restrict__ C,
                                               int M, int N, int bid) {
    constexpr int NI = BN / 32;
    const int tid = threadIdx.x;
    const int wave = tid >> 6, l = tid & 63;
    const int wm = wave & 1, wn = wave >> 1;
    const int lr = l & 15, lg = l >> 4;
    const int rt0 = bid * 4 + wm * 2;
    const int ct0 = wn * NI;
    const short8* ab = (const short8*)Ap + (size_t)rt0 * 1024 + lr * 4 + lg;  // layout v2
    const short8* bb = (const short8*)Bp + (size_t)ct0 * 512 + l;
    f32x4 acc[2][NI] = {};
#pragma unroll
    for (int kgb = 0; kgb < 8; ++kgb) {
        short8 b[NI], ah[2], al[2];
#pragma unroll
        for (int ni = 0; ni < NI; ++ni)
            b[ni] = bb[((size_t)ni * 8 + kgb) * 64];
#pragma unroll
        for (int i = 0; i < 2; ++i) {
            ah[i] = ab[((size_t)i * 16 + kgb) * 64];
            al[i] = ab[((size_t)i * 16 + 8 + kgb) * 64];
        }
#pragma unroll
        for (int i = 0; i < 2; ++i)
#pragma unroll
            for (int ni = 0; ni < NI; ++ni)
                acc[i][ni] = __builtin_amdgcn_mfma_f32_16x16x32_bf16(ah[i], b[ni], acc[i][ni], 0, 0, 0);
#pragma unroll
        for (int i = 0; i < 2; ++i)
#pragma unroll
            for (int ni = 0; ni < NI; ++ni)
                acc[i][ni] = __builtin_amdgcn_mfma_f32_16x16x32_bf16(al[i], b[ni], acc[i][ni], 0, 0, 0);
    }
#pragma unroll
    for (int i = 0; i < 2; ++i) {
        int rbase = bid * 64 + (wm * 2 + i) * 16 + lg * 4;
#pragma unroll
        for (int ni = 0; ni < NI; ++ni) {
            int col = wn * (BN / 2) + ni * 16 + lr;
#pragma unroll
            for (int r = 0; r < 4; ++r) {
                int row = rbase + r;
                if (row < M) C[(long)row * N + col] = f2bf(acc[i][ni][r] * dinv[row]);
            }
        }
    }
}

// ---------------- fused launch-group kernels ----------------

// K1: init_cnt U convert_w(W1) U convert_w(W2)
__global__ __launch_bounds__(256) void k1_init_convw_kernel(int* cnt, int n, int nbI,
                                                            const float* W1, unsigned short* Wt1,
                                                            int F, int D1, int nbW1,
                                                            const float* W2, unsigned short* Wt2,
                                                            int D1b, int D2) {
    int b = blockIdx.x;
    if (b < nbI) {
        int i = b * 256 + threadIdx.x;
        if (i < n) cnt[i] = 1;   // self loop
    } else if (b < nbI + nbW1) {
        convert_w_body(W1, Wt1, F, D1, (b - nbI) * 256 + threadIdx.x);
    } else {
        convert_w_body(W2, Wt2, D1b, D2, (b - nbI - nbW1) * 256 + threadIdx.x);
    }
}

// K2: count_edges U convert_x (independent; atomics hide under streaming)
__global__ __launch_bounds__(256) void k2_count_convx_kernel(const int* ei, int* cnt, int E, int nbC,
                                                             const float* x, unsigned short* Ap,
                                                             int n, int F) {
    int b = blockIdx.x;
    if (b < nbC) {
        int e = b * 256 + threadIdx.x;
        if (e < E) atomicAdd(&cnt[ei[E + e]], 1);   // dst row
    } else {
        convert_x_body(x, Ap, n, F, (long)(b - nbC) * 256 + threadIdx.x);
    }
}

// ---------------- 3-phase multi-block exclusive scan (coalesced) ----------------
__global__ __launch_bounds__(256) void scan_p1_kernel(const int* __restrict__ cnt,
                                                      int* __restrict__ bsum, int n) {
    __shared__ int sh[256];
    int i = blockIdx.x * 256 + threadIdx.x;
    int v = (i < n) ? cnt[i] : 0;
    sh[threadIdx.x] = v;
    __syncthreads();
#pragma unroll
    for (int off = 128; off > 0; off >>= 1) {
        if ((int)threadIdx.x < off) sh[threadIdx.x] += sh[threadIdx.x + off];
        __syncthreads();
    }
    if (threadIdx.x == 0) bsum[blockIdx.x] = sh[0];
}

__global__ __launch_bounds__(1024) void scan_p2_kernel(int* __restrict__ bsum, int nb) {
    __shared__ int sh[1024];
    int v = ((int)threadIdx.x < nb) ? bsum[threadIdx.x] : 0;
    sh[threadIdx.x] = v;
    __syncthreads();
    for (int off = 1; off < 1024; off <<= 1) {
        int t = (threadIdx.x >= (unsigned)off) ? sh[threadIdx.x - off] : 0;
        __syncthreads();
        sh[threadIdx.x] += t;
        __syncthreads();
    }
    if ((int)threadIdx.x < nb) bsum[threadIdx.x] = sh[threadIdx.x] - v;   // exclusive
}

// K5: scan_p3 + prep (dinv, self-loop fill, cursor init) fused
__global__ __launch_bounds__(256) void scan_p3_prep_kernel(const int* __restrict__ cnt,
                                                           const int* __restrict__ bsum,
                                                           int* __restrict__ row_ptr,
                                                           float* __restrict__ dinv,
                                                           int* __restrict__ cursor,
                                                           int* __restrict__ src_sorted, int n) {
    __shared__ int sh[256];
    int i = blockIdx.x * 256 + threadIdx.x;
    int v = (i < n) ? cnt[i] : 0;
    sh[threadIdx.x] = v;
    __syncthreads();
    for (int off = 1; off < 256; off <<= 1) {
        int t = (threadIdx.x >= (unsigned)off) ? sh[threadIdx.x - off] : 0;
        __syncthreads();
        sh[threadIdx.x] += t;
        __syncthreads();
    }
    int excl = sh[threadIdx.x] - v + bsum[blockIdx.x];
    if (i < n) {
        row_ptr[i] = excl;
        dinv[i] = rsqrtf((float)v);
        src_sorted[excl] = i;      // self loop first (deterministic slot)
        cursor[i] = excl + 1;
    }
    if (i == n - 1) row_ptr[n] = excl + v;
}

// K6: gemm1 (BN=256) U fill_edges (independent; atomics hide under MFMA)
__global__ __launch_bounds__(256) void k6_gemm_fill_kernel(const unsigned short* __restrict__ Ap,
                                                           const unsigned short* __restrict__ Bp,
                                                           const float* __restrict__ dinv,
                                                           unsigned short* __restrict__ C,
                                                           int M, int N, int nbG,
                                                           const int* __restrict__ ei,
                                                           int* __restrict__ cursor,
                                                           int* __restrict__ src_sorted, int E) {
    if ((int)blockIdx.x < nbG) {
        gemm_pack_body<256>(Ap, Bp, dinv, C, M, N, blockIdx.x);
    } else {
        int e = (blockIdx.x - nbG) * 256 + threadIdx.x;
        if (e < E) {
            int s = ei[e];
            int d = ei[E + e];
            int pos = atomicAdd(&cursor[d], 1);
            src_sorted[pos] = s;
        }
    }
}

// GEMM2 standalone
template <int BN>
__global__ __launch_bounds__(256) void gemm_pack_kernel(const unsigned short* __restrict__ Ap,
                                                        const unsigned short* __restrict__ Bp,
                                                        const float* __restrict__ dinv,
                                                        unsigned short* __restrict__ C,
                                                        int M, int N) {
    gemm_pack_body<BN>(Ap, Bp, dinv, C, M, N, blockIdx.x);
}

// ---------------- bf16 gather cores ----------------
template <int R4>   // row stride in u16x4 units
__device__ __forceinline__ f32x4 gather_sum_bf4(const u16x4* __restrict__ base,
                                                const int* __restrict__ src,
                                                int beg, int end) {
    f32x4 acc = {0.f, 0.f, 0.f, 0.f};
    int e = beg;
    for (; e + 16 <= end; e += 16) {
        u16x4 v[16];
#pragma unroll
        for (int j = 0; j < 16; ++j) v[j] = base[(long)src[e + j] * R4];
        f32x4 s0 = (bfv4(v[0]) + bfv4(v[1])) + (bfv4(v[2]) + bfv4(v[3]));
        f32x4 s1 = (bfv4(v[4]) + bfv4(v[5])) + (bfv4(v[6]) + bfv4(v[7]));
        f32x4 s2 = (bfv4(v[8]) + bfv4(v[9])) + (bfv4(v[10]) + bfv4(v[11]));
        f32x4 s3 = (bfv4(v[12]) + bfv4(v[13])) + (bfv4(v[14]) + bfv4(v[15]));
        acc += (s0 + s1) + (s2 + s3);
    }
    for (; e + 4 <= end; e += 4) {
        u16x4 v0 = base[(long)src[e] * R4],     v1 = base[(long)src[e + 1] * R4];
        u16x4 v2 = base[(long)src[e + 2] * R4], v3 = base[(long)src[e + 3] * R4];
        acc += (bfv4(v0) + bfv4(v1)) + (bfv4(v2) + bfv4(v3));
    }
    for (; e < end; ++e) acc += bfv4(base[(long)src[e] * R4]);
    return acc;
}

// ---------------- f32 gather core (layers 3/4) ----------------
template <int G>
__device__ __forceinline__ f32x4 gather_sum(const f32x4* __restrict__ tsv,
                                            const int* __restrict__ src,
                                            int beg, int end, int lane) {
    f32x4 acc = {0.f, 0.f, 0.f, 0.f};
    int e = beg;
    for (; e + 8 <= end; e += 8) {
        int s0 = src[e], s1 = src[e + 1], s2 = src[e + 2], s3 = src[e + 3];
        int s4 = src[e + 4], s5 = src[e + 5], s6 = src[e + 6], s7 = src[e + 7];
        f32x4 v0 = tsv[(long)s0 * G + lane], v1 = tsv[(long)s1 * G + lane];
        f32x4 v2 = tsv[(long)s2 * G + lane], v3 = tsv[(long)s3 * G + lane];
        f32x4 v4 = tsv[(long)s4 * G + lane], v5 = tsv[(long)s5 * G + lane];
        f32x4 v6 = tsv[(long)s6 * G + lane], v7 = tsv[(long)s7 * G + lane];
        acc += ((v0 + v1) + (v2 + v3)) + ((v4 + v5) + (v6 + v7));
    }
    for (; e + 2 <= end; e += 2) {
        int s0 = src[e], s1 = src[e + 1];
        acc += tsv[(long)s0 * G + lane] + tsv[(long)s1 * G + lane];
    }
    if (e < end) acc += tsv[(long)src[e] * G + lane];
    return acc;
}

// D=256 bf16 gather, ONE NODE PER WAVE:
// h1 = relu(dinv*sum + b1) -> packed [hi|lo] layout-v2 write (full 64B lines).
__global__ __launch_bounds__(256) void agg_split256_kernel(const unsigned short* __restrict__ ts,
                                                           const int* __restrict__ row_ptr,
                                                           const int* __restrict__ src_sorted,
                                                           const float* __restrict__ dinv,
                                                           const float* __restrict__ bias,
                                                           unsigned short* __restrict__ out_p,
                                                           int n) {
    int w = threadIdx.x >> 6, l = threadIdx.x & 63;      // 4 nodes/block, 64 lanes/node
    int node = blockIdx.x * 4 + w;
    if (node >= n) return;
    const u16x4* base = (const u16x4*)ts + l;            // row stride 64 u16x4
    f32x4 acc = gather_sum_bf4<64>(base, src_sorted, row_ptr[node], row_ptr[node + 1]);
    float di = dinv[node];
    f32x4 b4 = *(const f32x4*)&bias[l * 4];
    f32x4 v = acc * di + b4;
    u16x4 hi, lo;
#pragma unroll
    for (int j = 0; j < 4; ++j) {
        float r = fmaxf(v[j], 0.f);
        hi[j] = f2bf(r);
        lo[j] = f2bf(r - bf2f(hi[j]));
    }
    int row = node & 15;
    int kg = l >> 3, ks = (l >> 1) & 3, half = l & 1;
    size_t choff = (size_t)(node >> 4) * 1024 + (size_t)kg * 64 + row * 4 + ks;
    *(u16x4*)&out_p[choff * 8 + half * 4] = hi;
    *(u16x4*)&out_p[(choff + 8 * 64) * 8 + half * 4] = lo;   // lo kg block = kg+8
}

// D=128 bf16 gather (32 lanes/node, u16x4) + fused W3 matvec (128 -> 32)
__global__ __launch_bounds__(256) void agg_fused_w3_kernel(const unsigned short* __restrict__ ts,
                                                           const int* __restrict__ row_ptr,
                                                           const int* __restrict__ src_sorted,
                                                           const float* __restrict__ dinv,
                                                           const float* __restrict__ bias,
                                                           const float* __restrict__ W3,
                                                           float* __restrict__ ts3, int n) {
    __shared__ float W3s[128 * 32];
    __shared__ float hbuf[8][132];    // +4 pad
    for (int i = threadIdx.x; i < 128 * 32; i += 256) W3s[i] = W3[i];
    __syncthreads();
    int g = threadIdx.x >> 5, lane = threadIdx.x & 31;   // 8 nodes/block, 32 lanes/node
    int node = blockIdx.x * 8 + g;
    if (node >= n) return;
    const u16x4* base = (const u16x4*)ts + lane;         // row stride 32 u16x4
    f32x4 acc = gather_sum_bf4<32>(base, src_sorted, row_ptr[node], row_ptr[node + 1]);
    float di = dinv[node];
    f32x4 b4 = *(const f32x4*)&bias[lane * 4];
    f32x4 v = acc * di + b4;
#pragma unroll
    for (int j = 0; j < 4; ++j) v[j] = fmaxf(v[j], 0.f);
    *(f32x4*)&hbuf[g][lane * 4] = v;    // same-wave (32-lane group) DS: in-order
    float aj = 0.f;
#pragma unroll
    for (int k = 0; k < 128; k += 4) {
        f32x4 hv = *(const f32x4*)&hbuf[g][k];
        aj += hv[0] * W3s[k * 32 + lane] + hv[1] * W3s[(k + 1) * 32 + lane]
            + hv[2] * W3s[(k + 2) * 32 + lane] + hv[3] * W3s[(k + 3) * 32 + lane];
    }
    ts3[(long)node * 32 + lane] = aj * di;
}

// D=32 agg + fused Wk matvec: tsk[node] = dinv * (relu(dinv*sum+b3) @ Wk)    (32 -> 8)
__global__ __launch_bounds__(256) void agg_fused_wk_kernel(const float* __restrict__ ts,
                                                           const int* __restrict__ row_ptr,
                                                           const int* __restrict__ src_sorted,
                                                           const float* __restrict__ dinv,
                                                           const float* __restrict__ bias,
                                                           const float* __restrict__ Wk,
                                                           float* __restrict__ tsk, int n) {
    __shared__ float Wks[32 * 8];
    __shared__ float hbuf[32][36];   // +4 pad
    for (int i = threadIdx.x; i < 32 * 8; i += 256) Wks[i] = Wk[i];
    __syncthreads();
    int g = threadIdx.x >> 3, lane = threadIdx.x & 7;
    int node = blockIdx.x * 32 + g;
    if (node >= n) return;
    f32x4 acc = gather_sum<8>((const f32x4*)ts, src_sorted, row_ptr[node], row_ptr[node + 1], lane);
    float di = dinv[node];
    f32x4 b4 = *(const f32x4*)&bias[lane * 4];
    f32x4 v = acc * di + b4;
#pragma unroll
    for (int j = 0; j < 4; ++j) v[j] = fmaxf(v[j], 0.f);
    *(f32x4*)&hbuf[g][lane * 4] = v;
    float aj = 0.f;
#pragma unroll
    for (int k = 0; k < 32; k += 4) {
        f32x4 hv = *(const f32x4*)&hbuf[g][k];
        aj += hv[0] * Wks[k * 8 + lane] + hv[1] * Wks[(k + 1) * 8 + lane]
            + hv[2] * Wks[(k + 2) * 8 + lane] + hv[3] * Wks[(k + 3) * 8 + lane];
    }
    tsk[(long)node * 8 + lane] = aj * di;
}

// D=8: z = relu(dinv*sum + bk)
__global__ __launch_bounds__(256) void agg_plain8_kernel(const float* __restrict__ ts,
                                                         const int* __restrict__ row_ptr,
                                                         const int* __restrict__ src_sorted,
                                                         const float* __restrict__ dinv,
                                                         const float* __restrict__ bias,
                                                         float* __restrict__ z, int n) {
    int g = threadIdx.x >> 1, lane = threadIdx.x & 1;
    int node = blockIdx.x * 128 + g;
    if (node >= n) return;
    f32x4 acc = gather_sum<2>((const f32x4*)ts, src_sorted, row_ptr[node], row_ptr[node + 1], lane);
    float di = dinv[node];
    f32x4 b4 = *(const f32x4*)&bias[lane * 4];
    f32x4 v = acc * di + b4;
#pragma unroll
    for (int j = 0; j < 4; ++j) v[j] = fmaxf(v[j], 0.f);
    *(f32x4*)&z[(long)node * 8 + lane * 4] = v;
}

// ---------------- decoder: out[k,e] = dot(z[s_e], z[d_e]) (identical across k) ----------------
__global__ __launch_bounds__(256) void decoder_kernel(const float* __restrict__ z,
                                                      const int* __restrict__ ei,
                                                      float* __restrict__ out,
                                                      int E, int K) {
    int e = blockIdx.x * blockDim.x + threadIdx.x;
    if (e >= E) return;
    int s = ei[e];
    int d = ei[E + e];
    const f32x4* zv = (const f32x4*)z;
    f32x4 a0 = zv[(long)s * 2], a1 = zv[(long)s * 2 + 1];
    f32x4 b0 = zv[(long)d * 2], b1 = zv[(long)d * 2 + 1];
    f32x4 p = a0 * b0 + a1 * b1;
    float acc = p[0] + p[1] + p[2] + p[3];
    for (int k = 0; k < K; k++) out[(long)k * E + e] = acc;
}

// ---------------- launch ----------------

extern "C" void kernel_launch(void* const* d_in, const int* in_sizes, int n_in,
                              void* d_out, int out_size, void* d_ws, size_t ws_size,
                              hipStream_t stream) {
    const float* x  = (const float*)d_in[0];
    const int*   ei = (const int*)d_in[1];
    const float* W1 = (const float*)d_in[3];
    const float* b1 = (const float*)d_in[4];
    const float* W2 = (const float*)d_in[5];
    const float* b2 = (const float*)d_in[6];
    const float* W3 = (const float*)d_in[7];
    const float* b3 = (const float*)d_in[8];
    const float* Wk = (const float*)d_in[9];
    const float* bk = (const float*)d_in[10];
    float* out = (float*)d_out;

    const int D1 = in_sizes[4];            // 256
    const int D2 = in_sizes[6];            // 128
    const int F  = in_sizes[3] / D1;       // 256
    const int N  = in_sizes[0] / F;        // 50000
    const int E  = in_sizes[1] / 2;        // 800000
    const int K  = out_size / E;           // 8
    const int M  = E + N;                  // edges incl self loops
    const int Mpad = (N + 127) & ~127;     // 50048

    size_t off = 0;
    auto alloc = [&](size_t bytes) -> void* {
        off = (off + 255) & ~(size_t)255;
        void* p = (char*)d_ws + off;
        off += bytes;
        return p;
    };
    int*   cnt        = (int*)alloc((size_t)N * sizeof(int));
    int*   row_ptr    = (int*)alloc((size_t)(N + 1) * sizeof(int));
    int*   cursor     = (int*)alloc((size_t)N * sizeof(int));
    int*   bsum       = (int*)alloc(1024 * sizeof(int));
    float* dinv       = (float*)alloc((size_t)N * sizeof(float));
    int*   src_sorted = (int*)alloc((size_t)M * sizeof(int));
    unsigned short* region_x = (unsigned short*)alloc((size_t)Mpad * 2 * F * sizeof(short));  // xs_pack -> h1s_pack (51.2MB)
    float* region_t   = (float*)alloc((size_t)Mpad * 256 * sizeof(float));                    // ts1/ts2 (as bf16)
    unsigned short* Wt1 = (unsigned short*)alloc((size_t)D1 * F * sizeof(short));             // W1_hi packed (131KB)
    unsigned short* Wt2 = (unsigned short*)alloc((size_t)D2 * D1 * sizeof(short));            // W2_hi packed (65KB)
    float* ts3        = (float*)alloc((size_t)Mpad * 32 * sizeof(float));
    float* tsk        = (float*)alloc((size_t)Mpad * 8 * sizeof(float));
    float* z          = (float*)alloc((size_t)Mpad * 8 * sizeof(float));
    (void)ws_size; (void)n_in;

    unsigned short* xs  = region_x;                   // packed A for GEMM1
    unsigned short* h1s = region_x;                   // packed A for GEMM2 (reuse after GEMM1)
    unsigned short* ts1 = (unsigned short*)region_t;  // [Mpad,256] bf16 row-major gather table
    unsigned short* ts2 = (unsigned short*)region_t;  // [Mpad,128] bf16 (ts1 consumed)

    const int nbN = (N + THREADS - 1) / THREADS;          // 196
    const int nbE = (E + THREADS - 1) / THREADS;          // 3125
    const int nbX = (int)(((long)N * 64 + 255) / 256);    // 12500
    const int nbW1 = (D1 * (F / 8) + 255) / 256;          // 32
    const int nbW2 = (D2 * (D1 / 8) + 255) / 256;         // 16
    const int nbG1 = Mpad / 64;                           // 782

    // K1: init_cnt U convert_w1 U convert_w2
    k1_init_convw_kernel<<<nbN + nbW1 + nbW2, THREADS, 0, stream>>>(
        cnt, N, nbN, W1, Wt1, F, D1, nbW1, W2, Wt2, D1, D2);
    // K2: count_edges U convert_x
    k2_count_convx_kernel<<<nbE + nbX, THREADS, 0, stream>>>(ei, cnt, E, nbE, x, xs, N, F);
    // K3-K5: scan + fused prep
    scan_p1_kernel<<<nbN, THREADS, 0, stream>>>(cnt, bsum, N);
    scan_p2_kernel<<<1, 1024, 0, stream>>>(bsum, nbN);
    scan_p3_prep_kernel<<<nbN, THREADS, 0, stream>>>(cnt, bsum, row_ptr, dinv, cursor, src_sorted, N);
    // K6: gemm1 U fill_edges
    k6_gemm_fill_kernel<<<nbG1 + nbE, THREADS, 0, stream>>>(
        xs, Wt1, dinv, ts1, N, D1, nbG1, ei, cursor, src_sorted, E);
    // K7: layer-1 aggregation -> h1s packed v2
    agg_split256_kernel<<<(N + 3) / 4, THREADS, 0, stream>>>(ts1, row_ptr, src_sorted, dinv, b1, h1s, N);
    // K8: gemm2
    gemm_pack_kernel<128><<<nbG1, THREADS, 0, stream>>>(h1s, Wt2, dinv, ts2, N, D2);
    // K9: layer-2 agg + fused W3
    agg_fused_w3_kernel<<<(N + 7) / 8, THREADS, 0, stream>>>(ts2, row_ptr, src_sorted, dinv, b2, W3, ts3, N);
    // K10-K11: layer 3 agg + fused Wk, final agg
    agg_fused_wk_kernel<<<(N + 31) / 32, THREADS, 0, stream>>>(ts3, row_ptr, src_sorted, dinv, b3, Wk, tsk, N);
    agg_plain8_kernel<<<(N + 127) / 128, THREADS, 0, stream>>>(tsk, row_ptr, src_sorted, dinv, bk, z, N);
    // K12: decoder
    decoder_kernel<<<nbE, THREADS, 0, stream>>>(z, ei, out, E, K);
}

// Round 20
// 309.237 us; speedup vs baseline: 1.7607x; 1.0307x over previous
//
#include <hip/hip_runtime.h>
#include <hip/hip_bf16.h>

#define THREADS 256

typedef __attribute__((ext_vector_type(2))) float f32x2;
typedef __attribute__((ext_vector_type(4))) float f32x4;
typedef __attribute__((ext_vector_type(8))) float f32x8;
typedef __attribute__((ext_vector_type(8))) short short8;
typedef __attribute__((ext_vector_type(4))) unsigned short u16x4;
typedef __attribute__((ext_vector_type(8))) unsigned short u16x8;

__device__ inline unsigned short f2bf(float f) {
    unsigned int u = __builtin_bit_cast(unsigned int, f);
    unsigned int r = (u + 0x7FFFu + ((u >> 16) & 1u)) >> 16;
    return (unsigned short)r;
}
__device__ inline float bf2f(unsigned short h) {
    unsigned int u = ((unsigned int)h) << 16;
    return __builtin_bit_cast(float, u);
}
__device__ __forceinline__ f32x8 bfv8(u16x8 v) {
    f32x8 r;
#pragma unroll
    for (int j = 0; j < 8; ++j) r[j] = bf2f(v[j]);
    return r;
}
__device__ __forceinline__ f32x4 bfv4(u16x4 v) {
    f32x4 r;
#pragma unroll
    for (int j = 0; j < 4; ++j) r[j] = bf2f(v[j]);
    return r;
}

// ---------------- device bodies for fused kernels ----------------

// W [K,N] f32 -> packed B = hi(W) only, fragment-linear (lane-linear layout).
__device__ __forceinline__ void convert_w_body(const float* __restrict__ W,
                                               unsigned short* __restrict__ Bp,
                                               int K, int N, int idx) {
    int cpc = K / 8;
    if (idx >= N * cpc) return;
    int n = idx / cpc, ck = idx % cpc;
    int c = ck * 8;
    u16x8 o;
#pragma unroll
    for (int j = 0; j < 8; ++j) o[j] = f2bf(W[(long)(c + j) * N + n]);
    size_t chunk = ((size_t)(n >> 4) * (K / 32) + (ck >> 2)) * 64 + (ck & 3) * 16 + (n & 15);
    *(u16x8*)&Bp[chunk * 8] = o;
}

// x row -> packed A layout v2 (KA=512 phys = 16 kg of 32 k):
// chunk(row,kg,ks) at rtile*1024 + kg*64 + (row&15)*4 + ks.
__device__ __forceinline__ void convert_x_body(const float* __restrict__ x,
                                               unsigned short* __restrict__ Ap,
                                               int n, int F, long idx) {
    if (idx >= (long)n * 64) return;
    int row = (int)(idx >> 6), c = (int)(idx & 63);
    int kg = c >> 2, ks = c & 3;
    bool ishi = kg < 8;
    int klocal = (kg & 7) * 32 + ks * 8;
    const float* src = &x[(long)row * F + klocal];
    f32x4 v0 = *(const f32x4*)src;
    f32x4 v1 = *(const f32x4*)(src + 4);
    u16x8 o;
#pragma unroll
    for (int j = 0; j < 4; ++j) {
        unsigned short h0 = f2bf(v0[j]);
        unsigned short h1 = f2bf(v1[j]);
        o[j]     = ishi ? h0 : f2bf(v0[j] - bf2f(h0));
        o[j + 4] = ishi ? h1 : f2bf(v1[j] - bf2f(h1));
    }
    size_t chunk = (size_t)(row >> 4) * 1024 + (size_t)kg * 64 + (row & 15) * 4 + ks;
    *(u16x8*)&Ap[chunk * 8] = o;
}

// MFMA GEMM body: C = (A_hi + A_lo) @ B_hi. A layout v2 (16 kg); B lane-linear.
template <int BN>
__device__ __forceinline__ void gemm_pack_body(const unsigned short* __restrict__ Ap,
                                               const unsigned short* __restrict__ Bp,
                                               const float* __restrict__ dinv,
                                               unsigned short* __restrict__ C,
                                               int M, int N, int bid) {
    constexpr int NI = BN / 32;
    const int tid = threadIdx.x;
    const int wave = tid >> 6, l = tid & 63;
    const int wm = wave & 1, wn = wave >> 1;
    const int lr = l & 15, lg = l >> 4;
    const int rt0 = bid * 4 + wm * 2;
    const int ct0 = wn * NI;
    const short8* ab = (const short8*)Ap + (size_t)rt0 * 1024 + lr * 4 + lg;  // layout v2
    const short8* bb = (const short8*)Bp + (size_t)ct0 * 512 + l;
    f32x4 acc[2][NI] = {};
#pragma unroll
    for (int kgb = 0; kgb < 8; ++kgb) {
        short8 b[NI], ah[2], al[2];
#pragma unroll
        for (int ni = 0; ni < NI; ++ni)
            b[ni] = bb[((size_t)ni * 8 + kgb) * 64];
#pragma unroll
        for (int i = 0; i < 2; ++i) {
            ah[i] = ab[((size_t)i * 16 + kgb) * 64];
            al[i] = ab[((size_t)i * 16 + 8 + kgb) * 64];
        }
#pragma unroll
        for (int i = 0; i < 2; ++i)
#pragma unroll
            for (int ni = 0; ni < NI; ++ni)
                acc[i][ni] = __builtin_amdgcn_mfma_f32_16x16x32_bf16(ah[i], b[ni], acc[i][ni], 0, 0, 0);
#pragma unroll
        for (int i = 0; i < 2; ++i)
#pragma unroll
            for (int ni = 0; ni < NI; ++ni)
                acc[i][ni] = __builtin_amdgcn_mfma_f32_16x16x32_bf16(al[i], b[ni], acc[i][ni], 0, 0, 0);
    }
#pragma unroll
    for (int i = 0; i < 2; ++i) {
        int rbase = bid * 64 + (wm * 2 + i) * 16 + lg * 4;
#pragma unroll
        for (int ni = 0; ni < NI; ++ni) {
            int col = wn * (BN / 2) + ni * 16 + lr;
#pragma unroll
            for (int r = 0; r < 4; ++r) {
                int row = rbase + r;
                if (row < M) C[(long)row * N + col] = f2bf(acc[i][ni][r] * dinv[row]);
            }
        }
    }
}

// ---------------- fused launch-group kernels ----------------

// K1: init_cnt U convert_w(W1) U convert_w(W2)
__global__ __launch_bounds__(256) void k1_init_convw_kernel(int* cnt, int n, int nbI,
                                                            const float* W1, unsigned short* Wt1,
                                                            int F, int D1, int nbW1,
                                                            const float* W2, unsigned short* Wt2,
                                                            int D1b, int D2) {
    int b = blockIdx.x;
    if (b < nbI) {
        int i = b * 256 + threadIdx.x;
        if (i < n) cnt[i] = 1;   // self loop
    } else if (b < nbI + nbW1) {
        convert_w_body(W1, Wt1, F, D1, (b - nbI) * 256 + threadIdx.x);
    } else {
        convert_w_body(W2, Wt2, D1b, D2, (b - nbI - nbW1) * 256 + threadIdx.x);
    }
}

// K2: count_edges U convert_x (independent; atomics hide under streaming)
__global__ __launch_bounds__(256) void k2_count_convx_kernel(const int* ei, int* cnt, int E, int nbC,
                                                             const float* x, unsigned short* Ap,
                                                             int n, int F) {
    int b = blockIdx.x;
    if (b < nbC) {
        int e = b * 256 + threadIdx.x;
        if (e < E) atomicAdd(&cnt[ei[E + e]], 1);   // dst row
    } else {
        convert_x_body(x, Ap, n, F, (long)(b - nbC) * 256 + threadIdx.x);
    }
}

// ---------------- 3-phase multi-block exclusive scan (coalesced) ----------------
__global__ __launch_bounds__(256) void scan_p1_kernel(const int* __restrict__ cnt,
                                                      int* __restrict__ bsum, int n) {
    __shared__ int sh[256];
    int i = blockIdx.x * 256 + threadIdx.x;
    int v = (i < n) ? cnt[i] : 0;
    sh[threadIdx.x] = v;
    __syncthreads();
#pragma unroll
    for (int off = 128; off > 0; off >>= 1) {
        if ((int)threadIdx.x < off) sh[threadIdx.x] += sh[threadIdx.x + off];
        __syncthreads();
    }
    if (threadIdx.x == 0) bsum[blockIdx.x] = sh[0];
}

__global__ __launch_bounds__(1024) void scan_p2_kernel(int* __restrict__ bsum, int nb) {
    __shared__ int sh[1024];
    int v = ((int)threadIdx.x < nb) ? bsum[threadIdx.x] : 0;
    sh[threadIdx.x] = v;
    __syncthreads();
    for (int off = 1; off < 1024; off <<= 1) {
        int t = (threadIdx.x >= (unsigned)off) ? sh[threadIdx.x - off] : 0;
        __syncthreads();
        sh[threadIdx.x] += t;
        __syncthreads();
    }
    if ((int)threadIdx.x < nb) bsum[threadIdx.x] = sh[threadIdx.x] - v;   // exclusive
}

// K5: scan_p3 + prep (dinv, self-loop fill, cursor init) fused
__global__ __launch_bounds__(256) void scan_p3_prep_kernel(const int* __restrict__ cnt,
                                                           const int* __restrict__ bsum,
                                                           int* __restrict__ row_ptr,
                                                           float* __restrict__ dinv,
                                                           int* __restrict__ cursor,
                                                           int* __restrict__ src_sorted, int n) {
    __shared__ int sh[256];
    int i = blockIdx.x * 256 + threadIdx.x;
    int v = (i < n) ? cnt[i] : 0;
    sh[threadIdx.x] = v;
    __syncthreads();
    for (int off = 1; off < 256; off <<= 1) {
        int t = (threadIdx.x >= (unsigned)off) ? sh[threadIdx.x - off] : 0;
        __syncthreads();
        sh[threadIdx.x] += t;
        __syncthreads();
    }
    int excl = sh[threadIdx.x] - v + bsum[blockIdx.x];
    if (i < n) {
        row_ptr[i] = excl;
        dinv[i] = rsqrtf((float)v);
        src_sorted[excl] = i;      // self loop first (deterministic slot)
        cursor[i] = excl + 1;
    }
    if (i == n - 1) row_ptr[n] = excl + v;
}

// K6: gemm1 (BN=256, hi+lo A) U fill_edges (independent; atomics hide under MFMA)
__global__ __launch_bounds__(256) void k6_gemm_fill_kernel(const unsigned short* __restrict__ Ap,
                                                           const unsigned short* __restrict__ Bp,
                                                           const float* __restrict__ dinv,
                                                           unsigned short* __restrict__ C,
                                                           int M, int N, int nbG,
                                                           const int* __restrict__ ei,
                                                           int* __restrict__ cursor,
                                                           int* __restrict__ src_sorted, int E) {
    if ((int)blockIdx.x < nbG) {
        gemm_pack_body<256>(Ap, Bp, dinv, C, M, N, blockIdx.x);
    } else {
        int e = (blockIdx.x - nbG) * 256 + threadIdx.x;
        if (e < E) {
            int s = ei[e];
            int d = ei[E + e];
            int pos = atomicAdd(&cursor[d], 1);
            src_sorted[pos] = s;
        }
    }
}

// GEMM2: C = A_hi @ B_hi (A has only 8 kg of hi; rtile stride = 512 chunks)
template <int BN>
__global__ __launch_bounds__(256) void gemm_hi_kernel(const unsigned short* __restrict__ Ap,
                                                      const unsigned short* __restrict__ Bp,
                                                      const float* __restrict__ dinv,
                                                      unsigned short* __restrict__ C,
                                                      int M, int N) {
    constexpr int NI = BN / 32;
    const int tid = threadIdx.x;
    const int wave = tid >> 6, l = tid & 63;
    const int wm = wave & 1, wn = wave >> 1;
    const int lr = l & 15, lg = l >> 4;
    const int rt0 = blockIdx.x * 4 + wm * 2;
    const int ct0 = wn * NI;
    const short8* ab = (const short8*)Ap + (size_t)rt0 * 512 + lr * 4 + lg;   // 8 kg per rtile
    const short8* bb = (const short8*)Bp + (size_t)ct0 * 512 + l;
    f32x4 acc[2][NI] = {};
#pragma unroll
    for (int kgb = 0; kgb < 8; ++kgb) {
        short8 b[NI], ah[2];
#pragma unroll
        for (int ni = 0; ni < NI; ++ni)
            b[ni] = bb[((size_t)ni * 8 + kgb) * 64];
#pragma unroll
        for (int i = 0; i < 2; ++i)
            ah[i] = ab[((size_t)i * 8 + kgb) * 64];
#pragma unroll
        for (int i = 0; i < 2; ++i)
#pragma unroll
            for (int ni = 0; ni < NI; ++ni)
                acc[i][ni] = __builtin_amdgcn_mfma_f32_16x16x32_bf16(ah[i], b[ni], acc[i][ni], 0, 0, 0);
    }
#pragma unroll
    for (int i = 0; i < 2; ++i) {
        int rbase = blockIdx.x * 64 + (wm * 2 + i) * 16 + lg * 4;
#pragma unroll
        for (int ni = 0; ni < NI; ++ni) {
            int col = wn * (BN / 2) + ni * 16 + lr;
#pragma unroll
            for (int r = 0; r < 4; ++r) {
                int row = rbase + r;
                if (row < M) C[(long)row * N + col] = f2bf(acc[i][ni][r] * dinv[row]);
            }
        }
    }
}

// ---------------- bf16 gather cores ----------------
template <int R4>   // row stride in u16x4 units
__device__ __forceinline__ f32x4 gather_sum_bf4(const u16x4* __restrict__ base,
                                                const int* __restrict__ src,
                                                int beg, int end) {
    f32x4 acc = {0.f, 0.f, 0.f, 0.f};
    int e = beg;
    for (; e + 16 <= end; e += 16) {
        u16x4 v[16];
#pragma unroll
        for (int j = 0; j < 16; ++j) v[j] = base[(long)src[e + j] * R4];
        f32x4 s0 = (bfv4(v[0]) + bfv4(v[1])) + (bfv4(v[2]) + bfv4(v[3]));
        f32x4 s1 = (bfv4(v[4]) + bfv4(v[5])) + (bfv4(v[6]) + bfv4(v[7]));
        f32x4 s2 = (bfv4(v[8]) + bfv4(v[9])) + (bfv4(v[10]) + bfv4(v[11]));
        f32x4 s3 = (bfv4(v[12]) + bfv4(v[13])) + (bfv4(v[14]) + bfv4(v[15]));
        acc += (s0 + s1) + (s2 + s3);
    }
    for (; e + 4 <= end; e += 4) {
        u16x4 v0 = base[(long)src[e] * R4],     v1 = base[(long)src[e + 1] * R4];
        u16x4 v2 = base[(long)src[e + 2] * R4], v3 = base[(long)src[e + 3] * R4];
        acc += (bfv4(v0) + bfv4(v1)) + (bfv4(v2) + bfv4(v3));
    }
    for (; e < end; ++e) acc += bfv4(base[(long)src[e] * R4]);
    return acc;
}

// ---------------- f32 gather core (layers 3/4) ----------------
template <int G>
__device__ __forceinline__ f32x4 gather_sum(const f32x4* __restrict__ tsv,
                                            const int* __restrict__ src,
                                            int beg, int end, int lane) {
    f32x4 acc = {0.f, 0.f, 0.f, 0.f};
    int e = beg;
    for (; e + 8 <= end; e += 8) {
        int s0 = src[e], s1 = src[e + 1], s2 = src[e + 2], s3 = src[e + 3];
        int s4 = src[e + 4], s5 = src[e + 5], s6 = src[e + 6], s7 = src[e + 7];
        f32x4 v0 = tsv[(long)s0 * G + lane], v1 = tsv[(long)s1 * G + lane];
        f32x4 v2 = tsv[(long)s2 * G + lane], v3 = tsv[(long)s3 * G + lane];
        f32x4 v4 = tsv[(long)s4 * G + lane], v5 = tsv[(long)s5 * G + lane];
        f32x4 v6 = tsv[(long)s6 * G + lane], v7 = tsv[(long)s7 * G + lane];
        acc += ((v0 + v1) + (v2 + v3)) + ((v4 + v5) + (v6 + v7));
    }
    for (; e + 2 <= end; e += 2) {
        int s0 = src[e], s1 = src[e + 1];
        acc += tsv[(long)s0 * G + lane] + tsv[(long)s1 * G + lane];
    }
    if (e < end) acc += tsv[(long)src[e] * G + lane];
    return acc;
}

// D=256 bf16 gather, ONE NODE PER WAVE:
// h1 = relu(dinv*sum + b1) -> packed HI-ONLY layout-v2 write (rtile = 512 chunks).
__global__ __launch_bounds__(256) void agg_split256_kernel(const unsigned short* __restrict__ ts,
                                                           const int* __restrict__ row_ptr,
                                                           const int* __restrict__ src_sorted,
                                                           const float* __restrict__ dinv,
                                                           const float* __restrict__ bias,
                                                           unsigned short* __restrict__ out_p,
                                                           int n) {
    int w = threadIdx.x >> 6, l = threadIdx.x & 63;      // 4 nodes/block, 64 lanes/node
    int node = blockIdx.x * 4 + w;
    if (node >= n) return;
    const u16x4* base = (const u16x4*)ts + l;            // row stride 64 u16x4
    f32x4 acc = gather_sum_bf4<64>(base, src_sorted, row_ptr[node], row_ptr[node + 1]);
    float di = dinv[node];
    f32x4 b4 = *(const f32x4*)&bias[l * 4];
    f32x4 v = acc * di + b4;
    u16x4 hi;
#pragma unroll
    for (int j = 0; j < 4; ++j) hi[j] = f2bf(fmaxf(v[j], 0.f));
    // hi-only layout: rtile = 8 kg * 64 chunks = 512; lane covers k=l*4..l*4+3
    int row = node & 15;
    int kg = l >> 3, ks = (l >> 1) & 3, half = l & 1;
    size_t choff = (size_t)(node >> 4) * 512 + (size_t)kg * 64 + row * 4 + ks;
    *(u16x4*)&out_p[choff * 8 + half * 4] = hi;
}

// D=128 bf16 gather (32 lanes/node, u16x4) + fused W3 matvec (128 -> 32)
__global__ __launch_bounds__(256) void agg_fused_w3_kernel(const unsigned short* __restrict__ ts,
                                                           const int* __restrict__ row_ptr,
                                                           const int* __restrict__ src_sorted,
                                                           const float* __restrict__ dinv,
                                                           const float* __restrict__ bias,
                                                           const float* __restrict__ W3,
                                                           float* __restrict__ ts3, int n) {
    __shared__ float W3s[128 * 32];
    __shared__ float hbuf[8][132];    // +4 pad
    for (int i = threadIdx.x; i < 128 * 32; i += 256) W3s[i] = W3[i];
    __syncthreads();
    int g = threadIdx.x >> 5, lane = threadIdx.x & 31;   // 8 nodes/block, 32 lanes/node
    int node = blockIdx.x * 8 + g;
    if (node >= n) return;
    const u16x4* base = (const u16x4*)ts + lane;         // row stride 32 u16x4
    f32x4 acc = gather_sum_bf4<32>(base, src_sorted, row_ptr[node], row_ptr[node + 1]);
    float di = dinv[node];
    f32x4 b4 = *(const f32x4*)&bias[lane * 4];
    f32x4 v = acc * di + b4;
#pragma unroll
    for (int j = 0; j < 4; ++j) v[j] = fmaxf(v[j], 0.f);
    *(f32x4*)&hbuf[g][lane * 4] = v;    // same-wave (32-lane group) DS: in-order
    float aj = 0.f;
#pragma unroll
    for (int k = 0; k < 128; k += 4) {
        f32x4 hv = *(const f32x4*)&hbuf[g][k];
        aj += hv[0] * W3s[k * 32 + lane] + hv[1] * W3s[(k + 1) * 32 + lane]
            + hv[2] * W3s[(k + 2) * 32 + lane] + hv[3] * W3s[(k + 3) * 32 + lane];
    }
    ts3[(long)node * 32 + lane] = aj * di;
}

// D=32 agg + fused Wk matvec: tsk[node] = dinv * (relu(dinv*sum+b3) @ Wk)    (32 -> 8)
__global__ __launch_bounds__(256) void agg_fused_wk_kernel(const float* __restrict__ ts,
                                                           const int* __restrict__ row_ptr,
                                                           const int* __restrict__ src_sorted,
                                                           const float* __restrict__ dinv,
                                                           const float* __restrict__ bias,
                                                           const float* __restrict__ Wk,
                                                           float* __restrict__ tsk, int n) {
    __shared__ float Wks[32 * 8];
    __shared__ float hbuf[32][36];   // +4 pad
    for (int i = threadIdx.x; i < 32 * 8; i += 256) Wks[i] = Wk[i];
    __syncthreads();
    int g = threadIdx.x >> 3, lane = threadIdx.x & 7;
    int node = blockIdx.x * 32 + g;
    if (node >= n) return;
    f32x4 acc = gather_sum<8>((const f32x4*)ts, src_sorted, row_ptr[node], row_ptr[node + 1], lane);
    float di = dinv[node];
    f32x4 b4 = *(const f32x4*)&bias[lane * 4];
    f32x4 v = acc * di + b4;
#pragma unroll
    for (int j = 0; j < 4; ++j) v[j] = fmaxf(v[j], 0.f);
    *(f32x4*)&hbuf[g][lane * 4] = v;
    float aj = 0.f;
#pragma unroll
    for (int k = 0; k < 32; k += 4) {
        f32x4 hv = *(const f32x4*)&hbuf[g][k];
        aj += hv[0] * Wks[k * 8 + lane] + hv[1] * Wks[(k + 1) * 8 + lane]
            + hv[2] * Wks[(k + 2) * 8 + lane] + hv[3] * Wks[(k + 3) * 8 + lane];
    }
    tsk[(long)node * 8 + lane] = aj * di;
}

// D=8: z = relu(dinv*sum + bk)
__global__ __launch_bounds__(256) void agg_plain8_kernel(const float* __restrict__ ts,
                                                         const int* __restrict__ row_ptr,
                                                         const int* __restrict__ src_sorted,
                                                         const float* __restrict__ dinv,
                                                         const float* __restrict__ bias,
                                                         float* __restrict__ z, int n) {
    int g = threadIdx.x >> 1, lane = threadIdx.x & 1;
    int node = blockIdx.x * 128 + g;
    if (node >= n) return;
    f32x4 acc = gather_sum<2>((const f32x4*)ts, src_sorted, row_ptr[node], row_ptr[node + 1], lane);
    float di = dinv[node];
    f32x4 b4 = *(const f32x4*)&bias[lane * 4];
    f32x4 v = acc * di + b4;
#pragma unroll
    for (int j = 0; j < 4; ++j) v[j] = fmaxf(v[j], 0.f);
    *(f32x4*)&z[(long)node * 8 + lane * 4] = v;
}

// ---------------- decoder: out[k,e] = dot(z[s_e], z[d_e]) (identical across k) ----------------
__global__ __launch_bounds__(256) void decoder_kernel(const float* __restrict__ z,
                                                      const int* __restrict__ ei,
                                                      float* __restrict__ out,
                                                      int E, int K) {
    int e = blockIdx.x * blockDim.x + threadIdx.x;
    if (e >= E) return;
    int s = ei[e];
    int d = ei[E + e];
    const f32x4* zv = (const f32x4*)z;
    f32x4 a0 = zv[(long)s * 2], a1 = zv[(long)s * 2 + 1];
    f32x4 b0 = zv[(long)d * 2], b1 = zv[(long)d * 2 + 1];
    f32x4 p = a0 * b0 + a1 * b1;
    float acc = p[0] + p[1] + p[2] + p[3];
    for (int k = 0; k < K; k++) out[(long)k * E + e] = acc;
}

// ---------------- launch ----------------

extern "C" void kernel_launch(void* const* d_in, const int* in_sizes, int n_in,
                              void* d_out, int out_size, void* d_ws, size_t ws_size,
                              hipStream_t stream) {
    const float* x  = (const float*)d_in[0];
    const int*   ei = (const int*)d_in[1];
    const float* W1 = (const float*)d_in[3];
    const float* b1 = (const float*)d_in[4];
    const float* W2 = (const float*)d_in[5];
    const float* b2 = (const float*)d_in[6];
    const float* W3 = (const float*)d_in[7];
    const float* b3 = (const float*)d_in[8];
    const float* Wk = (const float*)d_in[9];
    const float* bk = (const float*)d_in[10];
    float* out = (float*)d_out;

    const int D1 = in_sizes[4];            // 256
    const int D2 = in_sizes[6];            // 128
    const int F  = in_sizes[3] / D1;       // 256
    const int N  = in_sizes[0] / F;        // 50000
    const int E  = in_sizes[1] / 2;        // 800000
    const int K  = out_size / E;           // 8
    const int M  = E + N;                  // edges incl self loops
    const int Mpad = (N + 127) & ~127;     // 50048

    size_t off = 0;
    auto alloc = [&](size_t bytes) -> void* {
        off = (off + 255) & ~(size_t)255;
        void* p = (char*)d_ws + off;
        off += bytes;
        return p;
    };
    int*   cnt        = (int*)alloc((size_t)N * sizeof(int));
    int*   row_ptr    = (int*)alloc((size_t)(N + 1) * sizeof(int));
    int*   cursor     = (int*)alloc((size_t)N * sizeof(int));
    int*   bsum       = (int*)alloc(1024 * sizeof(int));
    float* dinv       = (float*)alloc((size_t)N * sizeof(float));
    int*   src_sorted = (int*)alloc((size_t)M * sizeof(int));
    unsigned short* region_x = (unsigned short*)alloc((size_t)Mpad * 2 * F * sizeof(short));  // xs_pack -> h1s_pack
    float* region_t   = (float*)alloc((size_t)Mpad * 256 * sizeof(float));                    // ts1/ts2 (as bf16)
    unsigned short* Wt1 = (unsigned short*)alloc((size_t)D1 * F * sizeof(short));             // W1_hi packed (131KB)
    unsigned short* Wt2 = (unsigned short*)alloc((size_t)D2 * D1 * sizeof(short));            // W2_hi packed (65KB)
    float* ts3        = (float*)alloc((size_t)Mpad * 32 * sizeof(float));
    float* tsk        = (float*)alloc((size_t)Mpad * 8 * sizeof(float));
    float* z          = (float*)alloc((size_t)Mpad * 8 * sizeof(float));
    (void)ws_size; (void)n_in;

    unsigned short* xs  = region_x;                   // packed A (hi+lo) for GEMM1
    unsigned short* h1s = region_x;                   // packed A (hi only) for GEMM2 (reuse after GEMM1)
    unsigned short* ts1 = (unsigned short*)region_t;  // [Mpad,256] bf16 row-major gather table
    unsigned short* ts2 = (unsigned short*)region_t;  // [Mpad,128] bf16 (ts1 consumed)

    const int nbN = (N + THREADS - 1) / THREADS;          // 196
    const int nbE = (E + THREADS - 1) / THREADS;          // 3125
    const int nbX = (int)(((long)N * 64 + 255) / 256);    // 12500
    const int nbW1 = (D1 * (F / 8) + 255) / 256;          // 32
    const int nbW2 = (D2 * (D1 / 8) + 255) / 256;         // 16
    const int nbG1 = Mpad / 64;                           // 782

    // K1: init_cnt U convert_w1 U convert_w2
    k1_init_convw_kernel<<<nbN + nbW1 + nbW2, THREADS, 0, stream>>>(
        cnt, N, nbN, W1, Wt1, F, D1, nbW1, W2, Wt2, D1, D2);
    // K2: count_edges U convert_x
    k2_count_convx_kernel<<<nbE + nbX, THREADS, 0, stream>>>(ei, cnt, E, nbE, x, xs, N, F);
    // K3-K5: scan + fused prep
    scan_p1_kernel<<<nbN, THREADS, 0, stream>>>(cnt, bsum, N);
    scan_p2_kernel<<<1, 1024, 0, stream>>>(bsum, nbN);
    scan_p3_prep_kernel<<<nbN, THREADS, 0, stream>>>(cnt, bsum, row_ptr, dinv, cursor, src_sorted, N);
    // K6: gemm1 U fill_edges
    k6_gemm_fill_kernel<<<nbG1 + nbE, THREADS, 0, stream>>>(
        xs, Wt1, dinv, ts1, N, D1, nbG1, ei, cursor, src_sorted, E);
    // K7: layer-1 aggregation -> h1s packed hi-only
    agg_split256_kernel<<<(N + 3) / 4, THREADS, 0, stream>>>(ts1, row_ptr, src_sorted, dinv, b1, h1s, N);
    // K8: gemm2 (hi-only A)
    gemm_hi_kernel<128><<<nbG1, THREADS, 0, stream>>>(h1s, Wt2, dinv, ts2, N, D2);
    // K9: layer-2 agg + fused W3
    agg_fused_w3_kernel<<<(N + 7) / 8, THREADS, 0, stream>>>(ts2, row_ptr, src_sorted, dinv, b2, W3, ts3, N);
    // K10-K11: layer 3 agg + fused Wk, final agg
    agg_fused_wk_kernel<<<(N + 31) / 32, THREADS, 0, stream>>>(ts3, row_ptr, src_sorted, dinv, b3, Wk, tsk, N);
    agg_plain8_kernel<<<(N + 127) / 128, THREADS, 0, stream>>>(tsk, row_ptr, src_sorted, dinv, bk, z, N);
    // K12: decoder
    decoder_kernel<<<nbE, THREADS, 0, stream>>>(z, ei, out, E, K);
}

// Round 21
// 301.480 us; speedup vs baseline: 1.8060x; 1.0257x over previous
//
#include <hip/hip_runtime.h>
#include <hip/hip_bf16.h>

#define THREADS 256

typedef __attribute__((ext_vector_type(2))) float f32x2;
typedef __attribute__((ext_vector_type(4))) float f32x4;
typedef __attribute__((ext_vector_type(8))) float f32x8;
typedef __attribute__((ext_vector_type(8))) short short8;
typedef __attribute__((ext_vector_type(4))) unsigned short u16x4;
typedef __attribute__((ext_vector_type(8))) unsigned short u16x8;

__device__ inline unsigned short f2bf(float f) {
    unsigned int u = __builtin_bit_cast(unsigned int, f);
    unsigned int r = (u + 0x7FFFu + ((u >> 16) & 1u)) >> 16;
    return (unsigned short)r;
}
__device__ inline float bf2f(unsigned short h) {
    unsigned int u = ((unsigned int)h) << 16;
    return __builtin_bit_cast(float, u);
}
__device__ __forceinline__ f32x8 bfv8(u16x8 v) {
    f32x8 r;
#pragma unroll
    for (int j = 0; j < 8; ++j) r[j] = bf2f(v[j]);
    return r;
}
__device__ __forceinline__ f32x4 bfv4(u16x4 v) {
    f32x4 r;
#pragma unroll
    for (int j = 0; j < 4; ++j) r[j] = bf2f(v[j]);
    return r;
}

// ---------------- device bodies for fused kernels ----------------

// W [K,N] f32 -> packed B = hi(W) only, fragment-linear (lane-linear layout).
__device__ __forceinline__ void convert_w_body(const float* __restrict__ W,
                                               unsigned short* __restrict__ Bp,
                                               int K, int N, int idx) {
    int cpc = K / 8;
    if (idx >= N * cpc) return;
    int n = idx / cpc, ck = idx % cpc;
    int c = ck * 8;
    u16x8 o;
#pragma unroll
    for (int j = 0; j < 8; ++j) o[j] = f2bf(W[(long)(c + j) * N + n]);
    size_t chunk = ((size_t)(n >> 4) * (K / 32) + (ck >> 2)) * 64 + (ck & 3) * 16 + (n & 15);
    *(u16x8*)&Bp[chunk * 8] = o;
}

// x row -> packed A layout v2 (KA=512 phys = 16 kg of 32 k):
// chunk(row,kg,ks) at rtile*1024 + kg*64 + (row&15)*4 + ks.
__device__ __forceinline__ void convert_x_body(const float* __restrict__ x,
                                               unsigned short* __restrict__ Ap,
                                               int n, int F, long idx) {
    if (idx >= (long)n * 64) return;
    int row = (int)(idx >> 6), c = (int)(idx & 63);
    int kg = c >> 2, ks = c & 3;
    bool ishi = kg < 8;
    int klocal = (kg & 7) * 32 + ks * 8;
    const float* src = &x[(long)row * F + klocal];
    f32x4 v0 = *(const f32x4*)src;
    f32x4 v1 = *(const f32x4*)(src + 4);
    u16x8 o;
#pragma unroll
    for (int j = 0; j < 4; ++j) {
        unsigned short h0 = f2bf(v0[j]);
        unsigned short h1 = f2bf(v1[j]);
        o[j]     = ishi ? h0 : f2bf(v0[j] - bf2f(h0));
        o[j + 4] = ishi ? h1 : f2bf(v1[j] - bf2f(h1));
    }
    size_t chunk = (size_t)(row >> 4) * 1024 + (size_t)kg * 64 + (row & 15) * 4 + ks;
    *(u16x8*)&Ap[chunk * 8] = o;
}

// GEMM1 body, BN=128 column-half: C[:,ch*128:(ch+1)*128] = (A_hi+A_lo) @ B_hi.
// A layout v2 (16 kg, rtile stride 1024 chunks); B lane-linear (8 kg/ctile).
// acc[2][4] = 32 VGPRs -> low register pressure so fill co-blocks keep occupancy.
__device__ __forceinline__ void gemm_pack_body128(const unsigned short* __restrict__ Ap,
                                                  const unsigned short* __restrict__ Bp,
                                                  const float* __restrict__ dinv,
                                                  unsigned short* __restrict__ C,
                                                  int M, int N, int rtg, int ch) {
    const int tid = threadIdx.x;
    const int wave = tid >> 6, l = tid & 63;
    const int wm = wave & 1, wn = wave >> 1;
    const int lr = l & 15, lg = l >> 4;
    const int rt0 = rtg * 4 + wm * 2;
    const int ct0 = ch * 8 + wn * 4;          // 16-col tile index
    const short8* ab = (const short8*)Ap + (size_t)rt0 * 1024 + lr * 4 + lg;
    const short8* bb = (const short8*)Bp + (size_t)ct0 * 512 + l;
    f32x4 acc[2][4] = {};
#pragma unroll
    for (int kgb = 0; kgb < 8; ++kgb) {
        short8 b[4], ah[2], al[2];
#pragma unroll
        for (int ni = 0; ni < 4; ++ni)
            b[ni] = bb[((size_t)ni * 8 + kgb) * 64];
#pragma unroll
        for (int i = 0; i < 2; ++i) {
            ah[i] = ab[((size_t)i * 16 + kgb) * 64];
            al[i] = ab[((size_t)i * 16 + 8 + kgb) * 64];
        }
#pragma unroll
        for (int i = 0; i < 2; ++i)
#pragma unroll
            for (int ni = 0; ni < 4; ++ni)
                acc[i][ni] = __builtin_amdgcn_mfma_f32_16x16x32_bf16(ah[i], b[ni], acc[i][ni], 0, 0, 0);
#pragma unroll
        for (int i = 0; i < 2; ++i)
#pragma unroll
            for (int ni = 0; ni < 4; ++ni)
                acc[i][ni] = __builtin_amdgcn_mfma_f32_16x16x32_bf16(al[i], b[ni], acc[i][ni], 0, 0, 0);
    }
#pragma unroll
    for (int i = 0; i < 2; ++i) {
        int rbase = rtg * 64 + (wm * 2 + i) * 16 + lg * 4;
#pragma unroll
        for (int ni = 0; ni < 4; ++ni) {
            int col = ch * 128 + wn * 64 + ni * 16 + lr;
#pragma unroll
            for (int r = 0; r < 4; ++r) {
                int row = rbase + r;
                if (row < M) C[(long)row * N + col] = f2bf(acc[i][ni][r] * dinv[row]);
            }
        }
    }
}

// ---------------- fused launch-group kernels ----------------

// K1: init_cnt U convert_w(W1) U convert_w(W2)
__global__ __launch_bounds__(256) void k1_init_convw_kernel(int* cnt, int n, int nbI,
                                                            const float* W1, unsigned short* Wt1,
                                                            int F, int D1, int nbW1,
                                                            const float* W2, unsigned short* Wt2,
                                                            int D1b, int D2) {
    int b = blockIdx.x;
    if (b < nbI) {
        int i = b * 256 + threadIdx.x;
        if (i < n) cnt[i] = 1;   // self loop
    } else if (b < nbI + nbW1) {
        convert_w_body(W1, Wt1, F, D1, (b - nbI) * 256 + threadIdx.x);
    } else {
        convert_w_body(W2, Wt2, D1b, D2, (b - nbI - nbW1) * 256 + threadIdx.x);
    }
}

// K2: count_edges U convert_x (independent; atomics hide under streaming)
__global__ __launch_bounds__(256) void k2_count_convx_kernel(const int* ei, int* cnt, int E, int nbC,
                                                             const float* x, unsigned short* Ap,
                                                             int n, int F) {
    int b = blockIdx.x;
    if (b < nbC) {
        int e = b * 256 + threadIdx.x;
        if (e < E) atomicAdd(&cnt[ei[E + e]], 1);   // dst row
    } else {
        convert_x_body(x, Ap, n, F, (long)(b - nbC) * 256 + threadIdx.x);
    }
}

// ---------------- 3-phase multi-block exclusive scan (coalesced) ----------------
__global__ __launch_bounds__(256) void scan_p1_kernel(const int* __restrict__ cnt,
                                                      int* __restrict__ bsum, int n) {
    __shared__ int sh[256];
    int i = blockIdx.x * 256 + threadIdx.x;
    int v = (i < n) ? cnt[i] : 0;
    sh[threadIdx.x] = v;
    __syncthreads();
#pragma unroll
    for (int off = 128; off > 0; off >>= 1) {
        if ((int)threadIdx.x < off) sh[threadIdx.x] += sh[threadIdx.x + off];
        __syncthreads();
    }
    if (threadIdx.x == 0) bsum[blockIdx.x] = sh[0];
}

__global__ __launch_bounds__(1024) void scan_p2_kernel(int* __restrict__ bsum, int nb) {
    __shared__ int sh[1024];
    int v = ((int)threadIdx.x < nb) ? bsum[threadIdx.x] : 0;
    sh[threadIdx.x] = v;
    __syncthreads();
    for (int off = 1; off < 1024; off <<= 1) {
        int t = (threadIdx.x >= (unsigned)off) ? sh[threadIdx.x - off] : 0;
        __syncthreads();
        sh[threadIdx.x] += t;
        __syncthreads();
    }
    if ((int)threadIdx.x < nb) bsum[threadIdx.x] = sh[threadIdx.x] - v;   // exclusive
}

// K5: scan_p3 + prep (dinv, self-loop fill, cursor init) fused
__global__ __launch_bounds__(256) void scan_p3_prep_kernel(const int* __restrict__ cnt,
                                                           const int* __restrict__ bsum,
                                                           int* __restrict__ row_ptr,
                                                           float* __restrict__ dinv,
                                                           int* __restrict__ cursor,
                                                           int* __restrict__ src_sorted, int n) {
    __shared__ int sh[256];
    int i = blockIdx.x * 256 + threadIdx.x;
    int v = (i < n) ? cnt[i] : 0;
    sh[threadIdx.x] = v;
    __syncthreads();
    for (int off = 1; off < 256; off <<= 1) {
        int t = (threadIdx.x >= (unsigned)off) ? sh[threadIdx.x - off] : 0;
        __syncthreads();
        sh[threadIdx.x] += t;
        __syncthreads();
    }
    int excl = sh[threadIdx.x] - v + bsum[blockIdx.x];
    if (i < n) {
        row_ptr[i] = excl;
        dinv[i] = rsqrtf((float)v);
        src_sorted[excl] = i;      // self loop first (deterministic slot)
        cursor[i] = excl + 1;
    }
    if (i == n - 1) row_ptr[n] = excl + v;
}

// K6: gemm1 (BN=128 x 2 column halves) U fill_edges; low VGPR -> high occupancy for both
__global__ __launch_bounds__(256) void k6_gemm_fill_kernel(const unsigned short* __restrict__ Ap,
                                                           const unsigned short* __restrict__ Bp,
                                                           const float* __restrict__ dinv,
                                                           unsigned short* __restrict__ C,
                                                           int M, int N, int nbG,
                                                           const int* __restrict__ ei,
                                                           int* __restrict__ cursor,
                                                           int* __restrict__ src_sorted, int E) {
    if ((int)blockIdx.x < nbG) {
        int gb = blockIdx.x;
        gemm_pack_body128(Ap, Bp, dinv, C, M, N, gb >> 1, gb & 1);
    } else {
        int e = (blockIdx.x - nbG) * 256 + threadIdx.x;
        if (e < E) {
            int s = ei[e];
            int d = ei[E + e];
            int pos = atomicAdd(&cursor[d], 1);
            src_sorted[pos] = s;
        }
    }
}

// GEMM2: C = A_hi @ B_hi (A has only 8 kg of hi; rtile stride = 512 chunks)
template <int BN>
__global__ __launch_bounds__(256) void gemm_hi_kernel(const unsigned short* __restrict__ Ap,
                                                      const unsigned short* __restrict__ Bp,
                                                      const float* __restrict__ dinv,
                                                      unsigned short* __restrict__ C,
                                                      int M, int N) {
    constexpr int NI = BN / 32;
    const int tid = threadIdx.x;
    const int wave = tid >> 6, l = tid & 63;
    const int wm = wave & 1, wn = wave >> 1;
    const int lr = l & 15, lg = l >> 4;
    const int rt0 = blockIdx.x * 4 + wm * 2;
    const int ct0 = wn * NI;
    const short8* ab = (const short8*)Ap + (size_t)rt0 * 512 + lr * 4 + lg;   // 8 kg per rtile
    const short8* bb = (const short8*)Bp + (size_t)ct0 * 512 + l;
    f32x4 acc[2][NI] = {};
#pragma unroll
    for (int kgb = 0; kgb < 8; ++kgb) {
        short8 b[NI], ah[2];
#pragma unroll
        for (int ni = 0; ni < NI; ++ni)
            b[ni] = bb[((size_t)ni * 8 + kgb) * 64];
#pragma unroll
        for (int i = 0; i < 2; ++i)
            ah[i] = ab[((size_t)i * 8 + kgb) * 64];
#pragma unroll
        for (int i = 0; i < 2; ++i)
#pragma unroll
            for (int ni = 0; ni < NI; ++ni)
                acc[i][ni] = __builtin_amdgcn_mfma_f32_16x16x32_bf16(ah[i], b[ni], acc[i][ni], 0, 0, 0);
    }
#pragma unroll
    for (int i = 0; i < 2; ++i) {
        int rbase = blockIdx.x * 64 + (wm * 2 + i) * 16 + lg * 4;
#pragma unroll
        for (int ni = 0; ni < NI; ++ni) {
            int col = wn * (BN / 2) + ni * 16 + lr;
#pragma unroll
            for (int r = 0; r < 4; ++r) {
                int row = rbase + r;
                if (row < M) C[(long)row * N + col] = f2bf(acc[i][ni][r] * dinv[row]);
            }
        }
    }
}

// ---------------- bf16 gather cores ----------------
template <int R4>   // row stride in u16x4 units
__device__ __forceinline__ f32x4 gather_sum_bf4(const u16x4* __restrict__ base,
                                                const int* __restrict__ src,
                                                int beg, int end) {
    f32x4 acc = {0.f, 0.f, 0.f, 0.f};
    int e = beg;
    for (; e + 16 <= end; e += 16) {
        u16x4 v[16];
#pragma unroll
        for (int j = 0; j < 16; ++j) v[j] = base[(long)src[e + j] * R4];
        f32x4 s0 = (bfv4(v[0]) + bfv4(v[1])) + (bfv4(v[2]) + bfv4(v[3]));
        f32x4 s1 = (bfv4(v[4]) + bfv4(v[5])) + (bfv4(v[6]) + bfv4(v[7]));
        f32x4 s2 = (bfv4(v[8]) + bfv4(v[9])) + (bfv4(v[10]) + bfv4(v[11]));
        f32x4 s3 = (bfv4(v[12]) + bfv4(v[13])) + (bfv4(v[14]) + bfv4(v[15]));
        acc += (s0 + s1) + (s2 + s3);
    }
    for (; e + 4 <= end; e += 4) {
        u16x4 v0 = base[(long)src[e] * R4],     v1 = base[(long)src[e + 1] * R4];
        u16x4 v2 = base[(long)src[e + 2] * R4], v3 = base[(long)src[e + 3] * R4];
        acc += (bfv4(v0) + bfv4(v1)) + (bfv4(v2) + bfv4(v3));
    }
    for (; e < end; ++e) acc += bfv4(base[(long)src[e] * R4]);
    return acc;
}

// ---------------- f32 gather core (layers 3/4) ----------------
template <int G>
__device__ __forceinline__ f32x4 gather_sum(const f32x4* __restrict__ tsv,
                                            const int* __restrict__ src,
                                            int beg, int end, int lane) {
    f32x4 acc = {0.f, 0.f, 0.f, 0.f};
    int e = beg;
    for (; e + 8 <= end; e += 8) {
        int s0 = src[e], s1 = src[e + 1], s2 = src[e + 2], s3 = src[e + 3];
        int s4 = src[e + 4], s5 = src[e + 5], s6 = src[e + 6], s7 = src[e + 7];
        f32x4 v0 = tsv[(long)s0 * G + lane], v1 = tsv[(long)s1 * G + lane];
        f32x4 v2 = tsv[(long)s2 * G + lane], v3 = tsv[(long)s3 * G + lane];
        f32x4 v4 = tsv[(long)s4 * G + lane], v5 = tsv[(long)s5 * G + lane];
        f32x4 v6 = tsv[(long)s6 * G + lane], v7 = tsv[(long)s7 * G + lane];
        acc += ((v0 + v1) + (v2 + v3)) + ((v4 + v5) + (v6 + v7));
    }
    for (; e + 2 <= end; e += 2) {
        int s0 = src[e], s1 = src[e + 1];
        acc += tsv[(long)s0 * G + lane] + tsv[(long)s1 * G + lane];
    }
    if (e < end) acc += tsv[(long)src[e] * G + lane];
    return acc;
}

// D=256 bf16 gather, ONE NODE PER WAVE:
// h1 = relu(dinv*sum + b1) -> packed HI-ONLY layout-v2 write (rtile = 512 chunks).
__global__ __launch_bounds__(256) void agg_split256_kernel(const unsigned short* __restrict__ ts,
                                                           const int* __restrict__ row_ptr,
                                                           const int* __restrict__ src_sorted,
                                                           const float* __restrict__ dinv,
                                                           const float* __restrict__ bias,
                                                           unsigned short* __restrict__ out_p,
                                                           int n) {
    int w = threadIdx.x >> 6, l = threadIdx.x & 63;      // 4 nodes/block, 64 lanes/node
    int node = blockIdx.x * 4 + w;
    if (node >= n) return;
    const u16x4* base = (const u16x4*)ts + l;            // row stride 64 u16x4
    f32x4 acc = gather_sum_bf4<64>(base, src_sorted, row_ptr[node], row_ptr[node + 1]);
    float di = dinv[node];
    f32x4 b4 = *(const f32x4*)&bias[l * 4];
    f32x4 v = acc * di + b4;
    u16x4 hi;
#pragma unroll
    for (int j = 0; j < 4; ++j) hi[j] = f2bf(fmaxf(v[j], 0.f));
    // hi-only layout: rtile = 8 kg * 64 chunks = 512; lane covers k=l*4..l*4+3
    int row = node & 15;
    int kg = l >> 3, ks = (l >> 1) & 3, half = l & 1;
    size_t choff = (size_t)(node >> 4) * 512 + (size_t)kg * 64 + row * 4 + ks;
    *(u16x4*)&out_p[choff * 8 + half * 4] = hi;
}

// D=128 bf16 gather (32 lanes/node, u16x4) + fused W3 matvec (128 -> 32)
__global__ __launch_bounds__(256) void agg_fused_w3_kernel(const unsigned short* __restrict__ ts,
                                                           const int* __restrict__ row_ptr,
                                                           const int* __restrict__ src_sorted,
                                                           const float* __restrict__ dinv,
                                                           const float* __restrict__ bias,
                                                           const float* __restrict__ W3,
                                                           float* __restrict__ ts3, int n) {
    __shared__ float W3s[128 * 32];
    __shared__ float hbuf[8][132];    // +4 pad
    for (int i = threadIdx.x; i < 128 * 32; i += 256) W3s[i] = W3[i];
    __syncthreads();
    int g = threadIdx.x >> 5, lane = threadIdx.x & 31;   // 8 nodes/block, 32 lanes/node
    int node = blockIdx.x * 8 + g;
    if (node >= n) return;
    const u16x4* base = (const u16x4*)ts + lane;         // row stride 32 u16x4
    f32x4 acc = gather_sum_bf4<32>(base, src_sorted, row_ptr[node], row_ptr[node + 1]);
    float di = dinv[node];
    f32x4 b4 = *(const f32x4*)&bias[lane * 4];
    f32x4 v = acc * di + b4;
#pragma unroll
    for (int j = 0; j < 4; ++j) v[j] = fmaxf(v[j], 0.f);
    *(f32x4*)&hbuf[g][lane * 4] = v;    // same-wave (32-lane group) DS: in-order
    float aj = 0.f;
#pragma unroll
    for (int k = 0; k < 128; k += 4) {
        f32x4 hv = *(const f32x4*)&hbuf[g][k];
        aj += hv[0] * W3s[k * 32 + lane] + hv[1] * W3s[(k + 1) * 32 + lane]
            + hv[2] * W3s[(k + 2) * 32 + lane] + hv[3] * W3s[(k + 3) * 32 + lane];
    }
    ts3[(long)node * 32 + lane] = aj * di;
}

// D=32 agg + fused Wk matvec: tsk[node] = dinv * (relu(dinv*sum+b3) @ Wk)    (32 -> 8)
__global__ __launch_bounds__(256) void agg_fused_wk_kernel(const float* __restrict__ ts,
                                                           const int* __restrict__ row_ptr,
                                                           const int* __restrict__ src_sorted,
                                                           const float* __restrict__ dinv,
                                                           const float* __restrict__ bias,
                                                           const float* __restrict__ Wk,
                                                           float* __restrict__ tsk, int n) {
    __shared__ float Wks[32 * 8];
    __shared__ float hbuf[32][36];   // +4 pad
    for (int i = threadIdx.x; i < 32 * 8; i += 256) Wks[i] = Wk[i];
    __syncthreads();
    int g = threadIdx.x >> 3, lane = threadIdx.x & 7;
    int node = blockIdx.x * 32 + g;
    if (node >= n) return;
    f32x4 acc = gather_sum<8>((const f32x4*)ts, src_sorted, row_ptr[node], row_ptr[node + 1], lane);
    float di = dinv[node];
    f32x4 b4 = *(const f32x4*)&bias[lane * 4];
    f32x4 v = acc * di + b4;
#pragma unroll
    for (int j = 0; j < 4; ++j) v[j] = fmaxf(v[j], 0.f);
    *(f32x4*)&hbuf[g][lane * 4] = v;
    float aj = 0.f;
#pragma unroll
    for (int k = 0; k < 32; k += 4) {
        f32x4 hv = *(const f32x4*)&hbuf[g][k];
        aj += hv[0] * Wks[k * 8 + lane] + hv[1] * Wks[(k + 1) * 8 + lane]
            + hv[2] * Wks[(k + 2) * 8 + lane] + hv[3] * Wks[(k + 3) * 8 + lane];
    }
    tsk[(long)node * 8 + lane] = aj * di;
}

// D=8: z = relu(dinv*sum + bk)
__global__ __launch_bounds__(256) void agg_plain8_kernel(const float* __restrict__ ts,
                                                         const int* __restrict__ row_ptr,
                                                         const int* __restrict__ src_sorted,
                                                         const float* __restrict__ dinv,
                                                         const float* __restrict__ bias,
                                                         float* __restrict__ z, int n) {
    int g = threadIdx.x >> 1, lane = threadIdx.x & 1;
    int node = blockIdx.x * 128 + g;
    if (node >= n) return;
    f32x4 acc = gather_sum<2>((const f32x4*)ts, src_sorted, row_ptr[node], row_ptr[node + 1], lane);
    float di = dinv[node];
    f32x4 b4 = *(const f32x4*)&bias[lane * 4];
    f32x4 v = acc * di + b4;
#pragma unroll
    for (int j = 0; j < 4; ++j) v[j] = fmaxf(v[j], 0.f);
    *(f32x4*)&z[(long)node * 8 + lane * 4] = v;
}

// ---------------- decoder: out[k,e] = dot(z[s_e], z[d_e]) (identical across k) ----------------
__global__ __launch_bounds__(256) void decoder_kernel(const float* __restrict__ z,
                                                      const int* __restrict__ ei,
                                                      float* __restrict__ out,
                                                      int E, int K) {
    int e = blockIdx.x * blockDim.x + threadIdx.x;
    if (e >= E) return;
    int s = ei[e];
    int d = ei[E + e];
    const f32x4* zv = (const f32x4*)z;
    f32x4 a0 = zv[(long)s * 2], a1 = zv[(long)s * 2 + 1];
    f32x4 b0 = zv[(long)d * 2], b1 = zv[(long)d * 2 + 1];
    f32x4 p = a0 * b0 + a1 * b1;
    float acc = p[0] + p[1] + p[2] + p[3];
    for (int k = 0; k < K; k++) out[(long)k * E + e] = acc;
}

// ---------------- launch ----------------

extern "C" void kernel_launch(void* const* d_in, const int* in_sizes, int n_in,
                              void* d_out, int out_size, void* d_ws, size_t ws_size,
                              hipStream_t stream) {
    const float* x  = (const float*)d_in[0];
    const int*   ei = (const int*)d_in[1];
    const float* W1 = (const float*)d_in[3];
    const float* b1 = (const float*)d_in[4];
    const float* W2 = (const float*)d_in[5];
    const float* b2 = (const float*)d_in[6];
    const float* W3 = (const float*)d_in[7];
    const float* b3 = (const float*)d_in[8];
    const float* Wk = (const float*)d_in[9];
    const float* bk = (const float*)d_in[10];
    float* out = (float*)d_out;

    const int D1 = in_sizes[4];            // 256
    const int D2 = in_sizes[6];            // 128
    const int F  = in_sizes[3] / D1;       // 256
    const int N  = in_sizes[0] / F;        // 50000
    const int E  = in_sizes[1] / 2;        // 800000
    const int K  = out_size / E;           // 8
    const int M  = E + N;                  // edges incl self loops
    const int Mpad = (N + 127) & ~127;     // 50048

    size_t off = 0;
    auto alloc = [&](size_t bytes) -> void* {
        off = (off + 255) & ~(size_t)255;
        void* p = (char*)d_ws + off;
        off += bytes;
        return p;
    };
    int*   cnt        = (int*)alloc((size_t)N * sizeof(int));
    int*   row_ptr    = (int*)alloc((size_t)(N + 1) * sizeof(int));
    int*   cursor     = (int*)alloc((size_t)N * sizeof(int));
    int*   bsum       = (int*)alloc(1024 * sizeof(int));
    float* dinv       = (float*)alloc((size_t)N * sizeof(float));
    int*   src_sorted = (int*)alloc((size_t)M * sizeof(int));
    unsigned short* region_x = (unsigned short*)alloc((size_t)Mpad * 2 * F * sizeof(short));  // xs_pack -> h1s_pack
    float* region_t   = (float*)alloc((size_t)Mpad * 256 * sizeof(float));                    // ts1/ts2 (as bf16)
    unsigned short* Wt1 = (unsigned short*)alloc((size_t)D1 * F * sizeof(short));             // W1_hi packed (131KB)
    unsigned short* Wt2 = (unsigned short*)alloc((size_t)D2 * D1 * sizeof(short));            // W2_hi packed (65KB)
    float* ts3        = (float*)alloc((size_t)Mpad * 32 * sizeof(float));
    float* tsk        = (float*)alloc((size_t)Mpad * 8 * sizeof(float));
    float* z          = (float*)alloc((size_t)Mpad * 8 * sizeof(float));
    (void)ws_size; (void)n_in;

    unsigned short* xs  = region_x;                   // packed A (hi+lo) for GEMM1
    unsigned short* h1s = region_x;                   // packed A (hi only) for GEMM2 (reuse after GEMM1)
    unsigned short* ts1 = (unsigned short*)region_t;  // [Mpad,256] bf16 row-major gather table
    unsigned short* ts2 = (unsigned short*)region_t;  // [Mpad,128] bf16 (ts1 consumed)

    const int nbN = (N + THREADS - 1) / THREADS;          // 196
    const int nbE = (E + THREADS - 1) / THREADS;          // 3125
    const int nbX = (int)(((long)N * 64 + 255) / 256);    // 12500
    const int nbW1 = (D1 * (F / 8) + 255) / 256;          // 32
    const int nbW2 = (D2 * (D1 / 8) + 255) / 256;         // 16
    const int nbG1 = Mpad / 64;                           // 782
    const int nbG6 = 2 * nbG1;                            // 1564 (two column halves)

    // K1: init_cnt U convert_w1 U convert_w2
    k1_init_convw_kernel<<<nbN + nbW1 + nbW2, THREADS, 0, stream>>>(
        cnt, N, nbN, W1, Wt1, F, D1, nbW1, W2, Wt2, D1, D2);
    // K2: count_edges U convert_x
    k2_count_convx_kernel<<<nbE + nbX, THREADS, 0, stream>>>(ei, cnt, E, nbE, x, xs, N, F);
    // K3-K5: scan + fused prep
    scan_p1_kernel<<<nbN, THREADS, 0, stream>>>(cnt, bsum, N);
    scan_p2_kernel<<<1, 1024, 0, stream>>>(bsum, nbN);
    scan_p3_prep_kernel<<<nbN, THREADS, 0, stream>>>(cnt, bsum, row_ptr, dinv, cursor, src_sorted, N);
    // K6: gemm1 (BN=128 x2) U fill_edges
    k6_gemm_fill_kernel<<<nbG6 + nbE, THREADS, 0, stream>>>(
        xs, Wt1, dinv, ts1, N, D1, nbG6, ei, cursor, src_sorted, E);
    // K7: layer-1 aggregation -> h1s packed hi-only
    agg_split256_kernel<<<(N + 3) / 4, THREADS, 0, stream>>>(ts1, row_ptr, src_sorted, dinv, b1, h1s, N);
    // K8: gemm2 (hi-only A)
    gemm_hi_kernel<128><<<nbG1, THREADS, 0, stream>>>(h1s, Wt2, dinv, ts2, N, D2);
    // K9: layer-2 agg + fused W3
    agg_fused_w3_kernel<<<(N + 7) / 8, THREADS, 0, stream>>>(ts2, row_ptr, src_sorted, dinv, b2, W3, ts3, N);
    // K10-K11: layer 3 agg + fused Wk, final agg
    agg_fused_wk_kernel<<<(N + 31) / 32, THREADS, 0, stream>>>(ts3, row_ptr, src_sorted, dinv, b3, Wk, tsk, N);
    agg_plain8_kernel<<<(N + 127) / 128, THREADS, 0, stream>>>(tsk, row_ptr, src_sorted, dinv, bk, z, N);
    // K12: decoder
    decoder_kernel<<<nbE, THREADS, 0, stream>>>(z, ei, out, E, K);
}

// Round 22
// 289.071 us; speedup vs baseline: 1.8836x; 1.0429x over previous
//
#include <hip/hip_runtime.h>
#include <hip/hip_bf16.h>

#define THREADS 256

typedef __attribute__((ext_vector_type(2))) float f32x2;
typedef __attribute__((ext_vector_type(4))) float f32x4;
typedef __attribute__((ext_vector_type(8))) float f32x8;
typedef __attribute__((ext_vector_type(8))) short short8;
typedef __attribute__((ext_vector_type(4))) unsigned short u16x4;
typedef __attribute__((ext_vector_type(8))) unsigned short u16x8;

__device__ inline unsigned short f2bf(float f) {
    unsigned int u = __builtin_bit_cast(unsigned int, f);
    unsigned int r = (u + 0x7FFFu + ((u >> 16) & 1u)) >> 16;
    return (unsigned short)r;
}
__device__ inline float bf2f(unsigned short h) {
    unsigned int u = ((unsigned int)h) << 16;
    return __builtin_bit_cast(float, u);
}
__device__ __forceinline__ f32x8 bfv8(u16x8 v) {
    f32x8 r;
#pragma unroll
    for (int j = 0; j < 8; ++j) r[j] = bf2f(v[j]);
    return r;
}
__device__ __forceinline__ f32x4 bfv4(u16x4 v) {
    f32x4 r;
#pragma unroll
    for (int j = 0; j < 4; ++j) r[j] = bf2f(v[j]);
    return r;
}

// ---------------- device bodies for fused kernels ----------------

// W [K,N] f32 -> packed B = hi(W) only, fragment-linear (lane-linear layout).
__device__ __forceinline__ void convert_w_body(const float* __restrict__ W,
                                               unsigned short* __restrict__ Bp,
                                               int K, int N, int idx) {
    int cpc = K / 8;
    if (idx >= N * cpc) return;
    int n = idx / cpc, ck = idx % cpc;
    int c = ck * 8;
    u16x8 o;
#pragma unroll
    for (int j = 0; j < 8; ++j) o[j] = f2bf(W[(long)(c + j) * N + n]);
    size_t chunk = ((size_t)(n >> 4) * (K / 32) + (ck >> 2)) * 64 + (ck & 3) * 16 + (n & 15);
    *(u16x8*)&Bp[chunk * 8] = o;
}

// x row -> packed A layout v2 (KA=512 phys = 16 kg of 32 k):
// chunk(row,kg,ks) at rtile*1024 + kg*64 + (row&15)*4 + ks.
__device__ __forceinline__ void convert_x_body(const float* __restrict__ x,
                                               unsigned short* __restrict__ Ap,
                                               int n, int F, long idx) {
    if (idx >= (long)n * 64) return;
    int row = (int)(idx >> 6), c = (int)(idx & 63);
    int kg = c >> 2, ks = c & 3;
    bool ishi = kg < 8;
    int klocal = (kg & 7) * 32 + ks * 8;
    const float* src = &x[(long)row * F + klocal];
    f32x4 v0 = *(const f32x4*)src;
    f32x4 v1 = *(const f32x4*)(src + 4);
    u16x8 o;
#pragma unroll
    for (int j = 0; j < 4; ++j) {
        unsigned short h0 = f2bf(v0[j]);
        unsigned short h1 = f2bf(v1[j]);
        o[j]     = ishi ? h0 : f2bf(v0[j] - bf2f(h0));
        o[j + 4] = ishi ? h1 : f2bf(v1[j] - bf2f(h1));
    }
    size_t chunk = (size_t)(row >> 4) * 1024 + (size_t)kg * 64 + (row & 15) * 4 + ks;
    *(u16x8*)&Ap[chunk * 8] = o;
}

// GEMM1 body, BN=128 column-half: C[:,ch*128:(ch+1)*128] = (A_hi+A_lo) @ B_hi.
// acc[2][4] = 32 VGPRs -> low register pressure so fill co-blocks keep occupancy.
__device__ __forceinline__ void gemm_pack_body128(const unsigned short* __restrict__ Ap,
                                                  const unsigned short* __restrict__ Bp,
                                                  const float* __restrict__ dinv,
                                                  unsigned short* __restrict__ C,
                                                  int M, int N, int rtg, int ch) {
    const int tid = threadIdx.x;
    const int wave = tid >> 6, l = tid & 63;
    const int wm = wave & 1, wn = wave >> 1;
    const int lr = l & 15, lg = l >> 4;
    const int rt0 = rtg * 4 + wm * 2;
    const int ct0 = ch * 8 + wn * 4;          // 16-col tile index
    const short8* ab = (const short8*)Ap + (size_t)rt0 * 1024 + lr * 4 + lg;
    const short8* bb = (const short8*)Bp + (size_t)ct0 * 512 + l;
    f32x4 acc[2][4] = {};
#pragma unroll
    for (int kgb = 0; kgb < 8; ++kgb) {
        short8 b[4], ah[2], al[2];
#pragma unroll
        for (int ni = 0; ni < 4; ++ni)
            b[ni] = bb[((size_t)ni * 8 + kgb) * 64];
#pragma unroll
        for (int i = 0; i < 2; ++i) {
            ah[i] = ab[((size_t)i * 16 + kgb) * 64];
            al[i] = ab[((size_t)i * 16 + 8 + kgb) * 64];
        }
#pragma unroll
        for (int i = 0; i < 2; ++i)
#pragma unroll
            for (int ni = 0; ni < 4; ++ni)
                acc[i][ni] = __builtin_amdgcn_mfma_f32_16x16x32_bf16(ah[i], b[ni], acc[i][ni], 0, 0, 0);
#pragma unroll
        for (int i = 0; i < 2; ++i)
#pragma unroll
            for (int ni = 0; ni < 4; ++ni)
                acc[i][ni] = __builtin_amdgcn_mfma_f32_16x16x32_bf16(al[i], b[ni], acc[i][ni], 0, 0, 0);
    }
#pragma unroll
    for (int i = 0; i < 2; ++i) {
        int rbase = rtg * 64 + (wm * 2 + i) * 16 + lg * 4;
#pragma unroll
        for (int ni = 0; ni < 4; ++ni) {
            int col = ch * 128 + wn * 64 + ni * 16 + lr;
#pragma unroll
            for (int r = 0; r < 4; ++r) {
                int row = rbase + r;
                if (row < M) C[(long)row * N + col] = f2bf(acc[i][ni][r] * dinv[row]);
            }
        }
    }
}

// ---------------- fused launch-group kernels ----------------

// K1: init_cnt U convert_w(W1) U convert_w(W2)
__global__ __launch_bounds__(256) void k1_init_convw_kernel(int* cnt, int n, int nbI,
                                                            const float* W1, unsigned short* Wt1,
                                                            int F, int D1, int nbW1,
                                                            const float* W2, unsigned short* Wt2,
                                                            int D1b, int D2) {
    int b = blockIdx.x;
    if (b < nbI) {
        int i = b * 256 + threadIdx.x;
        if (i < n) cnt[i] = 1;   // self loop
    } else if (b < nbI + nbW1) {
        convert_w_body(W1, Wt1, F, D1, (b - nbI) * 256 + threadIdx.x);
    } else {
        convert_w_body(W2, Wt2, D1b, D2, (b - nbI - nbW1) * 256 + threadIdx.x);
    }
}

// K2: count_edges U convert_x (independent; atomics hide under streaming)
__global__ __launch_bounds__(256) void k2_count_convx_kernel(const int* ei, int* cnt, int E, int nbC,
                                                             const float* x, unsigned short* Ap,
                                                             int n, int F) {
    int b = blockIdx.x;
    if (b < nbC) {
        int e = b * 256 + threadIdx.x;
        if (e < E) atomicAdd(&cnt[ei[E + e]], 1);   // dst row
    } else {
        convert_x_body(x, Ap, n, F, (long)(b - nbC) * 256 + threadIdx.x);
    }
}

// ---------------- 3-phase multi-block exclusive scan (coalesced) ----------------
__global__ __launch_bounds__(256) void scan_p1_kernel(const int* __restrict__ cnt,
                                                      int* __restrict__ bsum, int n) {
    __shared__ int sh[256];
    int i = blockIdx.x * 256 + threadIdx.x;
    int v = (i < n) ? cnt[i] : 0;
    sh[threadIdx.x] = v;
    __syncthreads();
#pragma unroll
    for (int off = 128; off > 0; off >>= 1) {
        if ((int)threadIdx.x < off) sh[threadIdx.x] += sh[threadIdx.x + off];
        __syncthreads();
    }
    if (threadIdx.x == 0) bsum[blockIdx.x] = sh[0];
}

__global__ __launch_bounds__(1024) void scan_p2_kernel(int* __restrict__ bsum, int nb) {
    __shared__ int sh[1024];
    int v = ((int)threadIdx.x < nb) ? bsum[threadIdx.x] : 0;
    sh[threadIdx.x] = v;
    __syncthreads();
    for (int off = 1; off < 1024; off <<= 1) {
        int t = (threadIdx.x >= (unsigned)off) ? sh[threadIdx.x - off] : 0;
        __syncthreads();
        sh[threadIdx.x] += t;
        __syncthreads();
    }
    if ((int)threadIdx.x < nb) bsum[threadIdx.x] = sh[threadIdx.x] - v;   // exclusive
}

// K5: scan_p3 + prep (dinv, self-loop fill, cursor init) fused
__global__ __launch_bounds__(256) void scan_p3_prep_kernel(const int* __restrict__ cnt,
                                                           const int* __restrict__ bsum,
                                                           int* __restrict__ row_ptr,
                                                           float* __restrict__ dinv,
                                                           int* __restrict__ cursor,
                                                           unsigned short* __restrict__ src_sorted, int n) {
    __shared__ int sh[256];
    int i = blockIdx.x * 256 + threadIdx.x;
    int v = (i < n) ? cnt[i] : 0;
    sh[threadIdx.x] = v;
    __syncthreads();
    for (int off = 1; off < 256; off <<= 1) {
        int t = (threadIdx.x >= (unsigned)off) ? sh[threadIdx.x - off] : 0;
        __syncthreads();
        sh[threadIdx.x] += t;
        __syncthreads();
    }
    int excl = sh[threadIdx.x] - v + bsum[blockIdx.x];
    if (i < n) {
        row_ptr[i] = excl;
        dinv[i] = rsqrtf((float)v);
        src_sorted[excl] = (unsigned short)i;   // self loop first (deterministic slot)
        cursor[i] = excl + 1;
    }
    if (i == n - 1) row_ptr[n] = excl + v;
}

// K6: gemm1 (BN=128 x 2 column halves) U fill_edges (2 edges/thread, u16 stores)
__global__ __launch_bounds__(256) void k6_gemm_fill_kernel(const unsigned short* __restrict__ Ap,
                                                           const unsigned short* __restrict__ Bp,
                                                           const float* __restrict__ dinv,
                                                           unsigned short* __restrict__ C,
                                                           int M, int N, int nbG,
                                                           const int* __restrict__ ei,
                                                           int* __restrict__ cursor,
                                                           unsigned short* __restrict__ src_sorted, int E) {
    if ((int)blockIdx.x < nbG) {
        int gb = blockIdx.x;
        gemm_pack_body128(Ap, Bp, dinv, C, M, N, gb >> 1, gb & 1);
    } else {
        int base = (blockIdx.x - nbG) * 512 + threadIdx.x;
#pragma unroll
        for (int t = 0; t < 2; ++t) {
            int e = base + t * 256;
            if (e < E) {
                int s = ei[e];
                int d = ei[E + e];
                int pos = atomicAdd(&cursor[d], 1);
                src_sorted[pos] = (unsigned short)s;
            }
        }
    }
}

// GEMM2: C = A_hi @ B_hi (A has only 8 kg of hi; rtile stride = 512 chunks)
template <int BN>
__global__ __launch_bounds__(256) void gemm_hi_kernel(const unsigned short* __restrict__ Ap,
                                                      const unsigned short* __restrict__ Bp,
                                                      const float* __restrict__ dinv,
                                                      unsigned short* __restrict__ C,
                                                      int M, int N) {
    constexpr int NI = BN / 32;
    const int tid = threadIdx.x;
    const int wave = tid >> 6, l = tid & 63;
    const int wm = wave & 1, wn = wave >> 1;
    const int lr = l & 15, lg = l >> 4;
    const int rt0 = blockIdx.x * 4 + wm * 2;
    const int ct0 = wn * NI;
    const short8* ab = (const short8*)Ap + (size_t)rt0 * 512 + lr * 4 + lg;   // 8 kg per rtile
    const short8* bb = (const short8*)Bp + (size_t)ct0 * 512 + l;
    f32x4 acc[2][NI] = {};
#pragma unroll
    for (int kgb = 0; kgb < 8; ++kgb) {
        short8 b[NI], ah[2];
#pragma unroll
        for (int ni = 0; ni < NI; ++ni)
            b[ni] = bb[((size_t)ni * 8 + kgb) * 64];
#pragma unroll
        for (int i = 0; i < 2; ++i)
            ah[i] = ab[((size_t)i * 8 + kgb) * 64];
#pragma unroll
        for (int i = 0; i < 2; ++i)
#pragma unroll
            for (int ni = 0; ni < NI; ++ni)
                acc[i][ni] = __builtin_amdgcn_mfma_f32_16x16x32_bf16(ah[i], b[ni], acc[i][ni], 0, 0, 0);
    }
#pragma unroll
    for (int i = 0; i < 2; ++i) {
        int rbase = blockIdx.x * 64 + (wm * 2 + i) * 16 + lg * 4;
#pragma unroll
        for (int ni = 0; ni < NI; ++ni) {
            int col = wn * (BN / 2) + ni * 16 + lr;
#pragma unroll
            for (int r = 0; r < 4; ++r) {
                int row = rbase + r;
                if (row < M) C[(long)row * N + col] = f2bf(acc[i][ni][r] * dinv[row]);
            }
        }
    }
}

// ---------------- bf16 gather cores (u16 src indices) ----------------
template <int R4>   // row stride in u16x4 units
__device__ __forceinline__ f32x4 gather_sum_bf4(const u16x4* __restrict__ base,
                                                const unsigned short* __restrict__ src,
                                                int beg, int end) {
    f32x4 acc = {0.f, 0.f, 0.f, 0.f};
    int e = beg;
    for (; e + 16 <= end; e += 16) {
        u16x4 v[16];
#pragma unroll
        for (int j = 0; j < 16; ++j) v[j] = base[(long)src[e + j] * R4];
        f32x4 s0 = (bfv4(v[0]) + bfv4(v[1])) + (bfv4(v[2]) + bfv4(v[3]));
        f32x4 s1 = (bfv4(v[4]) + bfv4(v[5])) + (bfv4(v[6]) + bfv4(v[7]));
        f32x4 s2 = (bfv4(v[8]) + bfv4(v[9])) + (bfv4(v[10]) + bfv4(v[11]));
        f32x4 s3 = (bfv4(v[12]) + bfv4(v[13])) + (bfv4(v[14]) + bfv4(v[15]));
        acc += (s0 + s1) + (s2 + s3);
    }
    for (; e + 4 <= end; e += 4) {
        u16x4 v0 = base[(long)src[e] * R4],     v1 = base[(long)src[e + 1] * R4];
        u16x4 v2 = base[(long)src[e + 2] * R4], v3 = base[(long)src[e + 3] * R4];
        acc += (bfv4(v0) + bfv4(v1)) + (bfv4(v2) + bfv4(v3));
    }
    for (; e < end; ++e) acc += bfv4(base[(long)src[e] * R4]);
    return acc;
}

// ---------------- f32 gather core (layers 3/4, u16 src) ----------------
template <int G>
__device__ __forceinline__ f32x4 gather_sum(const f32x4* __restrict__ tsv,
                                            const unsigned short* __restrict__ src,
                                            int beg, int end, int lane) {
    f32x4 acc = {0.f, 0.f, 0.f, 0.f};
    int e = beg;
    for (; e + 8 <= end; e += 8) {
        int s0 = src[e], s1 = src[e + 1], s2 = src[e + 2], s3 = src[e + 3];
        int s4 = src[e + 4], s5 = src[e + 5], s6 = src[e + 6], s7 = src[e + 7];
        f32x4 v0 = tsv[(long)s0 * G + lane], v1 = tsv[(long)s1 * G + lane];
        f32x4 v2 = tsv[(long)s2 * G + lane], v3 = tsv[(long)s3 * G + lane];
        f32x4 v4 = tsv[(long)s4 * G + lane], v5 = tsv[(long)s5 * G + lane];
        f32x4 v6 = tsv[(long)s6 * G + lane], v7 = tsv[(long)s7 * G + lane];
        acc += ((v0 + v1) + (v2 + v3)) + ((v4 + v5) + (v6 + v7));
    }
    for (; e + 2 <= end; e += 2) {
        int s0 = src[e], s1 = src[e + 1];
        acc += tsv[(long)s0 * G + lane] + tsv[(long)s1 * G + lane];
    }
    if (e < end) acc += tsv[(long)src[e] * G + lane];
    return acc;
}

// D=256 bf16 gather, ONE NODE PER WAVE:
// h1 = relu(dinv*sum + b1) -> packed HI-ONLY layout-v2 write (rtile = 512 chunks).
__global__ __launch_bounds__(256) void agg_split256_kernel(const unsigned short* __restrict__ ts,
                                                           const int* __restrict__ row_ptr,
                                                           const unsigned short* __restrict__ src_sorted,
                                                           const float* __restrict__ dinv,
                                                           const float* __restrict__ bias,
                                                           unsigned short* __restrict__ out_p,
                                                           int n) {
    int w = threadIdx.x >> 6, l = threadIdx.x & 63;      // 4 nodes/block, 64 lanes/node
    int node = blockIdx.x * 4 + w;
    if (node >= n) return;
    const u16x4* base = (const u16x4*)ts + l;            // row stride 64 u16x4
    f32x4 acc = gather_sum_bf4<64>(base, src_sorted, row_ptr[node], row_ptr[node + 1]);
    float di = dinv[node];
    f32x4 b4 = *(const f32x4*)&bias[l * 4];
    f32x4 v = acc * di + b4;
    u16x4 hi;
#pragma unroll
    for (int j = 0; j < 4; ++j) hi[j] = f2bf(fmaxf(v[j], 0.f));
    // hi-only layout: rtile = 8 kg * 64 chunks = 512; lane covers k=l*4..l*4+3
    int row = node & 15;
    int kg = l >> 3, ks = (l >> 1) & 3, half = l & 1;
    size_t choff = (size_t)(node >> 4) * 512 + (size_t)kg * 64 + row * 4 + ks;
    *(u16x4*)&out_p[choff * 8 + half * 4] = hi;
}

// D=128 bf16 gather (32 lanes/node, u16x4) + fused W3 matvec (128 -> 32)
__global__ __launch_bounds__(256) void agg_fused_w3_kernel(const unsigned short* __restrict__ ts,
                                                           const int* __restrict__ row_ptr,
                                                           const unsigned short* __restrict__ src_sorted,
                                                           const float* __restrict__ dinv,
                                                           const float* __restrict__ bias,
                                                           const float* __restrict__ W3,
                                                           float* __restrict__ ts3, int n) {
    __shared__ float W3s[128 * 32];
    __shared__ float hbuf[8][132];    // +4 pad
    for (int i = threadIdx.x; i < 128 * 32; i += 256) W3s[i] = W3[i];
    __syncthreads();
    int g = threadIdx.x >> 5, lane = threadIdx.x & 31;   // 8 nodes/block, 32 lanes/node
    int node = blockIdx.x * 8 + g;
    if (node >= n) return;
    const u16x4* base = (const u16x4*)ts + lane;         // row stride 32 u16x4
    f32x4 acc = gather_sum_bf4<32>(base, src_sorted, row_ptr[node], row_ptr[node + 1]);
    float di = dinv[node];
    f32x4 b4 = *(const f32x4*)&bias[lane * 4];
    f32x4 v = acc * di + b4;
#pragma unroll
    for (int j = 0; j < 4; ++j) v[j] = fmaxf(v[j], 0.f);
    *(f32x4*)&hbuf[g][lane * 4] = v;    // same-wave (32-lane group) DS: in-order
    float aj = 0.f;
#pragma unroll
    for (int k = 0; k < 128; k += 4) {
        f32x4 hv = *(const f32x4*)&hbuf[g][k];
        aj += hv[0] * W3s[k * 32 + lane] + hv[1] * W3s[(k + 1) * 32 + lane]
            + hv[2] * W3s[(k + 2) * 32 + lane] + hv[3] * W3s[(k + 3) * 32 + lane];
    }
    ts3[(long)node * 32 + lane] = aj * di;
}

// D=32 agg + fused Wk matvec: tsk[node] = dinv * (relu(dinv*sum+b3) @ Wk)    (32 -> 8)
__global__ __launch_bounds__(256) void agg_fused_wk_kernel(const float* __restrict__ ts,
                                                           const int* __restrict__ row_ptr,
                                                           const unsigned short* __restrict__ src_sorted,
                                                           const float* __restrict__ dinv,
                                                           const float* __restrict__ bias,
                                                           const float* __restrict__ Wk,
                                                           float* __restrict__ tsk, int n) {
    __shared__ float Wks[32 * 8];
    __shared__ float hbuf[32][36];   // +4 pad
    for (int i = threadIdx.x; i < 32 * 8; i += 256) Wks[i] = Wk[i];
    __syncthreads();
    int g = threadIdx.x >> 3, lane = threadIdx.x & 7;
    int node = blockIdx.x * 32 + g;
    if (node >= n) return;
    f32x4 acc = gather_sum<8>((const f32x4*)ts, src_sorted, row_ptr[node], row_ptr[node + 1], lane);
    float di = dinv[node];
    f32x4 b4 = *(const f32x4*)&bias[lane * 4];
    f32x4 v = acc * di + b4;
#pragma unroll
    for (int j = 0; j < 4; ++j) v[j] = fmaxf(v[j], 0.f);
    *(f32x4*)&hbuf[g][lane * 4] = v;
    float aj = 0.f;
#pragma unroll
    for (int k = 0; k < 32; k += 4) {
        f32x4 hv = *(const f32x4*)&hbuf[g][k];
        aj += hv[0] * Wks[k * 8 + lane] + hv[1] * Wks[(k + 1) * 8 + lane]
            + hv[2] * Wks[(k + 2) * 8 + lane] + hv[3] * Wks[(k + 3) * 8 + lane];
    }
    tsk[(long)node * 8 + lane] = aj * di;
}

// D=8: z = relu(dinv*sum + bk)
__global__ __launch_bounds__(256) void agg_plain8_kernel(const float* __restrict__ ts,
                                                         const int* __restrict__ row_ptr,
                                                         const unsigned short* __restrict__ src_sorted,
                                                         const float* __restrict__ dinv,
                                                         const float* __restrict__ bias,
                                                         float* __restrict__ z, int n) {
    int g = threadIdx.x >> 1, lane = threadIdx.x & 1;
    int node = blockIdx.x * 128 + g;
    if (node >= n) return;
    f32x4 acc = gather_sum<2>((const f32x4*)ts, src_sorted, row_ptr[node], row_ptr[node + 1], lane);
    float di = dinv[node];
    f32x4 b4 = *(const f32x4*)&bias[lane * 4];
    f32x4 v = acc * di + b4;
#pragma unroll
    for (int j = 0; j < 4; ++j) v[j] = fmaxf(v[j], 0.f);
    *(f32x4*)&z[(long)node * 8 + lane * 4] = v;
}

// ---------------- decoder: out[k,e] = dot(z[s_e], z[d_e]) (identical across k) ----------------
__global__ __launch_bounds__(256) void decoder_kernel(const float* __restrict__ z,
                                                      const int* __restrict__ ei,
                                                      float* __restrict__ out,
                                                      int E, int K) {
    int e = blockIdx.x * blockDim.x + threadIdx.x;
    if (e >= E) return;
    int s = ei[e];
    int d = ei[E + e];
    const f32x4* zv = (const f32x4*)z;
    f32x4 a0 = zv[(long)s * 2], a1 = zv[(long)s * 2 + 1];
    f32x4 b0 = zv[(long)d * 2], b1 = zv[(long)d * 2 + 1];
    f32x4 p = a0 * b0 + a1 * b1;
    float acc = p[0] + p[1] + p[2] + p[3];
    for (int k = 0; k < K; k++) out[(long)k * E + e] = acc;
}

// ---------------- launch ----------------

extern "C" void kernel_launch(void* const* d_in, const int* in_sizes, int n_in,
                              void* d_out, int out_size, void* d_ws, size_t ws_size,
                              hipStream_t stream) {
    const float* x  = (const float*)d_in[0];
    const int*   ei = (const int*)d_in[1];
    const float* W1 = (const float*)d_in[3];
    const float* b1 = (const float*)d_in[4];
    const float* W2 = (const float*)d_in[5];
    const float* b2 = (const float*)d_in[6];
    const float* W3 = (const float*)d_in[7];
    const float* b3 = (const float*)d_in[8];
    const float* Wk = (const float*)d_in[9];
    const float* bk = (const float*)d_in[10];
    float* out = (float*)d_out;

    const int D1 = in_sizes[4];            // 256
    const int D2 = in_sizes[6];            // 128
    const int F  = in_sizes[3] / D1;       // 256
    const int N  = in_sizes[0] / F;        // 50000
    const int E  = in_sizes[1] / 2;        // 800000
    const int K  = out_size / E;           // 8
    const int M  = E + N;                  // edges incl self loops
    const int Mpad = (N + 127) & ~127;     // 50048

    size_t off = 0;
    auto alloc = [&](size_t bytes) -> void* {
        off = (off + 255) & ~(size_t)255;
        void* p = (char*)d_ws + off;
        off += bytes;
        return p;
    };
    int*   cnt        = (int*)alloc((size_t)N * sizeof(int));
    int*   row_ptr    = (int*)alloc((size_t)(N + 1) * sizeof(int));
    int*   cursor     = (int*)alloc((size_t)N * sizeof(int));
    int*   bsum       = (int*)alloc(1024 * sizeof(int));
    float* dinv       = (float*)alloc((size_t)N * sizeof(float));
    unsigned short* src_sorted = (unsigned short*)alloc((size_t)M * sizeof(unsigned short));
    unsigned short* region_x = (unsigned short*)alloc((size_t)Mpad * 2 * F * sizeof(short));  // xs_pack -> h1s_pack
    float* region_t   = (float*)alloc((size_t)Mpad * 256 * sizeof(float));                    // ts1/ts2 (as bf16)
    unsigned short* Wt1 = (unsigned short*)alloc((size_t)D1 * F * sizeof(short));             // W1_hi packed (131KB)
    unsigned short* Wt2 = (unsigned short*)alloc((size_t)D2 * D1 * sizeof(short));            // W2_hi packed (65KB)
    float* ts3        = (float*)alloc((size_t)Mpad * 32 * sizeof(float));
    float* tsk        = (float*)alloc((size_t)Mpad * 8 * sizeof(float));
    float* z          = (float*)alloc((size_t)Mpad * 8 * sizeof(float));
    (void)ws_size; (void)n_in;

    unsigned short* xs  = region_x;                   // packed A (hi+lo) for GEMM1
    unsigned short* h1s = region_x;                   // packed A (hi only) for GEMM2 (reuse after GEMM1)
    unsigned short* ts1 = (unsigned short*)region_t;  // [Mpad,256] bf16 row-major gather table
    unsigned short* ts2 = (unsigned short*)region_t;  // [Mpad,128] bf16 (ts1 consumed)

    const int nbN = (N + THREADS - 1) / THREADS;          // 196
    const int nbE = (E + THREADS - 1) / THREADS;          // 3125
    const int nbE2 = (E + 511) / 512;                     // 1563 (2 edges/thread)
    const int nbX = (int)(((long)N * 64 + 255) / 256);    // 12500
    const int nbW1 = (D1 * (F / 8) + 255) / 256;          // 32
    const int nbW2 = (D2 * (D1 / 8) + 255) / 256;         // 16
    const int nbG1 = Mpad / 64;                           // 782
    const int nbG6 = 2 * nbG1;                            // 1564 (two column halves)

    // K1: init_cnt U convert_w1 U convert_w2
    k1_init_convw_kernel<<<nbN + nbW1 + nbW2, THREADS, 0, stream>>>(
        cnt, N, nbN, W1, Wt1, F, D1, nbW1, W2, Wt2, D1, D2);
    // K2: count_edges U convert_x
    k2_count_convx_kernel<<<nbE + nbX, THREADS, 0, stream>>>(ei, cnt, E, nbE, x, xs, N, F);
    // K3-K5: scan + fused prep
    scan_p1_kernel<<<nbN, THREADS, 0, stream>>>(cnt, bsum, N);
    scan_p2_kernel<<<1, 1024, 0, stream>>>(bsum, nbN);
    scan_p3_prep_kernel<<<nbN, THREADS, 0, stream>>>(cnt, bsum, row_ptr, dinv, cursor, src_sorted, N);
    // K6: gemm1 (BN=128 x2) U fill_edges (2 edges/thread, u16)
    k6_gemm_fill_kernel<<<nbG6 + nbE2, THREADS, 0, stream>>>(
        xs, Wt1, dinv, ts1, N, D1, nbG6, ei, cursor, src_sorted, E);
    // K7: layer-1 aggregation -> h1s packed hi-only
    agg_split256_kernel<<<(N + 3) / 4, THREADS, 0, stream>>>(ts1, row_ptr, src_sorted, dinv, b1, h1s, N);
    // K8: gemm2 (hi-only A)
    gemm_hi_kernel<128><<<nbG1, THREADS, 0, stream>>>(h1s, Wt2, dinv, ts2, N, D2);
    // K9: layer-2 agg + fused W3
    agg_fused_w3_kernel<<<(N + 7) / 8, THREADS, 0, stream>>>(ts2, row_ptr, src_sorted, dinv, b2, W3, ts3, N);
    // K10-K11: layer 3 agg + fused Wk, final agg
    agg_fused_wk_kernel<<<(N + 31) / 32, THREADS, 0, stream>>>(ts3, row_ptr, src_sorted, dinv, b3, Wk, tsk, N);
    agg_plain8_kernel<<<(N + 127) / 128, THREADS, 0, stream>>>(tsk, row_ptr, src_sorted, dinv, bk, z, N);
    // K12: decoder
    decoder_kernel<<<nbE, THREADS, 0, stream>>>(z, ei, out, E, K);
}

// Round 23
// 263.770 us; speedup vs baseline: 2.0642x; 1.0959x over previous
//
#include <hip/hip_runtime.h>
#include <hip/hip_bf16.h>

#define THREADS 256

typedef __attribute__((ext_vector_type(2))) float f32x2;
typedef __attribute__((ext_vector_type(4))) float f32x4;
typedef __attribute__((ext_vector_type(8))) float f32x8;
typedef __attribute__((ext_vector_type(8))) short short8;
typedef __attribute__((ext_vector_type(4))) unsigned short u16x4;
typedef __attribute__((ext_vector_type(8))) unsigned short u16x8;

__device__ inline unsigned short f2bf(float f) {
    unsigned int u = __builtin_bit_cast(unsigned int, f);
    unsigned int r = (u + 0x7FFFu + ((u >> 16) & 1u)) >> 16;
    return (unsigned short)r;
}
__device__ inline float bf2f(unsigned short h) {
    unsigned int u = ((unsigned int)h) << 16;
    return __builtin_bit_cast(float, u);
}
__device__ __forceinline__ f32x8 bfv8(u16x8 v) {
    f32x8 r;
#pragma unroll
    for (int j = 0; j < 8; ++j) r[j] = bf2f(v[j]);
    return r;
}
__device__ __forceinline__ f32x4 bfv4(u16x4 v) {
    f32x4 r;
#pragma unroll
    for (int j = 0; j < 4; ++j) r[j] = bf2f(v[j]);
    return r;
}

// ---------------- device bodies for fused kernels ----------------

// W [K,N] f32 -> packed B = hi(W) only, fragment-linear (lane-linear layout).
__device__ __forceinline__ void convert_w_body(const float* __restrict__ W,
                                               unsigned short* __restrict__ Bp,
                                               int K, int N, int idx) {
    int cpc = K / 8;
    if (idx >= N * cpc) return;
    int n = idx / cpc, ck = idx % cpc;
    int c = ck * 8;
    u16x8 o;
#pragma unroll
    for (int j = 0; j < 8; ++j) o[j] = f2bf(W[(long)(c + j) * N + n]);
    size_t chunk = ((size_t)(n >> 4) * (K / 32) + (ck >> 2)) * 64 + (ck & 3) * 16 + (n & 15);
    *(u16x8*)&Bp[chunk * 8] = o;
}

// x row -> packed A layout v2 (KA=512 phys = 16 kg of 32 k):
// chunk(row,kg,ks) at rtile*1024 + kg*64 + (row&15)*4 + ks.
__device__ __forceinline__ void convert_x_body(const float* __restrict__ x,
                                               unsigned short* __restrict__ Ap,
                                               int n, int F, long idx) {
    if (idx >= (long)n * 64) return;
    int row = (int)(idx >> 6), c = (int)(idx & 63);
    int kg = c >> 2, ks = c & 3;
    bool ishi = kg < 8;
    int klocal = (kg & 7) * 32 + ks * 8;
    const float* src = &x[(long)row * F + klocal];
    f32x4 v0 = *(const f32x4*)src;
    f32x4 v1 = *(const f32x4*)(src + 4);
    u16x8 o;
#pragma unroll
    for (int j = 0; j < 4; ++j) {
        unsigned short h0 = f2bf(v0[j]);
        unsigned short h1 = f2bf(v1[j]);
        o[j]     = ishi ? h0 : f2bf(v0[j] - bf2f(h0));
        o[j + 4] = ishi ? h1 : f2bf(v1[j] - bf2f(h1));
    }
    size_t chunk = (size_t)(row >> 4) * 1024 + (size_t)kg * 64 + (row & 15) * 4 + ks;
    *(u16x8*)&Ap[chunk * 8] = o;
}

// GEMM1 body, BN=128 column-half: C[:,ch*128:(ch+1)*128] = (A_hi+A_lo) @ B_hi.
// acc[2][4] = 32 VGPRs -> low register pressure so fill co-blocks keep occupancy.
__device__ __forceinline__ void gemm_pack_body128(const unsigned short* __restrict__ Ap,
                                                  const unsigned short* __restrict__ Bp,
                                                  const float* __restrict__ dinv,
                                                  unsigned short* __restrict__ C,
                                                  int M, int N, int rtg, int ch) {
    const int tid = threadIdx.x;
    const int wave = tid >> 6, l = tid & 63;
    const int wm = wave & 1, wn = wave >> 1;
    const int lr = l & 15, lg = l >> 4;
    const int rt0 = rtg * 4 + wm * 2;
    const int ct0 = ch * 8 + wn * 4;          // 16-col tile index
    const short8* ab = (const short8*)Ap + (size_t)rt0 * 1024 + lr * 4 + lg;
    const short8* bb = (const short8*)Bp + (size_t)ct0 * 512 + l;
    f32x4 acc[2][4] = {};
#pragma unroll
    for (int kgb = 0; kgb < 8; ++kgb) {
        short8 b[4], ah[2], al[2];
#pragma unroll
        for (int ni = 0; ni < 4; ++ni)
            b[ni] = bb[((size_t)ni * 8 + kgb) * 64];
#pragma unroll
        for (int i = 0; i < 2; ++i) {
            ah[i] = ab[((size_t)i * 16 + kgb) * 64];
            al[i] = ab[((size_t)i * 16 + 8 + kgb) * 64];
        }
#pragma unroll
        for (int i = 0; i < 2; ++i)
#pragma unroll
            for (int ni = 0; ni < 4; ++ni)
                acc[i][ni] = __builtin_amdgcn_mfma_f32_16x16x32_bf16(ah[i], b[ni], acc[i][ni], 0, 0, 0);
#pragma unroll
        for (int i = 0; i < 2; ++i)
#pragma unroll
            for (int ni = 0; ni < 4; ++ni)
                acc[i][ni] = __builtin_amdgcn_mfma_f32_16x16x32_bf16(al[i], b[ni], acc[i][ni], 0, 0, 0);
    }
#pragma unroll
    for (int i = 0; i < 2; ++i) {
        int rbase = rtg * 64 + (wm * 2 + i) * 16 + lg * 4;
#pragma unroll
        for (int ni = 0; ni < 4; ++ni) {
            int col = ch * 128 + wn * 64 + ni * 16 + lr;
#pragma unroll
            for (int r = 0; r < 4; ++r) {
                int row = rbase + r;
                if (row < M) C[(long)row * N + col] = f2bf(acc[i][ni][r] * dinv[row]);
            }
        }
    }
}

// ---------------- fused launch-group kernels ----------------

// K1: init_cnt U convert_w(W1) U convert_w(W2)
__global__ __launch_bounds__(256) void k1_init_convw_kernel(int* cnt, int n, int nbI,
                                                            const float* W1, unsigned short* Wt1,
                                                            int F, int D1, int nbW1,
                                                            const float* W2, unsigned short* Wt2,
                                                            int D1b, int D2) {
    int b = blockIdx.x;
    if (b < nbI) {
        int i = b * 256 + threadIdx.x;
        if (i < n) cnt[i] = 1;   // self loop
    } else if (b < nbI + nbW1) {
        convert_w_body(W1, Wt1, F, D1, (b - nbI) * 256 + threadIdx.x);
    } else {
        convert_w_body(W2, Wt2, D1b, D2, (b - nbI - nbW1) * 256 + threadIdx.x);
    }
}

// K2: count_edges (records per-edge ordinal = atomic return) U convert_x
__global__ __launch_bounds__(256) void k2_count_convx_kernel(const int* ei, int* cnt,
                                                             unsigned short* __restrict__ ord,
                                                             int E, int nbC,
                                                             const float* x, unsigned short* Ap,
                                                             int n, int F) {
    int b = blockIdx.x;
    if (b < nbC) {
        int e = b * 256 + threadIdx.x;
        if (e < E) {
            int old = atomicAdd(&cnt[ei[E + e]], 1);   // dst row; old in [1,deg] (self loop=slot 0)
            ord[e] = (unsigned short)old;
        }
    } else {
        convert_x_body(x, Ap, n, F, (long)(b - nbC) * 256 + threadIdx.x);
    }
}

// ---------------- 3-phase multi-block exclusive scan (coalesced) ----------------
__global__ __launch_bounds__(256) void scan_p1_kernel(const int* __restrict__ cnt,
                                                      int* __restrict__ bsum, int n) {
    __shared__ int sh[256];
    int i = blockIdx.x * 256 + threadIdx.x;
    int v = (i < n) ? cnt[i] : 0;
    sh[threadIdx.x] = v;
    __syncthreads();
#pragma unroll
    for (int off = 128; off > 0; off >>= 1) {
        if ((int)threadIdx.x < off) sh[threadIdx.x] += sh[threadIdx.x + off];
        __syncthreads();
    }
    if (threadIdx.x == 0) bsum[blockIdx.x] = sh[0];
}

__global__ __launch_bounds__(1024) void scan_p2_kernel(int* __restrict__ bsum, int nb) {
    __shared__ int sh[1024];
    int v = ((int)threadIdx.x < nb) ? bsum[threadIdx.x] : 0;
    sh[threadIdx.x] = v;
    __syncthreads();
    for (int off = 1; off < 1024; off <<= 1) {
        int t = (threadIdx.x >= (unsigned)off) ? sh[threadIdx.x - off] : 0;
        __syncthreads();
        sh[threadIdx.x] += t;
        __syncthreads();
    }
    if ((int)threadIdx.x < nb) bsum[threadIdx.x] = sh[threadIdx.x] - v;   // exclusive
}

// K5: scan_p3 + prep (dinv, self-loop fill) fused — no cursor needed anymore
__global__ __launch_bounds__(256) void scan_p3_prep_kernel(const int* __restrict__ cnt,
                                                           const int* __restrict__ bsum,
                                                           int* __restrict__ row_ptr,
                                                           float* __restrict__ dinv,
                                                           unsigned short* __restrict__ src_sorted, int n) {
    __shared__ int sh[256];
    int i = blockIdx.x * 256 + threadIdx.x;
    int v = (i < n) ? cnt[i] : 0;
    sh[threadIdx.x] = v;
    __syncthreads();
    for (int off = 1; off < 256; off <<= 1) {
        int t = (threadIdx.x >= (unsigned)off) ? sh[threadIdx.x - off] : 0;
        __syncthreads();
        sh[threadIdx.x] += t;
        __syncthreads();
    }
    int excl = sh[threadIdx.x] - v + bsum[blockIdx.x];
    if (i < n) {
        row_ptr[i] = excl;
        dinv[i] = rsqrtf((float)v);
        src_sorted[excl] = (unsigned short)i;   // self loop: slot 0 of the row
    }
    if (i == n - 1) row_ptr[n] = excl + v;
}

// K6: gemm1 (BN=128 x 2 column halves) U fill_edges (ATOMIC-FREE scatter via precomputed ordinal)
__global__ __launch_bounds__(256) void k6_gemm_fill_kernel(const unsigned short* __restrict__ Ap,
                                                           const unsigned short* __restrict__ Bp,
                                                           const float* __restrict__ dinv,
                                                           unsigned short* __restrict__ C,
                                                           int M, int N, int nbG,
                                                           const int* __restrict__ ei,
                                                           const int* __restrict__ row_ptr,
                                                           const unsigned short* __restrict__ ord,
                                                           unsigned short* __restrict__ src_sorted, int E) {
    if ((int)blockIdx.x < nbG) {
        int gb = blockIdx.x;
        gemm_pack_body128(Ap, Bp, dinv, C, M, N, gb >> 1, gb & 1);
    } else {
        int base = (blockIdx.x - nbG) * 512 + threadIdx.x;
#pragma unroll
        for (int t = 0; t < 2; ++t) {
            int e = base + t * 256;
            if (e < E) {
                int s = ei[e];
                int d = ei[E + e];
                src_sorted[row_ptr[d] + ord[e]] = (unsigned short)s;   // no atomic
            }
        }
    }
}

// GEMM2: C = A_hi @ B_hi (A has only 8 kg of hi; rtile stride = 512 chunks)
template <int BN>
__global__ __launch_bounds__(256) void gemm_hi_kernel(const unsigned short* __restrict__ Ap,
                                                      const unsigned short* __restrict__ Bp,
                                                      const float* __restrict__ dinv,
                                                      unsigned short* __restrict__ C,
                                                      int M, int N) {
    constexpr int NI = BN / 32;
    const int tid = threadIdx.x;
    const int wave = tid >> 6, l = tid & 63;
    const int wm = wave & 1, wn = wave >> 1;
    const int lr = l & 15, lg = l >> 4;
    const int rt0 = blockIdx.x * 4 + wm * 2;
    const int ct0 = wn * NI;
    const short8* ab = (const short8*)Ap + (size_t)rt0 * 512 + lr * 4 + lg;   // 8 kg per rtile
    const short8* bb = (const short8*)Bp + (size_t)ct0 * 512 + l;
    f32x4 acc[2][NI] = {};
#pragma unroll
    for (int kgb = 0; kgb < 8; ++kgb) {
        short8 b[NI], ah[2];
#pragma unroll
        for (int ni = 0; ni < NI; ++ni)
            b[ni] = bb[((size_t)ni * 8 + kgb) * 64];
#pragma unroll
        for (int i = 0; i < 2; ++i)
            ah[i] = ab[((size_t)i * 8 + kgb) * 64];
#pragma unroll
        for (int i = 0; i < 2; ++i)
#pragma unroll
            for (int ni = 0; ni < NI; ++ni)
                acc[i][ni] = __builtin_amdgcn_mfma_f32_16x16x32_bf16(ah[i], b[ni], acc[i][ni], 0, 0, 0);
    }
#pragma unroll
    for (int i = 0; i < 2; ++i) {
        int rbase = blockIdx.x * 64 + (wm * 2 + i) * 16 + lg * 4;
#pragma unroll
        for (int ni = 0; ni < NI; ++ni) {
            int col = wn * (BN / 2) + ni * 16 + lr;
#pragma unroll
            for (int r = 0; r < 4; ++r) {
                int row = rbase + r;
                if (row < M) C[(long)row * N + col] = f2bf(acc[i][ni][r] * dinv[row]);
            }
        }
    }
}

// ---------------- bf16 gather cores (u16 src indices) ----------------
template <int R4>   // row stride in u16x4 units
__device__ __forceinline__ f32x4 gather_sum_bf4(const u16x4* __restrict__ base,
                                                const unsigned short* __restrict__ src,
                                                int beg, int end) {
    f32x4 acc = {0.f, 0.f, 0.f, 0.f};
    int e = beg;
    for (; e + 16 <= end; e += 16) {
        u16x4 v[16];
#pragma unroll
        for (int j = 0; j < 16; ++j) v[j] = base[(long)src[e + j] * R4];
        f32x4 s0 = (bfv4(v[0]) + bfv4(v[1])) + (bfv4(v[2]) + bfv4(v[3]));
        f32x4 s1 = (bfv4(v[4]) + bfv4(v[5])) + (bfv4(v[6]) + bfv4(v[7]));
        f32x4 s2 = (bfv4(v[8]) + bfv4(v[9])) + (bfv4(v[10]) + bfv4(v[11]));
        f32x4 s3 = (bfv4(v[12]) + bfv4(v[13])) + (bfv4(v[14]) + bfv4(v[15]));
        acc += (s0 + s1) + (s2 + s3);
    }
    for (; e + 4 <= end; e += 4) {
        u16x4 v0 = base[(long)src[e] * R4],     v1 = base[(long)src[e + 1] * R4];
        u16x4 v2 = base[(long)src[e + 2] * R4], v3 = base[(long)src[e + 3] * R4];
        acc += (bfv4(v0) + bfv4(v1)) + (bfv4(v2) + bfv4(v3));
    }
    for (; e < end; ++e) acc += bfv4(base[(long)src[e] * R4]);
    return acc;
}

// ---------------- f32 gather core (layers 3/4, u16 src) ----------------
template <int G>
__device__ __forceinline__ f32x4 gather_sum(const f32x4* __restrict__ tsv,
                                            const unsigned short* __restrict__ src,
                                            int beg, int end, int lane) {
    f32x4 acc = {0.f, 0.f, 0.f, 0.f};
    int e = beg;
    for (; e + 8 <= end; e += 8) {
        int s0 = src[e], s1 = src[e + 1], s2 = src[e + 2], s3 = src[e + 3];
        int s4 = src[e + 4], s5 = src[e + 5], s6 = src[e + 6], s7 = src[e + 7];
        f32x4 v0 = tsv[(long)s0 * G + lane], v1 = tsv[(long)s1 * G + lane];
        f32x4 v2 = tsv[(long)s2 * G + lane], v3 = tsv[(long)s3 * G + lane];
        f32x4 v4 = tsv[(long)s4 * G + lane], v5 = tsv[(long)s5 * G + lane];
        f32x4 v6 = tsv[(long)s6 * G + lane], v7 = tsv[(long)s7 * G + lane];
        acc += ((v0 + v1) + (v2 + v3)) + ((v4 + v5) + (v6 + v7));
    }
    for (; e + 2 <= end; e += 2) {
        int s0 = src[e], s1 = src[e + 1];
        acc += tsv[(long)s0 * G + lane] + tsv[(long)s1 * G + lane];
    }
    if (e < end) acc += tsv[(long)src[e] * G + lane];
    return acc;
}

// D=256 bf16 gather, ONE NODE PER WAVE:
// h1 = relu(dinv*sum + b1) -> packed HI-ONLY layout-v2 write (rtile = 512 chunks).
__global__ __launch_bounds__(256) void agg_split256_kernel(const unsigned short* __restrict__ ts,
                                                           const int* __restrict__ row_ptr,
                                                           const unsigned short* __restrict__ src_sorted,
                                                           const float* __restrict__ dinv,
                                                           const float* __restrict__ bias,
                                                           unsigned short* __restrict__ out_p,
                                                           int n) {
    int w = threadIdx.x >> 6, l = threadIdx.x & 63;      // 4 nodes/block, 64 lanes/node
    int node = blockIdx.x * 4 + w;
    if (node >= n) return;
    const u16x4* base = (const u16x4*)ts + l;            // row stride 64 u16x4
    f32x4 acc = gather_sum_bf4<64>(base, src_sorted, row_ptr[node], row_ptr[node + 1]);
    float di = dinv[node];
    f32x4 b4 = *(const f32x4*)&bias[l * 4];
    f32x4 v = acc * di + b4;
    u16x4 hi;
#pragma unroll
    for (int j = 0; j < 4; ++j) hi[j] = f2bf(fmaxf(v[j], 0.f));
    // hi-only layout: rtile = 8 kg * 64 chunks = 512; lane covers k=l*4..l*4+3
    int row = node & 15;
    int kg = l >> 3, ks = (l >> 1) & 3, half = l & 1;
    size_t choff = (size_t)(node >> 4) * 512 + (size_t)kg * 64 + row * 4 + ks;
    *(u16x4*)&out_p[choff * 8 + half * 4] = hi;
}

// D=128 bf16 gather (32 lanes/node, u16x4) + fused W3 matvec (128 -> 32)
__global__ __launch_bounds__(256) void agg_fused_w3_kernel(const unsigned short* __restrict__ ts,
                                                           const int* __restrict__ row_ptr,
                                                           const unsigned short* __restrict__ src_sorted,
                                                           const float* __restrict__ dinv,
                                                           const float* __restrict__ bias,
                                                           const float* __restrict__ W3,
                                                           float* __restrict__ ts3, int n) {
    __shared__ float W3s[128 * 32];
    __shared__ float hbuf[8][132];    // +4 pad
    for (int i = threadIdx.x; i < 128 * 32; i += 256) W3s[i] = W3[i];
    __syncthreads();
    int g = threadIdx.x >> 5, lane = threadIdx.x & 31;   // 8 nodes/block, 32 lanes/node
    int node = blockIdx.x * 8 + g;
    if (node >= n) return;
    const u16x4* base = (const u16x4*)ts + lane;         // row stride 32 u16x4
    f32x4 acc = gather_sum_bf4<32>(base, src_sorted, row_ptr[node], row_ptr[node + 1]);
    float di = dinv[node];
    f32x4 b4 = *(const f32x4*)&bias[lane * 4];
    f32x4 v = acc * di + b4;
#pragma unroll
    for (int j = 0; j < 4; ++j) v[j] = fmaxf(v[j], 0.f);
    *(f32x4*)&hbuf[g][lane * 4] = v;    // same-wave (32-lane group) DS: in-order
    float aj = 0.f;
#pragma unroll
    for (int k = 0; k < 128; k += 4) {
        f32x4 hv = *(const f32x4*)&hbuf[g][k];
        aj += hv[0] * W3s[k * 32 + lane] + hv[1] * W3s[(k + 1) * 32 + lane]
            + hv[2] * W3s[(k + 2) * 32 + lane] + hv[3] * W3s[(k + 3) * 32 + lane];
    }
    ts3[(long)node * 32 + lane] = aj * di;
}

// D=32 agg + fused Wk matvec: tsk[node] = dinv * (relu(dinv*sum+b3) @ Wk)    (32 -> 8)
__global__ __launch_bounds__(256) void agg_fused_wk_kernel(const float* __restrict__ ts,
                                                           const int* __restrict__ row_ptr,
                                                           const unsigned short* __restrict__ src_sorted,
                                                           const float* __restrict__ dinv,
                                                           const float* __restrict__ bias,
                                                           const float* __restrict__ Wk,
                                                           float* __restrict__ tsk, int n) {
    __shared__ float Wks[32 * 8];
    __shared__ float hbuf[32][36];   // +4 pad
    for (int i = threadIdx.x; i < 32 * 8; i += 256) Wks[i] = Wk[i];
    __syncthreads();
    int g = threadIdx.x >> 3, lane = threadIdx.x & 7;
    int node = blockIdx.x * 32 + g;
    if (node >= n) return;
    f32x4 acc = gather_sum<8>((const f32x4*)ts, src_sorted, row_ptr[node], row_ptr[node + 1], lane);
    float di = dinv[node];
    f32x4 b4 = *(const f32x4*)&bias[lane * 4];
    f32x4 v = acc * di + b4;
#pragma unroll
    for (int j = 0; j < 4; ++j) v[j] = fmaxf(v[j], 0.f);
    *(f32x4*)&hbuf[g][lane * 4] = v;
    float aj = 0.f;
#pragma unroll
    for (int k = 0; k < 32; k += 4) {
        f32x4 hv = *(const f32x4*)&hbuf[g][k];
        aj += hv[0] * Wks[k * 8 + lane] + hv[1] * Wks[(k + 1) * 8 + lane]
            + hv[2] * Wks[(k + 2) * 8 + lane] + hv[3] * Wks[(k + 3) * 8 + lane];
    }
    tsk[(long)node * 8 + lane] = aj * di;
}

// D=8: z = relu(dinv*sum + bk)
__global__ __launch_bounds__(256) void agg_plain8_kernel(const float* __restrict__ ts,
                                                         const int* __restrict__ row_ptr,
                                                         const unsigned short* __restrict__ src_sorted,
                                                         const float* __restrict__ dinv,
                                                         const float* __restrict__ bias,
                                                         float* __restrict__ z, int n) {
    int g = threadIdx.x >> 1, lane = threadIdx.x & 1;
    int node = blockIdx.x * 128 + g;
    if (node >= n) return;
    f32x4 acc = gather_sum<2>((const f32x4*)ts, src_sorted, row_ptr[node], row_ptr[node + 1], lane);
    float di = dinv[node];
    f32x4 b4 = *(const f32x4*)&bias[lane * 4];
    f32x4 v = acc * di + b4;
#pragma unroll
    for (int j = 0; j < 4; ++j) v[j] = fmaxf(v[j], 0.f);
    *(f32x4*)&z[(long)node * 8 + lane * 4] = v;
}

// ---------------- decoder: out[k,e] = dot(z[s_e], z[d_e]) (identical across k) ----------------
__global__ __launch_bounds__(256) void decoder_kernel(const float* __restrict__ z,
                                                      const int* __restrict__ ei,
                                                      float* __restrict__ out,
                                                      int E, int K) {
    int e = blockIdx.x * blockDim.x + threadIdx.x;
    if (e >= E) return;
    int s = ei[e];
    int d = ei[E + e];
    const f32x4* zv = (const f32x4*)z;
    f32x4 a0 = zv[(long)s * 2], a1 = zv[(long)s * 2 + 1];
    f32x4 b0 = zv[(long)d * 2], b1 = zv[(long)d * 2 + 1];
    f32x4 p = a0 * b0 + a1 * b1;
    float acc = p[0] + p[1] + p[2] + p[3];
    for (int k = 0; k < K; k++) out[(long)k * E + e] = acc;
}

// ---------------- launch ----------------

extern "C" void kernel_launch(void* const* d_in, const int* in_sizes, int n_in,
                              void* d_out, int out_size, void* d_ws, size_t ws_size,
                              hipStream_t stream) {
    const float* x  = (const float*)d_in[0];
    const int*   ei = (const int*)d_in[1];
    const float* W1 = (const float*)d_in[3];
    const float* b1 = (const float*)d_in[4];
    const float* W2 = (const float*)d_in[5];
    const float* b2 = (const float*)d_in[6];
    const float* W3 = (const float*)d_in[7];
    const float* b3 = (const float*)d_in[8];
    const float* Wk = (const float*)d_in[9];
    const float* bk = (const float*)d_in[10];
    float* out = (float*)d_out;

    const int D1 = in_sizes[4];            // 256
    const int D2 = in_sizes[6];            // 128
    const int F  = in_sizes[3] / D1;       // 256
    const int N  = in_sizes[0] / F;        // 50000
    const int E  = in_sizes[1] / 2;        // 800000
    const int K  = out_size / E;           // 8
    const int M  = E + N;                  // edges incl self loops
    const int Mpad = (N + 127) & ~127;     // 50048

    size_t off = 0;
    auto alloc = [&](size_t bytes) -> void* {
        off = (off + 255) & ~(size_t)255;
        void* p = (char*)d_ws + off;
        off += bytes;
        return p;
    };
    int*   cnt        = (int*)alloc((size_t)N * sizeof(int));
    int*   row_ptr    = (int*)alloc((size_t)(N + 1) * sizeof(int));
    int*   bsum       = (int*)alloc(1024 * sizeof(int));
    float* dinv       = (float*)alloc((size_t)N * sizeof(float));
    unsigned short* ord        = (unsigned short*)alloc((size_t)E * sizeof(unsigned short));
    unsigned short* src_sorted = (unsigned short*)alloc((size_t)M * sizeof(unsigned short));
    unsigned short* region_x = (unsigned short*)alloc((size_t)Mpad * 2 * F * sizeof(short));  // xs_pack -> h1s_pack
    float* region_t   = (float*)alloc((size_t)Mpad * 256 * sizeof(float));                    // ts1/ts2 (as bf16)
    unsigned short* Wt1 = (unsigned short*)alloc((size_t)D1 * F * sizeof(short));             // W1_hi packed (131KB)
    unsigned short* Wt2 = (unsigned short*)alloc((size_t)D2 * D1 * sizeof(short));            // W2_hi packed (65KB)
    float* ts3        = (float*)alloc((size_t)Mpad * 32 * sizeof(float));
    float* tsk        = (float*)alloc((size_t)Mpad * 8 * sizeof(float));
    float* z          = (float*)alloc((size_t)Mpad * 8 * sizeof(float));
    (void)ws_size; (void)n_in;

    unsigned short* xs  = region_x;                   // packed A (hi+lo) for GEMM1
    unsigned short* h1s = region_x;                   // packed A (hi only) for GEMM2 (reuse after GEMM1)
    unsigned short* ts1 = (unsigned short*)region_t;  // [Mpad,256] bf16 row-major gather table
    unsigned short* ts2 = (unsigned short*)region_t;  // [Mpad,128] bf16 (ts1 consumed)

    const int nbN = (N + THREADS - 1) / THREADS;          // 196
    const int nbE = (E + THREADS - 1) / THREADS;          // 3125
    const int nbE2 = (E + 511) / 512;                     // 1563 (2 edges/thread)
    const int nbX = (int)(((long)N * 64 + 255) / 256);    // 12500
    const int nbW1 = (D1 * (F / 8) + 255) / 256;          // 32
    const int nbW2 = (D2 * (D1 / 8) + 255) / 256;         // 16
    const int nbG1 = Mpad / 64;                           // 782
    const int nbG6 = 2 * nbG1;                            // 1564 (two column halves)

    // K1: init_cnt U convert_w1 U convert_w2
    k1_init_convw_kernel<<<nbN + nbW1 + nbW2, THREADS, 0, stream>>>(
        cnt, N, nbN, W1, Wt1, F, D1, nbW1, W2, Wt2, D1, D2);
    // K2: count_edges (+ordinals) U convert_x
    k2_count_convx_kernel<<<nbE + nbX, THREADS, 0, stream>>>(ei, cnt, ord, E, nbE, x, xs, N, F);
    // K3-K5: scan + fused prep
    scan_p1_kernel<<<nbN, THREADS, 0, stream>>>(cnt, bsum, N);
    scan_p2_kernel<<<1, 1024, 0, stream>>>(bsum, nbN);
    scan_p3_prep_kernel<<<nbN, THREADS, 0, stream>>>(cnt, bsum, row_ptr, dinv, src_sorted, N);
    // K6: gemm1 (BN=128 x2) U fill_edges (atomic-free)
    k6_gemm_fill_kernel<<<nbG6 + nbE2, THREADS, 0, stream>>>(
        xs, Wt1, dinv, ts1, N, D1, nbG6, ei, row_ptr, ord, src_sorted, E);
    // K7: layer-1 aggregation -> h1s packed hi-only
    agg_split256_kernel<<<(N + 3) / 4, THREADS, 0, stream>>>(ts1, row_ptr, src_sorted, dinv, b1, h1s, N);
    // K8: gemm2 (hi-only A)
    gemm_hi_kernel<128><<<nbG1, THREADS, 0, stream>>>(h1s, Wt2, dinv, ts2, N, D2);
    // K9: layer-2 agg + fused W3
    agg_fused_w3_kernel<<<(N + 7) / 8, THREADS, 0, stream>>>(ts2, row_ptr, src_sorted, dinv, b2, W3, ts3, N);
    // K10-K11: layer 3 agg + fused Wk, final agg
    agg_fused_wk_kernel<<<(N + 31) / 32, THREADS, 0, stream>>>(ts3, row_ptr, src_sorted, dinv, b3, Wk, tsk, N);
    agg_plain8_kernel<<<(N + 127) / 128, THREADS, 0, stream>>>(tsk, row_ptr, src_sorted, dinv, bk, z, N);
    // K12: decoder
    decoder_kernel<<<nbE, THREADS, 0, stream>>>(z, ei, out, E, K);
}

// Round 24
// 263.312 us; speedup vs baseline: 2.0678x; 1.0017x over previous
//
#include <hip/hip_runtime.h>
#include <hip/hip_bf16.h>

#define THREADS 256

typedef __attribute__((ext_vector_type(2))) float f32x2;
typedef __attribute__((ext_vector_type(4))) float f32x4;
typedef __attribute__((ext_vector_type(8))) float f32x8;
typedef __attribute__((ext_vector_type(8))) short short8;
typedef __attribute__((ext_vector_type(4))) unsigned short u16x4;
typedef __attribute__((ext_vector_type(8))) unsigned short u16x8;

__device__ inline unsigned short f2bf(float f) {
    unsigned int u = __builtin_bit_cast(unsigned int, f);
    unsigned int r = (u + 0x7FFFu + ((u >> 16) & 1u)) >> 16;
    return (unsigned short)r;
}
__device__ inline float bf2f(unsigned short h) {
    unsigned int u = ((unsigned int)h) << 16;
    return __builtin_bit_cast(float, u);
}
__device__ __forceinline__ f32x4 bfv4(u16x4 v) {
    f32x4 r;
#pragma unroll
    for (int j = 0; j < 4; ++j) r[j] = bf2f(v[j]);
    return r;
}

// ---------------- device bodies for fused kernels ----------------

// W [K,N] f32 -> packed B = hi(W) only, fragment-linear (lane-linear layout).
__device__ __forceinline__ void convert_w_body(const float* __restrict__ W,
                                               unsigned short* __restrict__ Bp,
                                               int K, int N, int idx) {
    int cpc = K / 8;
    if (idx >= N * cpc) return;
    int n = idx / cpc, ck = idx % cpc;
    int c = ck * 8;
    u16x8 o;
#pragma unroll
    for (int j = 0; j < 8; ++j) o[j] = f2bf(W[(long)(c + j) * N + n]);
    size_t chunk = ((size_t)(n >> 4) * (K / 32) + (ck >> 2)) * 64 + (ck & 3) * 16 + (n & 15);
    *(u16x8*)&Bp[chunk * 8] = o;
}

// x row -> packed A layout v2 (KA=512 phys = 16 kg of 32 k):
// chunk(row,kg,ks) at rtile*1024 + kg*64 + (row&15)*4 + ks.
__device__ __forceinline__ void convert_x_body(const float* __restrict__ x,
                                               unsigned short* __restrict__ Ap,
                                               int n, int F, long idx) {
    if (idx >= (long)n * 64) return;
    int row = (int)(idx >> 6), c = (int)(idx & 63);
    int kg = c >> 2, ks = c & 3;
    bool ishi = kg < 8;
    int klocal = (kg & 7) * 32 + ks * 8;
    const float* src = &x[(long)row * F + klocal];
    f32x4 v0 = *(const f32x4*)src;
    f32x4 v1 = *(const f32x4*)(src + 4);
    u16x8 o;
#pragma unroll
    for (int j = 0; j < 4; ++j) {
        unsigned short h0 = f2bf(v0[j]);
        unsigned short h1 = f2bf(v1[j]);
        o[j]     = ishi ? h0 : f2bf(v0[j] - bf2f(h0));
        o[j + 4] = ishi ? h1 : f2bf(v1[j] - bf2f(h1));
    }
    size_t chunk = (size_t)(row >> 4) * 1024 + (size_t)kg * 64 + (row & 15) * 4 + ks;
    *(u16x8*)&Ap[chunk * 8] = o;
}

// GEMM1 body, BN=128 column-half: C[:,ch*128:(ch+1)*128] = (A_hi+A_lo) @ B_hi.
// acc[2][4] = 32 VGPRs -> low register pressure so fill co-blocks keep occupancy.
__device__ __forceinline__ void gemm_pack_body128(const unsigned short* __restrict__ Ap,
                                                  const unsigned short* __restrict__ Bp,
                                                  const float* __restrict__ dinv,
                                                  unsigned short* __restrict__ C,
                                                  int M, int N, int rtg, int ch) {
    const int tid = threadIdx.x;
    const int wave = tid >> 6, l = tid & 63;
    const int wm = wave & 1, wn = wave >> 1;
    const int lr = l & 15, lg = l >> 4;
    const int rt0 = rtg * 4 + wm * 2;
    const int ct0 = ch * 8 + wn * 4;          // 16-col tile index
    const short8* ab = (const short8*)Ap + (size_t)rt0 * 1024 + lr * 4 + lg;
    const short8* bb = (const short8*)Bp + (size_t)ct0 * 512 + l;
    f32x4 acc[2][4] = {};
#pragma unroll
    for (int kgb = 0; kgb < 8; ++kgb) {
        short8 b[4], ah[2], al[2];
#pragma unroll
        for (int ni = 0; ni < 4; ++ni)
            b[ni] = bb[((size_t)ni * 8 + kgb) * 64];
#pragma unroll
        for (int i = 0; i < 2; ++i) {
            ah[i] = ab[((size_t)i * 16 + kgb) * 64];
            al[i] = ab[((size_t)i * 16 + 8 + kgb) * 64];
        }
#pragma unroll
        for (int i = 0; i < 2; ++i)
#pragma unroll
            for (int ni = 0; ni < 4; ++ni)
                acc[i][ni] = __builtin_amdgcn_mfma_f32_16x16x32_bf16(ah[i], b[ni], acc[i][ni], 0, 0, 0);
#pragma unroll
        for (int i = 0; i < 2; ++i)
#pragma unroll
            for (int ni = 0; ni < 4; ++ni)
                acc[i][ni] = __builtin_amdgcn_mfma_f32_16x16x32_bf16(al[i], b[ni], acc[i][ni], 0, 0, 0);
    }
#pragma unroll
    for (int i = 0; i < 2; ++i) {
        int rbase = rtg * 64 + (wm * 2 + i) * 16 + lg * 4;
#pragma unroll
        for (int ni = 0; ni < 4; ++ni) {
            int col = ch * 128 + wn * 64 + ni * 16 + lr;
#pragma unroll
            for (int r = 0; r < 4; ++r) {
                int row = rbase + r;
                if (row < M) C[(long)row * N + col] = f2bf(acc[i][ni][r] * dinv[row]);
            }
        }
    }
}

// ---------------- fused launch-group kernels ----------------

// K1: init_cnt U convert_w(W1) U convert_w(W2)
__global__ __launch_bounds__(256) void k1_init_convw_kernel(int* cnt, int n, int nbI,
                                                            const float* W1, unsigned short* Wt1,
                                                            int F, int D1, int nbW1,
                                                            const float* W2, unsigned short* Wt2,
                                                            int D1b, int D2) {
    int b = blockIdx.x;
    if (b < nbI) {
        int i = b * 256 + threadIdx.x;
        if (i < n) cnt[i] = 1;   // self loop
    } else if (b < nbI + nbW1) {
        convert_w_body(W1, Wt1, F, D1, (b - nbI) * 256 + threadIdx.x);
    } else {
        convert_w_body(W2, Wt2, D1b, D2, (b - nbI - nbW1) * 256 + threadIdx.x);
    }
}

// K2: count_edges (2 edges/thread, records ordinal = atomic return) U convert_x
__global__ __launch_bounds__(256) void k2_count_convx_kernel(const int* ei, int* cnt,
                                                             unsigned short* __restrict__ ord,
                                                             int E, int nbC,
                                                             const float* x, unsigned short* Ap,
                                                             int n, int F) {
    int b = blockIdx.x;
    if (b < nbC) {
        int base = b * 512 + threadIdx.x;
#pragma unroll
        for (int t = 0; t < 2; ++t) {
            int e = base + t * 256;
            if (e < E) {
                int old = atomicAdd(&cnt[ei[E + e]], 1);   // old in [1,deg] (self loop=slot 0)
                ord[e] = (unsigned short)old;
            }
        }
    } else {
        convert_x_body(x, Ap, n, F, (long)(b - nbC) * 256 + threadIdx.x);
    }
}

// ---------------- 3-phase multi-block exclusive scan (coalesced) ----------------
__global__ __launch_bounds__(256) void scan_p1_kernel(const int* __restrict__ cnt,
                                                      int* __restrict__ bsum, int n) {
    __shared__ int sh[256];
    int i = blockIdx.x * 256 + threadIdx.x;
    int v = (i < n) ? cnt[i] : 0;
    sh[threadIdx.x] = v;
    __syncthreads();
#pragma unroll
    for (int off = 128; off > 0; off >>= 1) {
        if ((int)threadIdx.x < off) sh[threadIdx.x] += sh[threadIdx.x + off];
        __syncthreads();
    }
    if (threadIdx.x == 0) bsum[blockIdx.x] = sh[0];
}

__global__ __launch_bounds__(1024) void scan_p2_kernel(int* __restrict__ bsum, int nb) {
    __shared__ int sh[1024];
    int v = ((int)threadIdx.x < nb) ? bsum[threadIdx.x] : 0;
    sh[threadIdx.x] = v;
    __syncthreads();
    for (int off = 1; off < 1024; off <<= 1) {
        int t = (threadIdx.x >= (unsigned)off) ? sh[threadIdx.x - off] : 0;
        __syncthreads();
        sh[threadIdx.x] += t;
        __syncthreads();
    }
    if ((int)threadIdx.x < nb) bsum[threadIdx.x] = sh[threadIdx.x] - v;   // exclusive
}

// K5: scan_p3 + prep (dinv, self-loop fill) fused
__global__ __launch_bounds__(256) void scan_p3_prep_kernel(const int* __restrict__ cnt,
                                                           const int* __restrict__ bsum,
                                                           int* __restrict__ row_ptr,
                                                           float* __restrict__ dinv,
                                                           unsigned short* __restrict__ src_sorted, int n) {
    __shared__ int sh[256];
    int i = blockIdx.x * 256 + threadIdx.x;
    int v = (i < n) ? cnt[i] : 0;
    sh[threadIdx.x] = v;
    __syncthreads();
    for (int off = 1; off < 256; off <<= 1) {
        int t = (threadIdx.x >= (unsigned)off) ? sh[threadIdx.x - off] : 0;
        __syncthreads();
        sh[threadIdx.x] += t;
        __syncthreads();
    }
    int excl = sh[threadIdx.x] - v + bsum[blockIdx.x];
    if (i < n) {
        row_ptr[i] = excl;
        dinv[i] = rsqrtf((float)v);
        src_sorted[excl] = (unsigned short)i;   // self loop: slot 0 of the row
    }
    if (i == n - 1) row_ptr[n] = excl + v;
}

// K6: gemm1 (BN=128 x 2 column halves) U fill_edges (ATOMIC-FREE scatter via precomputed ordinal)
__global__ __launch_bounds__(256) void k6_gemm_fill_kernel(const unsigned short* __restrict__ Ap,
                                                           const unsigned short* __restrict__ Bp,
                                                           const float* __restrict__ dinv,
                                                           unsigned short* __restrict__ C,
                                                           int M, int N, int nbG,
                                                           const int* __restrict__ ei,
                                                           const int* __restrict__ row_ptr,
                                                           const unsigned short* __restrict__ ord,
                                                           unsigned short* __restrict__ src_sorted, int E) {
    if ((int)blockIdx.x < nbG) {
        int gb = blockIdx.x;
        gemm_pack_body128(Ap, Bp, dinv, C, M, N, gb >> 1, gb & 1);
    } else {
        int base = (blockIdx.x - nbG) * 512 + threadIdx.x;
#pragma unroll
        for (int t = 0; t < 2; ++t) {
            int e = base + t * 256;
            if (e < E) {
                int s = ei[e];
                int d = ei[E + e];
                src_sorted[row_ptr[d] + ord[e]] = (unsigned short)s;   // no atomic
            }
        }
    }
}

// GEMM2: C = A_hi @ B_hi (A has only 8 kg of hi; rtile stride = 512 chunks)
template <int BN>
__global__ __launch_bounds__(256) void gemm_hi_kernel(const unsigned short* __restrict__ Ap,
                                                      const unsigned short* __restrict__ Bp,
                                                      const float* __restrict__ dinv,
                                                      unsigned short* __restrict__ C,
                                                      int M, int N) {
    constexpr int NI = BN / 32;
    const int tid = threadIdx.x;
    const int wave = tid >> 6, l = tid & 63;
    const int wm = wave & 1, wn = wave >> 1;
    const int lr = l & 15, lg = l >> 4;
    const int rt0 = blockIdx.x * 4 + wm * 2;
    const int ct0 = wn * NI;
    const short8* ab = (const short8*)Ap + (size_t)rt0 * 512 + lr * 4 + lg;   // 8 kg per rtile
    const short8* bb = (const short8*)Bp + (size_t)ct0 * 512 + l;
    f32x4 acc[2][NI] = {};
#pragma unroll
    for (int kgb = 0; kgb < 8; ++kgb) {
        short8 b[NI], ah[2];
#pragma unroll
        for (int ni = 0; ni < NI; ++ni)
            b[ni] = bb[((size_t)ni * 8 + kgb) * 64];
#pragma unroll
        for (int i = 0; i < 2; ++i)
            ah[i] = ab[((size_t)i * 8 + kgb) * 64];
#pragma unroll
        for (int i = 0; i < 2; ++i)
#pragma unroll
            for (int ni = 0; ni < NI; ++ni)
                acc[i][ni] = __builtin_amdgcn_mfma_f32_16x16x32_bf16(ah[i], b[ni], acc[i][ni], 0, 0, 0);
    }
#pragma unroll
    for (int i = 0; i < 2; ++i) {
        int rbase = blockIdx.x * 64 + (wm * 2 + i) * 16 + lg * 4;
#pragma unroll
        for (int ni = 0; ni < NI; ++ni) {
            int col = wn * (BN / 2) + ni * 16 + lr;
#pragma unroll
            for (int r = 0; r < 4; ++r) {
                int row = rbase + r;
                if (row < M) C[(long)row * N + col] = f2bf(acc[i][ni][r] * dinv[row]);
            }
        }
    }
}

// ---------------- bf16 gather core (u16 src indices) ----------------
template <int R4>   // row stride in u16x4 units
__device__ __forceinline__ f32x4 gather_sum_bf4(const u16x4* __restrict__ base,
                                                const unsigned short* __restrict__ src,
                                                int beg, int end) {
    f32x4 acc = {0.f, 0.f, 0.f, 0.f};
    int e = beg;
    for (; e + 16 <= end; e += 16) {
        u16x4 v[16];
#pragma unroll
        for (int j = 0; j < 16; ++j) v[j] = base[(long)src[e + j] * R4];
        f32x4 s0 = (bfv4(v[0]) + bfv4(v[1])) + (bfv4(v[2]) + bfv4(v[3]));
        f32x4 s1 = (bfv4(v[4]) + bfv4(v[5])) + (bfv4(v[6]) + bfv4(v[7]));
        f32x4 s2 = (bfv4(v[8]) + bfv4(v[9])) + (bfv4(v[10]) + bfv4(v[11]));
        f32x4 s3 = (bfv4(v[12]) + bfv4(v[13])) + (bfv4(v[14]) + bfv4(v[15]));
        acc += (s0 + s1) + (s2 + s3);
    }
    for (; e + 4 <= end; e += 4) {
        u16x4 v0 = base[(long)src[e] * R4],     v1 = base[(long)src[e + 1] * R4];
        u16x4 v2 = base[(long)src[e + 2] * R4], v3 = base[(long)src[e + 3] * R4];
        acc += (bfv4(v0) + bfv4(v1)) + (bfv4(v2) + bfv4(v3));
    }
    for (; e < end; ++e) acc += bfv4(base[(long)src[e] * R4]);
    return acc;
}

// D=256 bf16 gather, ONE NODE PER WAVE:
// h1 = relu(dinv*sum + b1) -> packed HI-ONLY layout-v2 write (rtile = 512 chunks).
__global__ __launch_bounds__(256) void agg_split256_kernel(const unsigned short* __restrict__ ts,
                                                           const int* __restrict__ row_ptr,
                                                           const unsigned short* __restrict__ src_sorted,
                                                           const float* __restrict__ dinv,
                                                           const float* __restrict__ bias,
                                                           unsigned short* __restrict__ out_p,
                                                           int n) {
    int w = threadIdx.x >> 6, l = threadIdx.x & 63;      // 4 nodes/block, 64 lanes/node
    int node = blockIdx.x * 4 + w;
    if (node >= n) return;
    const u16x4* base = (const u16x4*)ts + l;            // row stride 64 u16x4
    f32x4 acc = gather_sum_bf4<64>(base, src_sorted, row_ptr[node], row_ptr[node + 1]);
    float di = dinv[node];
    f32x4 b4 = *(const f32x4*)&bias[l * 4];
    f32x4 v = acc * di + b4;
    u16x4 hi;
#pragma unroll
    for (int j = 0; j < 4; ++j) hi[j] = f2bf(fmaxf(v[j], 0.f));
    // hi-only layout: rtile = 8 kg * 64 chunks = 512; lane covers k=l*4..l*4+3
    int row = node & 15;
    int kg = l >> 3, ks = (l >> 1) & 3, half = l & 1;
    size_t choff = (size_t)(node >> 4) * 512 + (size_t)kg * 64 + row * 4 + ks;
    *(u16x4*)&out_p[choff * 8 + half * 4] = hi;
}

// D=128 bf16 gather (32 lanes/node, u16x4) + fused W3 matvec (128 -> 32), bf16 ts3 out
__global__ __launch_bounds__(256) void agg_fused_w3_kernel(const unsigned short* __restrict__ ts,
                                                           const int* __restrict__ row_ptr,
                                                           const unsigned short* __restrict__ src_sorted,
                                                           const float* __restrict__ dinv,
                                                           const float* __restrict__ bias,
                                                           const float* __restrict__ W3,
                                                           unsigned short* __restrict__ ts3, int n) {
    __shared__ float W3s[128 * 32];
    __shared__ float hbuf[8][132];    // +4 pad
    for (int i = threadIdx.x; i < 128 * 32; i += 256) W3s[i] = W3[i];
    __syncthreads();
    int g = threadIdx.x >> 5, lane = threadIdx.x & 31;   // 8 nodes/block, 32 lanes/node
    int node = blockIdx.x * 8 + g;
    if (node >= n) return;
    const u16x4* base = (const u16x4*)ts + lane;         // row stride 32 u16x4
    f32x4 acc = gather_sum_bf4<32>(base, src_sorted, row_ptr[node], row_ptr[node + 1]);
    float di = dinv[node];
    f32x4 b4 = *(const f32x4*)&bias[lane * 4];
    f32x4 v = acc * di + b4;
#pragma unroll
    for (int j = 0; j < 4; ++j) v[j] = fmaxf(v[j], 0.f);
    *(f32x4*)&hbuf[g][lane * 4] = v;    // same-wave (32-lane group) DS: in-order
    float aj = 0.f;
#pragma unroll
    for (int k = 0; k < 128; k += 4) {
        f32x4 hv = *(const f32x4*)&hbuf[g][k];
        aj += hv[0] * W3s[k * 32 + lane] + hv[1] * W3s[(k + 1) * 32 + lane]
            + hv[2] * W3s[(k + 2) * 32 + lane] + hv[3] * W3s[(k + 3) * 32 + lane];
    }
    ts3[(long)node * 32 + lane] = f2bf(aj * di);
}

// D=32 bf16 gather (8 lanes/node) + fused Wk matvec (32 -> 8), bf16 tsk out
__global__ __launch_bounds__(256) void agg_fused_wk_kernel(const unsigned short* __restrict__ ts,
                                                           const int* __restrict__ row_ptr,
                                                           const unsigned short* __restrict__ src_sorted,
                                                           const float* __restrict__ dinv,
                                                           const float* __restrict__ bias,
                                                           const float* __restrict__ Wk,
                                                           unsigned short* __restrict__ tsk, int n) {
    __shared__ float Wks[32 * 8];
    __shared__ float hbuf[32][36];   // +4 pad
    for (int i = threadIdx.x; i < 32 * 8; i += 256) Wks[i] = Wk[i];
    __syncthreads();
    int g = threadIdx.x >> 3, lane = threadIdx.x & 7;
    int node = blockIdx.x * 32 + g;
    if (node >= n) return;
    const u16x4* base = (const u16x4*)ts + lane;         // row stride 8 u16x4
    f32x4 acc = gather_sum_bf4<8>(base, src_sorted, row_ptr[node], row_ptr[node + 1]);
    float di = dinv[node];
    f32x4 b4 = *(const f32x4*)&bias[lane * 4];
    f32x4 v = acc * di + b4;
#pragma unroll
    for (int j = 0; j < 4; ++j) v[j] = fmaxf(v[j], 0.f);
    *(f32x4*)&hbuf[g][lane * 4] = v;
    float aj = 0.f;
#pragma unroll
    for (int k = 0; k < 32; k += 4) {
        f32x4 hv = *(const f32x4*)&hbuf[g][k];
        aj += hv[0] * Wks[k * 8 + lane] + hv[1] * Wks[(k + 1) * 8 + lane]
            + hv[2] * Wks[(k + 2) * 8 + lane] + hv[3] * Wks[(k + 3) * 8 + lane];
    }
    tsk[(long)node * 8 + lane] = f2bf(aj * di);
}

// D=8 bf16 gather (2 lanes/node): z = relu(dinv*sum + bk), f32 out
__global__ __launch_bounds__(256) void agg_plain8_kernel(const unsigned short* __restrict__ ts,
                                                         const int* __restrict__ row_ptr,
                                                         const unsigned short* __restrict__ src_sorted,
                                                         const float* __restrict__ dinv,
                                                         const float* __restrict__ bias,
                                                         float* __restrict__ z, int n) {
    int g = threadIdx.x >> 1, lane = threadIdx.x & 1;
    int node = blockIdx.x * 128 + g;
    if (node >= n) return;
    const u16x4* base = (const u16x4*)ts + lane;         // row stride 2 u16x4
    f32x4 acc = gather_sum_bf4<2>(base, src_sorted, row_ptr[node], row_ptr[node + 1]);
    float di = dinv[node];
    f32x4 b4 = *(const f32x4*)&bias[lane * 4];
    f32x4 v = acc * di + b4;
#pragma unroll
    for (int j = 0; j < 4; ++j) v[j] = fmaxf(v[j], 0.f);
    *(f32x4*)&z[(long)node * 8 + lane * 4] = v;
}

// ---------------- decoder: out[k,e] = dot(z[s_e], z[d_e]) (identical across k) ----------------
__global__ __launch_bounds__(256) void decoder_kernel(const float* __restrict__ z,
                                                      const int* __restrict__ ei,
                                                      float* __restrict__ out,
                                                      int E, int K) {
    int e = blockIdx.x * blockDim.x + threadIdx.x;
    if (e >= E) return;
    int s = ei[e];
    int d = ei[E + e];
    const f32x4* zv = (const f32x4*)z;
    f32x4 a0 = zv[(long)s * 2], a1 = zv[(long)s * 2 + 1];
    f32x4 b0 = zv[(long)d * 2], b1 = zv[(long)d * 2 + 1];
    f32x4 p = a0 * b0 + a1 * b1;
    float acc = p[0] + p[1] + p[2] + p[3];
    for (int k = 0; k < K; k++) out[(long)k * E + e] = acc;
}

// ---------------- launch ----------------

extern "C" void kernel_launch(void* const* d_in, const int* in_sizes, int n_in,
                              void* d_out, int out_size, void* d_ws, size_t ws_size,
                              hipStream_t stream) {
    const float* x  = (const float*)d_in[0];
    const int*   ei = (const int*)d_in[1];
    const float* W1 = (const float*)d_in[3];
    const float* b1 = (const float*)d_in[4];
    const float* W2 = (const float*)d_in[5];
    const float* b2 = (const float*)d_in[6];
    const float* W3 = (const float*)d_in[7];
    const float* b3 = (const float*)d_in[8];
    const float* Wk = (const float*)d_in[9];
    const float* bk = (const float*)d_in[10];
    float* out = (float*)d_out;

    const int D1 = in_sizes[4];            // 256
    const int D2 = in_sizes[6];            // 128
    const int F  = in_sizes[3] / D1;       // 256
    const int N  = in_sizes[0] / F;        // 50000
    const int E  = in_sizes[1] / 2;        // 800000
    const int K  = out_size / E;           // 8
    const int M  = E + N;                  // edges incl self loops
    const int Mpad = (N + 127) & ~127;     // 50048

    size_t off = 0;
    auto alloc = [&](size_t bytes) -> void* {
        off = (off + 255) & ~(size_t)255;
        void* p = (char*)d_ws + off;
        off += bytes;
        return p;
    };
    int*   cnt        = (int*)alloc((size_t)N * sizeof(int));
    int*   row_ptr    = (int*)alloc((size_t)(N + 1) * sizeof(int));
    int*   bsum       = (int*)alloc(1024 * sizeof(int));
    float* dinv       = (float*)alloc((size_t)N * sizeof(float));
    unsigned short* ord        = (unsigned short*)alloc((size_t)E * sizeof(unsigned short));
    unsigned short* src_sorted = (unsigned short*)alloc((size_t)M * sizeof(unsigned short));
    unsigned short* region_x = (unsigned short*)alloc((size_t)Mpad * 2 * F * sizeof(short));  // xs_pack -> h1s_pack
    float* region_t   = (float*)alloc((size_t)Mpad * 256 * sizeof(float));                    // ts1/ts2 (as bf16)
    unsigned short* Wt1 = (unsigned short*)alloc((size_t)D1 * F * sizeof(short));             // W1_hi packed (131KB)
    unsigned short* Wt2 = (unsigned short*)alloc((size_t)D2 * D1 * sizeof(short));            // W2_hi packed (65KB)
    unsigned short* ts3 = (unsigned short*)alloc((size_t)Mpad * 32 * sizeof(short));          // bf16
    unsigned short* tsk = (unsigned short*)alloc((size_t)Mpad * 8 * sizeof(short));           // bf16
    float* z          = (float*)alloc((size_t)Mpad * 8 * sizeof(float));
    (void)ws_size; (void)n_in;

    unsigned short* xs  = region_x;                   // packed A (hi+lo) for GEMM1
    unsigned short* h1s = region_x;                   // packed A (hi only) for GEMM2 (reuse after GEMM1)
    unsigned short* ts1 = (unsigned short*)region_t;  // [Mpad,256] bf16 row-major gather table
    unsigned short* ts2 = (unsigned short*)region_t;  // [Mpad,128] bf16 (ts1 consumed)

    const int nbN = (N + THREADS - 1) / THREADS;          // 196
    const int nbE = (E + THREADS - 1) / THREADS;          // 3125
    const int nbE2 = (E + 511) / 512;                     // 1563 (2 edges/thread)
    const int nbX = (int)(((long)N * 64 + 255) / 256);    // 12500
    const int nbW1 = (D1 * (F / 8) + 255) / 256;          // 32
    const int nbW2 = (D2 * (D1 / 8) + 255) / 256;         // 16
    const int nbG1 = Mpad / 64;                           // 782
    const int nbG6 = 2 * nbG1;                            // 1564 (two column halves)

    // K1: init_cnt U convert_w1 U convert_w2
    k1_init_convw_kernel<<<nbN + nbW1 + nbW2, THREADS, 0, stream>>>(
        cnt, N, nbN, W1, Wt1, F, D1, nbW1, W2, Wt2, D1, D2);
    // K2: count_edges (2/thread, +ordinals) U convert_x
    k2_count_convx_kernel<<<nbE2 + nbX, THREADS, 0, stream>>>(ei, cnt, ord, E, nbE2, x, xs, N, F);
    // K3-K5: scan + fused prep
    scan_p1_kernel<<<nbN, THREADS, 0, stream>>>(cnt, bsum, N);
    scan_p2_kernel<<<1, 1024, 0, stream>>>(bsum, nbN);
    scan_p3_prep_kernel<<<nbN, THREADS, 0, stream>>>(cnt, bsum, row_ptr, dinv, src_sorted, N);
    // K6: gemm1 (BN=128 x2) U fill_edges (atomic-free)
    k6_gemm_fill_kernel<<<nbG6 + nbE2, THREADS, 0, stream>>>(
        xs, Wt1, dinv, ts1, N, D1, nbG6, ei, row_ptr, ord, src_sorted, E);
    // K7: layer-1 aggregation -> h1s packed hi-only
    agg_split256_kernel<<<(N + 3) / 4, THREADS, 0, stream>>>(ts1, row_ptr, src_sorted, dinv, b1, h1s, N);
    // K8: gemm2 (hi-only A)
    gemm_hi_kernel<128><<<nbG1, THREADS, 0, stream>>>(h1s, Wt2, dinv, ts2, N, D2);
    // K9: layer-2 agg + fused W3 -> bf16 ts3
    agg_fused_w3_kernel<<<(N + 7) / 8, THREADS, 0, stream>>>(ts2, row_ptr, src_sorted, dinv, b2, W3, ts3, N);
    // K10-K11: layer 3 agg + fused Wk -> bf16 tsk, final agg
    agg_fused_wk_kernel<<<(N + 31) / 32, THREADS, 0, stream>>>(ts3, row_ptr, src_sorted, dinv, b3, Wk, tsk, N);
    agg_plain8_kernel<<<(N + 127) / 128, THREADS, 0, stream>>>(tsk, row_ptr, src_sorted, dinv, bk, z, N);
    // K12: decoder
    decoder_kernel<<<nbE, THREADS, 0, stream>>>(z, ei, out, E, K);
}